// Round 2
// baseline (1970.528 us; speedup 1.0000x reference)
//
#include <hip/hip_runtime.h>
#include <hip/hip_bf16.h>

#define BB 4
#define NN 2048
#define NROWS (BB*NN)   // 8192

__device__ __forceinline__ float bf2f(unsigned short u){
  union { float f; unsigned int i; } x; x.i = ((unsigned int)u) << 16; return x.f;
}
__device__ __forceinline__ unsigned short f2bf(float f){
  union { float f; unsigned int i; } x; x.f = f;
  unsigned int i = x.i;
  i += 0x7fffu + ((i >> 16) & 1u);
  return (unsigned short)(i >> 16);
}
__device__ __forceinline__ float geluf(float x){
  return 0.5f * x * (1.0f + erff(x * 0.70710678118654752f));
}

#define FMA16(a, b, acc) \
  acc[0][0] = fmaf(a.x, b.x, acc[0][0]); acc[0][1] = fmaf(a.x, b.y, acc[0][1]); \
  acc[0][2] = fmaf(a.x, b.z, acc[0][2]); acc[0][3] = fmaf(a.x, b.w, acc[0][3]); \
  acc[1][0] = fmaf(a.y, b.x, acc[1][0]); acc[1][1] = fmaf(a.y, b.y, acc[1][1]); \
  acc[1][2] = fmaf(a.y, b.z, acc[1][2]); acc[1][3] = fmaf(a.y, b.w, acc[1][3]); \
  acc[2][0] = fmaf(a.z, b.x, acc[2][0]); acc[2][1] = fmaf(a.z, b.y, acc[2][1]); \
  acc[2][2] = fmaf(a.z, b.z, acc[2][2]); acc[2][3] = fmaf(a.z, b.w, acc[2][3]); \
  acc[3][0] = fmaf(a.w, b.x, acc[3][0]); acc[3][1] = fmaf(a.w, b.y, acc[3][1]); \
  acc[3][2] = fmaf(a.w, b.z, acc[3][2]); acc[3][3] = fmaf(a.w, b.w, acc[3][3]);

// flags[0] = 1 if float inputs are fp32 (else bf16); flags[1] = 1 if mask is byte-packed
__global__ __launch_bounds__(256) void sniff_k(const unsigned short* tokens, const unsigned int* mask, int* flags){
  __shared__ int s_f32, s_byte;
  if (threadIdx.x == 0) { s_f32 = 0; s_byte = 0; }
  __syncthreads();
  for (int i = threadIdx.x; i < 4096; i += 256) {
    float v = bf2f(tokens[i]);
    if (!(fabsf(v) < 1e10f)) atomicOr(&s_f32, 1);   // catches huge AND NaN
  }
  for (int i = threadIdx.x; i < 2048; i += 256) {
    if (mask[i] > 1u) atomicOr(&s_byte, 1);
  }
  __syncthreads();
  if (threadIdx.x == 0) { flags[0] = s_f32; flags[1] = s_byte; }
}

__global__ __launch_bounds__(256) void maskconv_k(const void* mask, const int* flags, int* m32){
  int i = blockIdx.x*256 + threadIdx.x;
  if (i < NROWS) {
    int v = flags[1] ? (int)((const unsigned char*)mask)[i] : ((const int*)mask)[i];
    m32[i] = v ? 1 : 0;
  }
}

__global__ __launch_bounds__(256) void fconv_k(const void* src, const int* flags, float* dst, int n){
  int f = flags[0];
  for (int i = blockIdx.x*256 + threadIdx.x; i < n; i += gridDim.x*256) {
    dst[i] = f ? ((const float*)src)[i] : bf2f(((const unsigned short*)src)[i]);
  }
}

// rope[p][j]: j<32 -> sin(p*invf[j]), j>=32 -> cos(p*invf[j-32])
__global__ __launch_bounds__(64) void rope_k(float* rope){
  int p = blockIdx.x, j = threadIdx.x;
  int jj = (j < 32) ? j : j - 32;
  float invf = powf(10000.0f, -(float)jj * (1.0f/32.0f));
  float prod = (float)p * invf;
  rope[p*64 + j] = (j < 32) ? sinf(prod) : cosf(prod);
}

// w[o][c][kk] -> wt[kk][c][o] (fp32), src dtype per flag
__global__ __launch_bounds__(256) void wtrans_k(const void* w, const int* flags, float* wt){
  const int total = 512*512*9;
  int f = flags[0];
  for (int idx = blockIdx.x*256 + threadIdx.x; idx < total; idx += gridDim.x*256) {
    float v = f ? ((const float*)w)[idx] : bf2f(((const unsigned short*)w)[idx]);
    int o = idx / 4608;
    int rem = idx - o*4608;
    int c = rem / 9;
    int kk = rem - c*9;
    wt[((size_t)kk*512 + c)*512 + o] = v;
  }
}

// C[M,N] = A[M,K] @ B[K,N] (+bias)(+gelu). All fp32.
template<bool BIAS, bool GELU>
__global__ __launch_bounds__(256) void gemm_k(const float* A, const float* B,
                                              const float* bias, float* C,
                                              int M, int N, int K){
  __shared__ float As[16][68];
  __shared__ float Bs[16][68];
  int tid = threadIdx.x;
  int tx = tid & 15, ty = tid >> 4;
  int n0 = blockIdx.x * 64, m0 = blockIdx.y * 64;
  float acc[4][4] = {{0.f,0.f,0.f,0.f},{0.f,0.f,0.f,0.f},{0.f,0.f,0.f,0.f},{0.f,0.f,0.f,0.f}};
  int am = tid >> 2;            // 0..63 local row
  int ak = (tid & 3) * 4;       // 0,4,8,12
  int bk = tid >> 4;            // 0..15
  int bn = (tid & 15) * 4;      // 0..60
  for (int k0 = 0; k0 < K; k0 += 16) {
    {
      const float* p = A + (size_t)(m0 + am)*K + k0 + ak;
      float4 u = *(const float4*)p;
      As[ak+0][am] = u.x; As[ak+1][am] = u.y; As[ak+2][am] = u.z; As[ak+3][am] = u.w;
    }
    {
      const float* p = B + (size_t)(k0 + bk)*N + n0 + bn;
      float4 u = *(const float4*)p;
      Bs[bk][bn+0] = u.x; Bs[bk][bn+1] = u.y; Bs[bk][bn+2] = u.z; Bs[bk][bn+3] = u.w;
    }
    __syncthreads();
    #pragma unroll
    for (int kk = 0; kk < 16; kk++) {
      float4 a = *(const float4*)&As[kk][ty*4];
      float4 b = *(const float4*)&Bs[kk][tx*4];
      FMA16(a, b, acc)
    }
    __syncthreads();
  }
  #pragma unroll
  for (int i = 0; i < 4; i++) {
    int row = m0 + ty*4 + i;
    float4 o;
    float* op = &o.x;
    #pragma unroll
    for (int j = 0; j < 4; j++) {
      float v = acc[i][j];
      if (BIAS) v += bias[n0 + tx*4 + j];
      if (GELU) v = geluf(v);
      op[j] = v;
    }
    *(float4*)&C[(size_t)row*N + n0 + tx*4] = o;
  }
}

// per-(b,n): q = softmax(q+rope, over d)*0.125 in place; v *= mask in place
__global__ __launch_bounds__(512) void qv_k(const float* rope, const int* mask, float* qkv){
  int row = blockIdx.x;
  int n = row & (NN-1);
  int tid = threadIdx.x;
  int d = tid & 63;
  float* qp = qkv + (size_t)row*1536;
  float v = qp[tid] + rope[n*64 + d];
  float m = v;
  #pragma unroll
  for (int o = 32; o; o >>= 1) m = fmaxf(m, __shfl_xor(m, o, 64));
  float e = expf(v - m);
  float s = e;
  #pragma unroll
  for (int o = 32; o; o >>= 1) s += __shfl_xor(s, o, 64);
  qp[tid] = e * (0.125f / s);
  float mk = mask[row] ? 1.0f : 0.0f;
  qp[1024 + tid] *= mk;
}

// per-(b,h): column max & expsum over n (masked) for each d
__global__ __launch_bounds__(256) void kstat_k(const float* qkv, const float* rope,
                                               const int* mask, float* kM, float* kS){
  int bh = blockIdx.x;
  int b = bh >> 3, h = bh & 7;
  int tid = threadIdx.x;
  int d = tid & 63, g = tid >> 6;
  __shared__ float red[4][64];
  const float* kp = qkv + (size_t)b*NN*1536 + 512 + h*64 + d;
  const int* mp = mask + b*NN;
  float m = -3.0e38f;
  for (int n = g*512; n < g*512+512; n++) {
    if (mp[n]) m = fmaxf(m, kp[(size_t)n*1536] + rope[n*64 + d]);
  }
  red[g][d] = m;
  __syncthreads();
  float M = fmaxf(fmaxf(red[0][d], red[1][d]), fmaxf(red[2][d], red[3][d]));
  float s = 0.0f;
  for (int n = g*512; n < g*512+512; n++) {
    if (mp[n]) s += expf(kp[(size_t)n*1536] + rope[n*64 + d] - M);
  }
  __syncthreads();
  red[g][d] = s;
  __syncthreads();
  if (g == 0) {
    kM[bh*64 + d] = M;
    kS[bh*64 + d] = red[0][d] + red[1][d] + red[2][d] + red[3][d];
  }
}

// elementwise: k <- mask ? exp(k+rope-M)/S : 0  (in place)
__global__ __launch_bounds__(256) void kexp_k(const float* rope, const int* mask,
                                              const float* kM, const float* kS, float* qkv){
  const int total = NROWS*512;
  for (int idx = blockIdx.x*256 + threadIdx.x; idx < total; idx += gridDim.x*256) {
    int row = idx >> 9;
    int hd = idx & 511;
    int b = row >> 11, n = row & (NN-1);
    float* kp = qkv + (size_t)row*1536 + 512 + hd;
    if (mask[row]) {
      float v = *kp + rope[n*64 + (hd & 63)] - kM[b*512 + hd];
      *kp = expf(v) / kS[b*512 + hd];
    } else {
      *kp = 0.0f;
    }
  }
}

__global__ __launch_bounds__(256) void zero_k(float* p, int n){
  int idx = blockIdx.x*256 + threadIdx.x;
  if (idx < n) p[idx] = 0.0f;
}

// ctx[bh][d][e] += sum_n ke[n,d]*v[n,e] over a 256-length n segment
__global__ __launch_bounds__(256) void ctx_k(const float* qkv, float* ctx){
  int bh = blockIdx.x, seg = blockIdx.y;
  int b = bh >> 3, h = bh & 7;
  __shared__ float Ks[32][68], Vs[32][68];
  int tid = threadIdx.x, tx = tid & 15, ty = tid >> 4;
  float acc[4][4] = {{0.f,0.f,0.f,0.f},{0.f,0.f,0.f,0.f},{0.f,0.f,0.f,0.f},{0.f,0.f,0.f,0.f}};
  const float* basep = qkv + (size_t)(b*NN + seg*256)*1536 + h*64;
  int nl = tid >> 3, col = (tid & 7)*8;
  for (int nc = 0; nc < 256; nc += 32) {
    const float* kp = basep + (size_t)(nc + nl)*1536 + 512 + col;
    const float* vp = basep + (size_t)(nc + nl)*1536 + 1024 + col;
    float4 a0 = *(const float4*)kp, a1 = *(const float4*)(kp+4);
    float4 b0 = *(const float4*)vp, b1 = *(const float4*)(vp+4);
    *(float4*)&Ks[nl][col]   = a0; *(float4*)&Ks[nl][col+4] = a1;
    *(float4*)&Vs[nl][col]   = b0; *(float4*)&Vs[nl][col+4] = b1;
    __syncthreads();
    #pragma unroll
    for (int q = 0; q < 32; q++) {
      float4 a = *(const float4*)&Ks[q][ty*4];
      float4 b = *(const float4*)&Vs[q][tx*4];
      FMA16(a, b, acc)
    }
    __syncthreads();
  }
  float* cp = ctx + (size_t)bh*4096;
  #pragma unroll
  for (int i = 0; i < 4; i++)
    #pragma unroll
    for (int j = 0; j < 4; j++)
      atomicAdd(&cp[(ty*4 + i)*64 + tx*4 + j], acc[i][j]);
}

// inner[row][h*64+e] = sum_d q[row][h*64+d] * ctx[b,h][d][e]
__global__ __launch_bounds__(512) void inner_k(const float* qkv, const float* ctx, float* inner){
  int row = blockIdx.x;
  int b = row >> 11;
  __shared__ float qs[512];
  int tid = threadIdx.x;
  qs[tid] = qkv[(size_t)row*1536 + tid];
  __syncthreads();
  int h = tid >> 6, e = tid & 63;
  const float* cp = ctx + (size_t)(b*8 + h)*4096 + e;
  const float* qh = &qs[h*64];
  float s = 0.0f;
  #pragma unroll
  for (int d2 = 0; d2 < 64; d2++) s = fmaf(qh[d2], cp[d2*64], s);
  inner[(size_t)row*512 + tid] = s;
}

// cpad[b][t'][c], t' in [0,2088): masked attn, zero-padded 20 both sides
__global__ __launch_bounds__(256) void cpad_k(const float* attn, const int* mask, float* cpad){
  const int total = BB*2088*512;
  for (int idx = blockIdx.x*256 + threadIdx.x; idx < total; idx += gridDim.x*256) {
    int c = idx & 511;
    int t = (idx >> 9) % 2088;
    int b = idx / (2088*512);
    int pos = t - 20;
    float v = 0.0f;
    if (pos >= 0 && pos < NN && mask[b*NN + pos]) v = attn[((size_t)b*NN + pos)*512 + c];
    cpad[idx] = v;
  }
}

// D[b][t][o] (+)= gelu(conv(cpad, wt) + bias); shifted implicit GEMM
__global__ __launch_bounds__(256) void conv_k(const float* cpad, const float* wt,
                                              const float* bias, float* D,
                                              int DIL, int P, int ROWS, int accumulate){
  __shared__ float As[104][33];
  __shared__ float Ws[32][68];
  int tid = threadIdx.x, tx = tid & 15, ty = tid >> 4;
  int o0 = blockIdx.x*64, t0 = blockIdx.y*64, b = blockIdx.z;
  int base = 20 - P;
  float acc[4][4] = {{0.f,0.f,0.f,0.f},{0.f,0.f,0.f,0.f},{0.f,0.f,0.f,0.f},{0.f,0.f,0.f,0.f}};
  const float* cb = cpad + ((size_t)b*2088 + t0 + base)*512;
  for (int c0 = 0; c0 < 512; c0 += 32) {
    for (int i = tid; i < ROWS*32; i += 256) {
      int r = i >> 5, cl = i & 31;
      As[r][cl] = cb[(size_t)r*512 + c0 + cl];
    }
    for (int kk = 0; kk < 9; kk++) {
      {
        int cl = tid >> 3, ol = (tid & 7)*8;
        const float* wp = wt + ((size_t)kk*512 + c0 + cl)*512 + o0 + ol;
        float4 w0 = *(const float4*)wp, w1 = *(const float4*)(wp + 4);
        *(float4*)&Ws[cl][ol]   = w0;
        *(float4*)&Ws[cl][ol+4] = w1;
      }
      __syncthreads();
      const float* arow = &As[ty*4 + kk*DIL][0];
      #pragma unroll
      for (int cl = 0; cl < 32; cl++) {
        float4 a;
        a.x = arow[cl]; a.y = arow[33 + cl]; a.z = arow[66 + cl]; a.w = arow[99 + cl];
        float4 b4 = *(const float4*)&Ws[cl][tx*4];
        FMA16(a, b4, acc)
      }
      __syncthreads();
    }
  }
  #pragma unroll
  for (int i = 0; i < 4; i++) {
    size_t off = ((size_t)b*NN + t0 + ty*4 + i)*512 + o0 + tx*4;
    float4 o;
    float* op = &o.x;
    #pragma unroll
    for (int j = 0; j < 4; j++) {
      float v = acc[i][j] + bias[o0 + tx*4 + j];
      op[j] = geluf(v);
    }
    if (accumulate) {
      float4 prev = *(float4*)&D[off];
      o.x += prev.x; o.y += prev.y; o.z += prev.z; o.w += prev.w;
    }
    *(float4*)&D[off] = o;
  }
}

__device__ __forceinline__ float block_sum512(float v, float* red){
  #pragma unroll
  for (int o = 32; o; o >>= 1) v += __shfl_xor(v, o, 64);
  int w = threadIdx.x >> 6;
  if ((threadIdx.x & 63) == 0) red[w] = v;
  __syncthreads();
  float t = red[0] + red[1] + red[2] + red[3];
  __syncthreads();
  return t;
}

// LN over 512 channels; optional add; FINAL => output dtype follows flags[0]
template<bool ADD, bool FINAL>
__global__ __launch_bounds__(256) void ln_k(const float* X, const float* Y,
                                            const float* g, const float* be,
                                            const int* flags, void* out){
  __shared__ float red[4];
  size_t row = blockIdx.x;
  int tid = threadIdx.x;
  const float* xp = X + row*512;
  float x0 = xp[tid], x1 = xp[tid + 256];
  if (ADD) { const float* yp = Y + row*512; x0 += yp[tid]; x1 += yp[tid + 256]; }
  float mean = block_sum512(x0 + x1, red) * (1.0f/512.0f);
  float d0 = x0 - mean, d1 = x1 - mean;
  float var = block_sum512(d0*d0 + d1*d1, red) * (1.0f/512.0f);
  float inv = rsqrtf(var + 1e-5f);
  float r0 = d0*inv*g[tid]       + be[tid];
  float r1 = d1*inv*g[tid + 256] + be[tid + 256];
  if (FINAL && !flags[0]) {
    unsigned short* op = (unsigned short*)out;
    op[row*512 + tid]       = f2bf(r0);
    op[row*512 + tid + 256] = f2bf(r1);
  } else {
    float* op = (float*)out;
    op[row*512 + tid]       = r0;
    op[row*512 + tid + 256] = r1;
  }
}

extern "C" void kernel_launch(void* const* d_in, const int* in_sizes, int n_in,
                              void* d_out, int out_size, void* d_ws, size_t ws_size,
                              hipStream_t stream) {
  const void* tokens   = d_in[0];
  const void* mask     = d_in[1];
  const void* w_qkv    = d_in[2];
  const void* w_out    = d_in[3];
  const void* b_out    = d_in[4];
  const void* w_narrow = d_in[5];
  const void* b_narrow = d_in[6];
  const void* w_wide   = d_in[7];
  const void* b_wide   = d_in[8];
  const void* ln1_g    = d_in[9];
  const void* ln1_b    = d_in[10];
  const void* ff_w     = d_in[11];
  const void* ff_b     = d_in[12];
  const void* ln2_g    = d_in[13];
  const void* ln2_b    = d_in[14];

  float* ws = (float*)d_ws;
  // layout (floats)
  int*   flags   = (int*)ws;                       // 16
  float* rope    = ws + 16;                        // 131072 -> 131088
  float* kM      = ws + 131088;                    // 2048   -> 133136
  float* kS      = ws + 133136;                    // 2048   -> 135184
  float* ctx     = ws + 135184;                    // 131072 -> 266256
  int*   m32     = (int*)(ws + 266256);            // 8192   -> 274448
  float* params  = ws + 274448;                    // 4096   -> 278544
  float* wqkv_f  = ws + 278544;                    // 786432 -> 1064976
  float* wout_f  = ws + 1064976;                   // 262144 -> 1327120
  float* ffw_f   = ws + 1327120;                   // 262144 -> 1589264
  float* wtN     = ws + 1589264;                   // 2359296-> 3948560
  float* wtW     = ws + 3948560;                   // 2359296-> 6307856
  float* tok_f   = ws + 6307856;                   // 4194304-> 10502160 (reused: attn, then E)
  float* qkv     = ws + 10502160;                  // 12582912->23085072 (reused: cpad, Dbuf)
  float* inner   = ws + 23085072;                  // 4194304-> 27279376 (reused: t1)
  // params sub-pointers
  float* p_bout = params;        float* p_bnar = params + 512;
  float* p_bwid = params + 1024; float* p_l1g  = params + 1536;
  float* p_l1b  = params + 2048; float* p_ffb  = params + 2560;
  float* p_l2g  = params + 3072; float* p_l2b  = params + 3584;
  // overlays
  float* attn = tok_f;
  float* cpad = qkv;
  float* Dbuf = qkv + 4276224;
  float* t1   = inner;
  float* Ebuf = tok_f;

  sniff_k<<<dim3(1), dim3(256), 0, stream>>>((const unsigned short*)tokens, (const unsigned int*)mask, flags);
  maskconv_k<<<dim3(32), dim3(256), 0, stream>>>(mask, flags, m32);
  fconv_k<<<dim3(2048), dim3(256), 0, stream>>>(tokens, flags, tok_f, NROWS*512);
  fconv_k<<<dim3(2048), dim3(256), 0, stream>>>(w_qkv, flags, wqkv_f, 512*1536);
  fconv_k<<<dim3(1024), dim3(256), 0, stream>>>(w_out, flags, wout_f, 512*512);
  fconv_k<<<dim3(1024), dim3(256), 0, stream>>>(ff_w, flags, ffw_f, 512*512);
  fconv_k<<<dim3(2), dim3(256), 0, stream>>>(b_out, flags, p_bout, 512);
  fconv_k<<<dim3(2), dim3(256), 0, stream>>>(b_narrow, flags, p_bnar, 512);
  fconv_k<<<dim3(2), dim3(256), 0, stream>>>(b_wide, flags, p_bwid, 512);
  fconv_k<<<dim3(2), dim3(256), 0, stream>>>(ln1_g, flags, p_l1g, 512);
  fconv_k<<<dim3(2), dim3(256), 0, stream>>>(ln1_b, flags, p_l1b, 512);
  fconv_k<<<dim3(2), dim3(256), 0, stream>>>(ff_b, flags, p_ffb, 512);
  fconv_k<<<dim3(2), dim3(256), 0, stream>>>(ln2_g, flags, p_l2g, 512);
  fconv_k<<<dim3(2), dim3(256), 0, stream>>>(ln2_b, flags, p_l2b, 512);
  wtrans_k<<<dim3(576), dim3(256), 0, stream>>>(w_narrow, flags, wtN);
  wtrans_k<<<dim3(576), dim3(256), 0, stream>>>(w_wide, flags, wtW);
  rope_k<<<dim3(2048), dim3(64), 0, stream>>>(rope);

  // qkv = tokens @ w_qkv  (8192 x 1536, K=512)
  gemm_k<false,false><<<dim3(24,128), dim3(256), 0, stream>>>(
      tok_f, wqkv_f, nullptr, qkv, NROWS, 1536, 512);

  qv_k<<<dim3(NROWS), dim3(512), 0, stream>>>(rope, m32, qkv);
  kstat_k<<<dim3(32), dim3(256), 0, stream>>>(qkv, rope, m32, kM, kS);
  kexp_k<<<dim3(4096), dim3(256), 0, stream>>>(rope, m32, kM, kS, qkv);

  zero_k<<<dim3(512), dim3(256), 0, stream>>>(ctx, 131072);
  ctx_k<<<dim3(32, 8), dim3(256), 0, stream>>>(qkv, ctx);
  inner_k<<<dim3(NROWS), dim3(512), 0, stream>>>(qkv, ctx, inner);

  // attn = inner @ w_out + b_out  (8192 x 512, K=512)  -> tok_f region (tokens dead)
  gemm_k<true,false><<<dim3(8,128), dim3(256), 0, stream>>>(
      inner, wout_f, p_bout, attn, NROWS, 512, 512);

  // qkv region dead from here; host cpad + Dbuf there
  cpad_k<<<dim3(4176), dim3(256), 0, stream>>>(attn, m32, cpad);
  conv_k<<<dim3(8,32,4), dim3(256), 0, stream>>>(cpad, wtN, p_bnar, Dbuf, 1, 4, 72, 0);
  conv_k<<<dim3(8,32,4), dim3(256), 0, stream>>>(cpad, wtW, p_bwid, Dbuf, 5, 20, 104, 1);

  // t1 = LN(attn + Dbuf) -> inner region (inner dead)
  ln_k<true,false><<<dim3(NROWS), dim3(256), 0, stream>>>(attn, Dbuf, p_l1g, p_l1b, flags, (void*)t1);

  // E = gelu(t1 @ ff_w + ff_b) -> attn region (attn dead)
  gemm_k<true,true><<<dim3(8,128), dim3(256), 0, stream>>>(
      t1, ffw_f, p_ffb, Ebuf, NROWS, 512, 512);

  // out = LN(E) -> d_out, dtype per flags[0]
  ln_k<false,true><<<dim3(NROWS), dim3(256), 0, stream>>>(Ebuf, nullptr, p_l2g, p_l2b, flags, d_out);
}

// Round 3
// 656.731 us; speedup vs baseline: 3.0005x; 3.0005x over previous
//
#include <hip/hip_runtime.h>
#include <hip/hip_bf16.h>

#define BB 4
#define NN 2048
#define NROWS (BB*NN)   // 8192

typedef unsigned short u16;
typedef __bf16 bf16x8 __attribute__((ext_vector_type(8)));
typedef u16    u16x8  __attribute__((ext_vector_type(8)));
typedef float  fx4    __attribute__((ext_vector_type(4)));

__device__ __forceinline__ float bf2f(u16 u){
  union { float f; unsigned int i; } x; x.i = ((unsigned int)u) << 16; return x.f;
}
__device__ __forceinline__ u16 f2bf(float f){
  union { float f; unsigned int i; } x; x.f = f;
  unsigned int i = x.i;
  i += 0x7fffu + ((i >> 16) & 1u);
  return (u16)(i >> 16);
}
__device__ __forceinline__ float geluf(float x){
  return 0.5f * x * (1.0f + erff(x * 0.70710678118654752f));
}

// flags[0] = 1 if float inputs are fp32 (else bf16); flags[1] = 1 if mask byte-packed
__global__ __launch_bounds__(256) void sniff_k(const u16* tokens, const unsigned int* mask, int* flags){
  __shared__ int s_f32, s_byte;
  if (threadIdx.x == 0) { s_f32 = 0; s_byte = 0; }
  __syncthreads();
  for (int i = threadIdx.x; i < 4096; i += 256) {
    float v = bf2f(tokens[i]);
    if (!(fabsf(v) < 1e10f)) atomicOr(&s_f32, 1);
  }
  for (int i = threadIdx.x; i < 2048; i += 256) {
    if (mask[i] > 1u) atomicOr(&s_byte, 1);
  }
  __syncthreads();
  if (threadIdx.x == 0) { flags[0] = s_f32; flags[1] = s_byte; }
}

__global__ __launch_bounds__(256) void maskconv_k(const void* mask, const int* flags, int* m32){
  int i = blockIdx.x*256 + threadIdx.x;
  if (i < NROWS) {
    int v = flags[1] ? (int)((const unsigned char*)mask)[i] : ((const int*)mask)[i];
    m32[i] = v ? 1 : 0;
  }
}

// fp32 params from src (dtype per flag)
__global__ __launch_bounds__(256) void fconv_k(const void* src, const int* flags, float* dst, int n){
  int f = flags[0];
  for (int i = blockIdx.x*256 + threadIdx.x; i < n; i += gridDim.x*256)
    dst[i] = f ? ((const float*)src)[i] : bf2f(((const u16*)src)[i]);
}

// straight copy to bf16
__global__ __launch_bounds__(256) void bfcopy_k(const void* src, const int* flags, u16* dst, int n){
  int f = flags[0];
  for (int i = blockIdx.x*256 + threadIdx.x; i < n; i += gridDim.x*256)
    dst[i] = f ? f2bf(((const float*)src)[i]) : ((const u16*)src)[i];
}

// src [K][N] -> dst [N][K] bf16
__global__ __launch_bounds__(256) void btrans_k(const void* src, const int* flags, u16* dst, int K, int N){
  int f = flags[0];
  int total = K*N;
  for (int idx = blockIdx.x*256 + threadIdx.x; idx < total; idx += gridDim.x*256) {
    int k = idx / N, n = idx - k*N;
    u16 v = f ? f2bf(((const float*)src)[idx]) : ((const u16*)src)[idx];
    dst[(size_t)n*K + k] = v;
  }
}

// w[o][c][kk] -> W2[kk][o][c] bf16
__global__ __launch_bounds__(256) void wtrans2_k(const void* w, const int* flags, u16* dst){
  const int total = 512*512*9;
  int f = flags[0];
  for (int idx = blockIdx.x*256 + threadIdx.x; idx < total; idx += gridDim.x*256) {
    u16 v = f ? f2bf(((const float*)w)[idx]) : ((const u16*)w)[idx];
    int o = idx / 4608;
    int rem = idx - o*4608;
    int c = rem / 9;
    int kk = rem - c*9;
    dst[(size_t)kk*262144 + o*512 + c] = v;
  }
}

// rope[p][j]: j<32 -> sin, j>=32 -> cos
__global__ __launch_bounds__(64) void rope_k(float* rope){
  int p = blockIdx.x, j = threadIdx.x;
  int jj = (j < 32) ? j : j - 32;
  float invf = powf(10000.0f, -(float)jj * (1.0f/32.0f));
  float prod = (float)p * invf;
  rope[p*64 + j] = (j < 32) ? sinf(prod) : cosf(prod);
}

// ---------------- MFMA bf16 GEMM: C[M,N] = A[M,K] @ Bt[N,K]^T ----------------
// A, Bt bf16 row-major over k. 128x128 tile, 4 waves (2x2 of 64x64), BK=32.
template<bool BIAS, bool GELU>
__global__ __launch_bounds__(256) void mgemm_k(const u16* A, const u16* Bt, const float* bias,
                                               float* C, int M, int N, int K){
  __shared__ u16 As[128][40];
  __shared__ u16 Bs[128][40];
  int tid = threadIdx.x;
  int lane = tid & 63;
  int wave = tid >> 6;
  int wm = (wave >> 1) * 64, wn = (wave & 1) * 64;
  int quad = lane >> 4, l16 = lane & 15;
  int m0 = blockIdx.y * 128, n0 = blockIdx.x * 128;
  fx4 acc[4][4] = {};
  int ar = tid >> 2;          // 0..63
  int ac = (tid & 3) * 8;     // 0,8,16,24
  for (int k0 = 0; k0 < K; k0 += 32) {
    *(u16x8*)&As[ar][ac]    = *(const u16x8*)&A[(size_t)(m0+ar)*K + k0 + ac];
    *(u16x8*)&As[ar+64][ac] = *(const u16x8*)&A[(size_t)(m0+ar+64)*K + k0 + ac];
    *(u16x8*)&Bs[ar][ac]    = *(const u16x8*)&Bt[(size_t)(n0+ar)*K + k0 + ac];
    *(u16x8*)&Bs[ar+64][ac] = *(const u16x8*)&Bt[(size_t)(n0+ar+64)*K + k0 + ac];
    __syncthreads();
    bf16x8 af[4], bfv[4];
    #pragma unroll
    for (int i = 0; i < 4; i++)
      af[i] = __builtin_bit_cast(bf16x8, *(const u16x8*)&As[wm + i*16 + l16][quad*8]);
    #pragma unroll
    for (int j = 0; j < 4; j++)
      bfv[j] = __builtin_bit_cast(bf16x8, *(const u16x8*)&Bs[wn + j*16 + l16][quad*8]);
    #pragma unroll
    for (int i = 0; i < 4; i++)
      #pragma unroll
      for (int j = 0; j < 4; j++)
        acc[i][j] = __builtin_amdgcn_mfma_f32_16x16x32_bf16(af[i], bfv[j], acc[i][j], 0, 0, 0);
    __syncthreads();
  }
  #pragma unroll
  for (int i = 0; i < 4; i++)
    #pragma unroll
    for (int j = 0; j < 4; j++) {
      int col = n0 + wn + j*16 + l16;
      float bv = BIAS ? bias[col] : 0.0f;
      #pragma unroll
      for (int r = 0; r < 4; r++) {
        int row = m0 + wm + i*16 + quad*4 + r;
        float v = acc[i][j][r] + bv;
        if (GELU) v = geluf(v);
        C[(size_t)row*N + col] = v;
      }
    }
}

// ---------------- MFMA conv (implicit GEMM over kk,c) ----------------
// out[b*2048+t][o] = gelu(sum_{kk,c} cpad[b][t+base+kk*DIL][c] * W2[kk][o][c] + bias[o])
__global__ __launch_bounds__(256) void mconv_k(const u16* cpad, const u16* W2, const float* bias,
                                               float* D, int DIL, int base, int accumulate){
  __shared__ u16 As[128][40];
  __shared__ u16 Bs[128][40];
  int tid = threadIdx.x;
  int lane = tid & 63;
  int wave = tid >> 6;
  int wm = (wave >> 1) * 64, wn = (wave & 1) * 64;
  int quad = lane >> 4, l16 = lane & 15;
  int o0 = blockIdx.x * 128, m0 = blockIdx.y * 128, b = blockIdx.z;
  fx4 acc[4][4] = {};
  int ar = tid >> 2;
  int ac = (tid & 3) * 8;
  const u16* cb = cpad + ((size_t)b*2088 + m0 + base)*512;
  for (int kk = 0; kk < 9; kk++) {
    const u16* arow = cb + (size_t)kk*DIL*512;
    const u16* wrow = W2 + (size_t)kk*262144 + (size_t)o0*512;
    for (int c0 = 0; c0 < 512; c0 += 32) {
      *(u16x8*)&As[ar][ac]    = *(const u16x8*)&arow[(size_t)ar*512 + c0 + ac];
      *(u16x8*)&As[ar+64][ac] = *(const u16x8*)&arow[(size_t)(ar+64)*512 + c0 + ac];
      *(u16x8*)&Bs[ar][ac]    = *(const u16x8*)&wrow[(size_t)ar*512 + c0 + ac];
      *(u16x8*)&Bs[ar+64][ac] = *(const u16x8*)&wrow[(size_t)(ar+64)*512 + c0 + ac];
      __syncthreads();
      bf16x8 af[4], bfv[4];
      #pragma unroll
      for (int i = 0; i < 4; i++)
        af[i] = __builtin_bit_cast(bf16x8, *(const u16x8*)&As[wm + i*16 + l16][quad*8]);
      #pragma unroll
      for (int j = 0; j < 4; j++)
        bfv[j] = __builtin_bit_cast(bf16x8, *(const u16x8*)&Bs[wn + j*16 + l16][quad*8]);
      #pragma unroll
      for (int i = 0; i < 4; i++)
        #pragma unroll
        for (int j = 0; j < 4; j++)
          acc[i][j] = __builtin_amdgcn_mfma_f32_16x16x32_bf16(af[i], bfv[j], acc[i][j], 0, 0, 0);
      __syncthreads();
    }
  }
  #pragma unroll
  for (int i = 0; i < 4; i++)
    #pragma unroll
    for (int j = 0; j < 4; j++) {
      int col = o0 + wn + j*16 + l16;
      float bv = bias[col];
      #pragma unroll
      for (int r = 0; r < 4; r++) {
        int row = b*2048 + m0 + wm + i*16 + quad*4 + r;
        float v = geluf(acc[i][j][r] + bv);
        if (accumulate) v += D[(size_t)row*512 + col];
        D[(size_t)row*512 + col] = v;
      }
    }
}

// per-(b,n): q = softmax(q+rope over d)*0.125 in place; v *= mask in place
__global__ __launch_bounds__(512) void qv_k(const float* rope, const int* mask, float* qkv){
  int row = blockIdx.x;
  int n = row & (NN-1);
  int tid = threadIdx.x;
  int d = tid & 63;
  float* qp = qkv + (size_t)row*1536;
  float v = qp[tid] + rope[n*64 + d];
  float m = v;
  #pragma unroll
  for (int o = 32; o; o >>= 1) m = fmaxf(m, __shfl_xor(m, o, 64));
  float e = expf(v - m);
  float s = e;
  #pragma unroll
  for (int o = 32; o; o >>= 1) s += __shfl_xor(s, o, 64);
  qp[tid] = e * (0.125f / s);
  float mk = mask[row] ? 1.0f : 0.0f;
  qp[1024 + tid] *= mk;
}

// segmented k-softmax stats: per (b,h), segment of 256 rows
__global__ __launch_bounds__(256) void kstat1_k(const float* qkv, const float* rope,
                                                const int* mask, float* kredM, float* kredS){
  int bh = blockIdx.x, seg = blockIdx.y;
  int b = bh >> 3, h = bh & 7;
  int tid = threadIdx.x;
  int d = tid & 63, g = tid >> 6;
  __shared__ float red[4][64];
  const float* kp = qkv + (size_t)b*NN*1536 + 512 + h*64 + d;
  const int* mp = mask + b*NN;
  int nbase = seg*256 + g*64;
  float m = -3.0e38f;
  for (int n = nbase; n < nbase+64; n++)
    if (mp[n]) m = fmaxf(m, kp[(size_t)n*1536] + rope[n*64 + d]);
  red[g][d] = m;
  __syncthreads();
  float M = fmaxf(fmaxf(red[0][d], red[1][d]), fmaxf(red[2][d], red[3][d]));
  __syncthreads();
  float s = 0.0f;
  if (M > -1e38f) {
    for (int n = nbase; n < nbase+64; n++)
      if (mp[n]) s += expf(kp[(size_t)n*1536] + rope[n*64 + d] - M);
  }
  red[g][d] = s;
  __syncthreads();
  if (g == 0) {
    int o = (bh*8 + seg)*64 + d;
    kredM[o] = M;
    kredS[o] = red[0][d] + red[1][d] + red[2][d] + red[3][d];
  }
}

__global__ __launch_bounds__(64) void kstat2_k(const float* kredM, const float* kredS,
                                               float* kM, float* kS){
  int bh = blockIdx.x, d = threadIdx.x;
  float M = -3.0e38f;
  for (int s = 0; s < 8; s++) M = fmaxf(M, kredM[(bh*8 + s)*64 + d]);
  float S = 0.0f;
  for (int s = 0; s < 8; s++) {
    float ms = kredM[(bh*8 + s)*64 + d];
    if (ms > -1e38f) S += kredS[(bh*8 + s)*64 + d] * expf(ms - M);
  }
  kM[bh*64 + d] = M;
  kS[bh*64 + d] = (S > 0.0f) ? S : 1.0f;
}

// k <- mask ? exp(k+rope-M)/S : 0  (in place)
__global__ __launch_bounds__(256) void kexp_k(const float* rope, const int* mask,
                                              const float* kM, const float* kS, float* qkv){
  const int total = NROWS*512;
  for (int idx = blockIdx.x*256 + threadIdx.x; idx < total; idx += gridDim.x*256) {
    int row = idx >> 9;
    int hd = idx & 511;
    int b = row >> 11, n = row & (NN-1);
    float* kp = qkv + (size_t)row*1536 + 512 + hd;
    if (mask[row]) {
      float v = *kp + rope[n*64 + (hd & 63)] - kM[b*512 + hd];
      *kp = expf(v) / kS[b*512 + hd];
    } else {
      *kp = 0.0f;
    }
  }
}

__global__ __launch_bounds__(256) void zero_k(float* p, int n){
  int idx = blockIdx.x*256 + threadIdx.x;
  if (idx < n) p[idx] = 0.0f;
}

#define FMA16(a, b, acc) \
  acc[0][0] = fmaf(a.x, b.x, acc[0][0]); acc[0][1] = fmaf(a.x, b.y, acc[0][1]); \
  acc[0][2] = fmaf(a.x, b.z, acc[0][2]); acc[0][3] = fmaf(a.x, b.w, acc[0][3]); \
  acc[1][0] = fmaf(a.y, b.x, acc[1][0]); acc[1][1] = fmaf(a.y, b.y, acc[1][1]); \
  acc[1][2] = fmaf(a.y, b.z, acc[1][2]); acc[1][3] = fmaf(a.y, b.w, acc[1][3]); \
  acc[2][0] = fmaf(a.z, b.x, acc[2][0]); acc[2][1] = fmaf(a.z, b.y, acc[2][1]); \
  acc[2][2] = fmaf(a.z, b.z, acc[2][2]); acc[2][3] = fmaf(a.z, b.w, acc[2][3]); \
  acc[3][0] = fmaf(a.w, b.x, acc[3][0]); acc[3][1] = fmaf(a.w, b.y, acc[3][1]); \
  acc[3][2] = fmaf(a.w, b.z, acc[3][2]); acc[3][3] = fmaf(a.w, b.w, acc[3][3]);

// ctx[bh][d][e] += sum_n ke[n,d]*v[n,e] over a 256-length n segment (fp32 VALU)
__global__ __launch_bounds__(256) void ctx_k(const float* qkv, float* ctx){
  int bh = blockIdx.x, seg = blockIdx.y;
  int b = bh >> 3, h = bh & 7;
  __shared__ float Ks[32][68], Vs[32][68];
  int tid = threadIdx.x, tx = tid & 15, ty = tid >> 4;
  float acc[4][4] = {{0.f,0.f,0.f,0.f},{0.f,0.f,0.f,0.f},{0.f,0.f,0.f,0.f},{0.f,0.f,0.f,0.f}};
  const float* basep = qkv + (size_t)(b*NN + seg*256)*1536 + h*64;
  int nl = tid >> 3, col = (tid & 7)*8;
  for (int nc = 0; nc < 256; nc += 32) {
    const float* kp = basep + (size_t)(nc + nl)*1536 + 512 + col;
    const float* vp = basep + (size_t)(nc + nl)*1536 + 1024 + col;
    float4 a0 = *(const float4*)kp, a1 = *(const float4*)(kp+4);
    float4 b0 = *(const float4*)vp, b1 = *(const float4*)(vp+4);
    *(float4*)&Ks[nl][col]   = a0; *(float4*)&Ks[nl][col+4] = a1;
    *(float4*)&Vs[nl][col]   = b0; *(float4*)&Vs[nl][col+4] = b1;
    __syncthreads();
    #pragma unroll
    for (int q = 0; q < 32; q++) {
      float4 a = *(const float4*)&Ks[q][ty*4];
      float4 b = *(const float4*)&Vs[q][tx*4];
      FMA16(a, b, acc)
    }
    __syncthreads();
  }
  float* cp = ctx + (size_t)bh*4096;
  #pragma unroll
  for (int i = 0; i < 4; i++)
    #pragma unroll
    for (int j = 0; j < 4; j++)
      atomicAdd(&cp[(ty*4 + i)*64 + tx*4 + j], acc[i][j]);
}

// inner[row][h*64+e] = sum_d q[row][h*64+d] * ctx[b,h][d][e]  -> bf16
__global__ __launch_bounds__(512) void inner_k(const float* qkv, const float* ctx, u16* inner){
  int row = blockIdx.x;
  int b = row >> 11;
  __shared__ float qs[512];
  int tid = threadIdx.x;
  qs[tid] = qkv[(size_t)row*1536 + tid];
  __syncthreads();
  int h = tid >> 6, e = tid & 63;
  const float* cp = ctx + (size_t)(b*8 + h)*4096 + e;
  const float* qh = &qs[h*64];
  float s = 0.0f;
  #pragma unroll
  for (int d2 = 0; d2 < 64; d2++) s = fmaf(qh[d2], cp[d2*64], s);
  inner[(size_t)row*512 + tid] = f2bf(s);
}

// cpad[b][t'][c] bf16, t' in [0,2088): masked attn, zero-padded 20 both sides
__global__ __launch_bounds__(256) void cpad_k(const float* attn, const int* mask, u16* cpad){
  const int total = BB*2088*512;
  for (int idx = blockIdx.x*256 + threadIdx.x; idx < total; idx += gridDim.x*256) {
    int c = idx & 511;
    int t = (idx >> 9) % 2088;
    int b = idx / (2088*512);
    int pos = t - 20;
    float v = 0.0f;
    if (pos >= 0 && pos < NN && mask[b*NN + pos]) v = attn[((size_t)b*NN + pos)*512 + c];
    cpad[idx] = f2bf(v);
  }
}

__device__ __forceinline__ float block_sum512(float v, float* red){
  #pragma unroll
  for (int o = 32; o; o >>= 1) v += __shfl_xor(v, o, 64);
  int w = threadIdx.x >> 6;
  if ((threadIdx.x & 63) == 0) red[w] = v;
  __syncthreads();
  float t = red[0] + red[1] + red[2] + red[3];
  __syncthreads();
  return t;
}

// LN over 512; OM=1: bf16 out; OM=2: flags[0]? fp32 : bf16
template<bool ADD, int OM>
__global__ __launch_bounds__(256) void ln_k(const float* X, const float* Y,
                                            const float* g, const float* be,
                                            const int* flags, void* out){
  __shared__ float red[4];
  size_t row = blockIdx.x;
  int tid = threadIdx.x;
  const float* xp = X + row*512;
  float x0 = xp[tid], x1 = xp[tid + 256];
  if (ADD) { const float* yp = Y + row*512; x0 += yp[tid]; x1 += yp[tid + 256]; }
  float mean = block_sum512(x0 + x1, red) * (1.0f/512.0f);
  float d0 = x0 - mean, d1 = x1 - mean;
  float var = block_sum512(d0*d0 + d1*d1, red) * (1.0f/512.0f);
  float inv = rsqrtf(var + 1e-5f);
  float r0 = d0*inv*g[tid]       + be[tid];
  float r1 = d1*inv*g[tid + 256] + be[tid + 256];
  bool obf = (OM == 1) || (OM == 2 && !flags[0]);
  if (obf) {
    u16* op = (u16*)out;
    op[row*512 + tid]       = f2bf(r0);
    op[row*512 + tid + 256] = f2bf(r1);
  } else {
    float* op = (float*)out;
    op[row*512 + tid]       = r0;
    op[row*512 + tid + 256] = r1;
  }
}

extern "C" void kernel_launch(void* const* d_in, const int* in_sizes, int n_in,
                              void* d_out, int out_size, void* d_ws, size_t ws_size,
                              hipStream_t stream) {
  const void* tokens   = d_in[0];
  const void* mask     = d_in[1];
  const void* w_qkv    = d_in[2];
  const void* w_out    = d_in[3];
  const void* b_out    = d_in[4];
  const void* w_narrow = d_in[5];
  const void* b_narrow = d_in[6];
  const void* w_wide   = d_in[7];
  const void* b_wide   = d_in[8];
  const void* ln1_g    = d_in[9];
  const void* ln1_b    = d_in[10];
  const void* ff_w     = d_in[11];
  const void* ff_b     = d_in[12];
  const void* ln2_g    = d_in[13];
  const void* ln2_b    = d_in[14];

  float* ws = (float*)d_ws;
  int*   flags  = (int*)ws;                    // 16
  int*   m32    = (int*)(ws + 16);             // 8192 -> 8208
  float* params = ws + 8208;                   // 4096 -> 12304
  float* kredM  = ws + 12304;                  // 16384 -> 28688
  float* kredS  = ws + 28688;                  // 16384 -> 45072
  float* kM     = ws + 45072;                  // 2048 -> 47120
  float* kS     = ws + 47120;                  // 2048 -> 49168
  float* ctx    = ws + 49168;                  // 131072 -> 180240
  float* rope   = ws + 180240;                 // 131072 -> 311312
  u16*   tokbf  = (u16*)(ws + 311312);         // 4194304 u16 -> 2408464
  u16*   wqkvt  = (u16*)(ws + 2408464);        // 786432 u16 -> 2801680
  u16*   woutt  = (u16*)(ws + 2801680);        // 262144 u16 -> 2932752
  u16*   ffwt   = (u16*)(ws + 2932752);        // 262144 u16 -> 3063824
  u16*   wtN2   = (u16*)(ws + 3063824);        // 2359296 u16 -> 4243472
  u16*   wtW2   = (u16*)(ws + 4243472);        // 2359296 u16 -> 5423120
  float* qkv    = ws + 5423120;                // 12582912 -> 18006032
  float* attn   = ws + 18006032;               // 4194304 -> 22200336 (~89 MB)
  // overlays
  float* Ebuf   = qkv;                         // after qkv dead
  float* Dbuf   = qkv + 4194304;
  u16*   cpadb  = (u16*)(qkv + 8388608);       // 4276224 u16
  u16*   innerb = tokbf;                       // tokens dead after qkv gemm
  u16*   t1b    = tokbf;                       // inner dead after w_out gemm

  float* p_bout = params;        float* p_bnar = params + 512;
  float* p_bwid = params + 1024; float* p_l1g  = params + 1536;
  float* p_l1b  = params + 2048; float* p_ffb  = params + 2560;
  float* p_l2g  = params + 3072; float* p_l2b  = params + 3584;

  sniff_k<<<dim3(1), dim3(256), 0, stream>>>((const u16*)tokens, (const unsigned int*)mask, flags);
  maskconv_k<<<dim3(32), dim3(256), 0, stream>>>(mask, flags, m32);
  bfcopy_k<<<dim3(2048), dim3(256), 0, stream>>>(tokens, flags, tokbf, NROWS*512);
  btrans_k<<<dim3(1024), dim3(256), 0, stream>>>(w_qkv, flags, wqkvt, 512, 1536);
  btrans_k<<<dim3(512), dim3(256), 0, stream>>>(w_out, flags, woutt, 512, 512);
  btrans_k<<<dim3(512), dim3(256), 0, stream>>>(ff_w, flags, ffwt, 512, 512);
  wtrans2_k<<<dim3(1152), dim3(256), 0, stream>>>(w_narrow, flags, wtN2);
  wtrans2_k<<<dim3(1152), dim3(256), 0, stream>>>(w_wide, flags, wtW2);
  fconv_k<<<dim3(2), dim3(256), 0, stream>>>(b_out, flags, p_bout, 512);
  fconv_k<<<dim3(2), dim3(256), 0, stream>>>(b_narrow, flags, p_bnar, 512);
  fconv_k<<<dim3(2), dim3(256), 0, stream>>>(b_wide, flags, p_bwid, 512);
  fconv_k<<<dim3(2), dim3(256), 0, stream>>>(ln1_g, flags, p_l1g, 512);
  fconv_k<<<dim3(2), dim3(256), 0, stream>>>(ln1_b, flags, p_l1b, 512);
  fconv_k<<<dim3(2), dim3(256), 0, stream>>>(ff_b, flags, p_ffb, 512);
  fconv_k<<<dim3(2), dim3(256), 0, stream>>>(ln2_g, flags, p_l2g, 512);
  fconv_k<<<dim3(2), dim3(256), 0, stream>>>(ln2_b, flags, p_l2b, 512);
  rope_k<<<dim3(2048), dim3(64), 0, stream>>>(rope);

  // qkv = tokens @ w_qkv  (8192 x 1536, K=512), MFMA
  mgemm_k<false,false><<<dim3(12, 64), dim3(256), 0, stream>>>(
      tokbf, wqkvt, nullptr, qkv, NROWS, 1536, 512);

  qv_k<<<dim3(NROWS), dim3(512), 0, stream>>>(rope, m32, qkv);
  kstat1_k<<<dim3(32, 8), dim3(256), 0, stream>>>(qkv, rope, m32, kredM, kredS);
  kstat2_k<<<dim3(32), dim3(64), 0, stream>>>(kredM, kredS, kM, kS);
  kexp_k<<<dim3(4096), dim3(256), 0, stream>>>(rope, m32, kM, kS, qkv);

  zero_k<<<dim3(512), dim3(256), 0, stream>>>(ctx, 131072);
  ctx_k<<<dim3(32, 8), dim3(256), 0, stream>>>(qkv, ctx);
  inner_k<<<dim3(NROWS), dim3(512), 0, stream>>>(qkv, ctx, innerb);

  // attn = inner @ w_out + b_out  (8192 x 512, K=512), MFMA
  mgemm_k<true,false><<<dim3(4, 64), dim3(256), 0, stream>>>(
      innerb, woutt, p_bout, attn, NROWS, 512, 512);

  // conv path (qkv region dead now)
  cpad_k<<<dim3(4176), dim3(256), 0, stream>>>(attn, m32, cpadb);
  mconv_k<<<dim3(4, 16, 4), dim3(256), 0, stream>>>(cpadb, wtN2, p_bnar, Dbuf, 1, 16, 0);
  mconv_k<<<dim3(4, 16, 4), dim3(256), 0, stream>>>(cpadb, wtW2, p_bwid, Dbuf, 5, 0, 1);

  // t1 = LN(attn + Dbuf) -> bf16
  ln_k<true,1><<<dim3(NROWS), dim3(256), 0, stream>>>(attn, Dbuf, p_l1g, p_l1b, flags, (void*)t1b);

  // E = gelu(t1 @ ff_w + ff_b), MFMA
  mgemm_k<true,true><<<dim3(4, 64), dim3(256), 0, stream>>>(
      t1b, ffwt, p_ffb, Ebuf, NROWS, 512, 512);

  // out = LN(E) -> d_out, dtype per flags
  ln_k<false,2><<<dim3(NROWS), dim3(256), 0, stream>>>(Ebuf, nullptr, p_l2g, p_l2b, flags, d_out);
}

// Round 4
// 496.764 us; speedup vs baseline: 3.9667x; 1.3220x over previous
//
#include <hip/hip_runtime.h>
#include <hip/hip_bf16.h>

#define BB 4
#define NN 2048
#define NROWS (BB*NN)   // 8192

typedef unsigned short u16;
typedef __bf16 bf16x8 __attribute__((ext_vector_type(8)));
typedef u16    u16x8  __attribute__((ext_vector_type(8)));
typedef float  fx4    __attribute__((ext_vector_type(4)));

__device__ __forceinline__ float bf2f(u16 u){
  union { float f; unsigned int i; } x; x.i = ((unsigned int)u) << 16; return x.f;
}
__device__ __forceinline__ u16 f2bf(float f){
  union { float f; unsigned int i; } x; x.f = f;
  unsigned int i = x.i;
  i += 0x7fffu + ((i >> 16) & 1u);
  return (u16)(i >> 16);
}
__device__ __forceinline__ float geluf(float x){
  return 0.5f * x * (1.0f + erff(x * 0.70710678118654752f));
}

// flags[0]=1 if float inputs fp32 (else bf16); flags[1]=1 if mask byte-packed
__global__ __launch_bounds__(256) void sniff_k(const u16* tokens, const unsigned int* mask, int* flags){
  __shared__ int s_f32, s_byte;
  if (threadIdx.x == 0) { s_f32 = 0; s_byte = 0; }
  __syncthreads();
  for (int i = threadIdx.x; i < 4096; i += 256) {
    float v = bf2f(tokens[i]);
    if (!(fabsf(v) < 1e10f)) atomicOr(&s_f32, 1);
  }
  for (int i = threadIdx.x; i < 2048; i += 256) {
    if (mask[i] > 1u) atomicOr(&s_byte, 1);
  }
  __syncthreads();
  if (threadIdx.x == 0) { flags[0] = s_f32; flags[1] = s_byte; }
}

__global__ __launch_bounds__(256) void maskconv_k(const void* mask, const int* flags, int* m32){
  int i = blockIdx.x*256 + threadIdx.x;
  if (i < NROWS) {
    int v = flags[1] ? (int)((const unsigned char*)mask)[i] : ((const int*)mask)[i];
    m32[i] = v ? 1 : 0;
  }
}

// all 8 512-element params in one launch; blockIdx.x = param id
__global__ __launch_bounds__(256) void params_k(const void* p0, const void* p1, const void* p2,
                                                const void* p3, const void* p4, const void* p5,
                                                const void* p6, const void* p7,
                                                const int* flags, float* params){
  const void* srcs[8] = {p0,p1,p2,p3,p4,p5,p6,p7};
  const void* s = srcs[blockIdx.x];
  int f = flags[0];
  for (int i = threadIdx.x; i < 512; i += 256)
    params[blockIdx.x*512 + i] = f ? ((const float*)s)[i] : bf2f(((const u16*)s)[i]);
}

// straight copy to bf16
__global__ __launch_bounds__(256) void bfcopy_k(const void* src, const int* flags, u16* dst, int n){
  int f = flags[0];
  for (int i = blockIdx.x*256 + threadIdx.x; i < n; i += gridDim.x*256)
    dst[i] = f ? f2bf(((const float*)src)[i]) : ((const u16*)src)[i];
}

// src [K][N] -> dst [N][K] bf16
__global__ __launch_bounds__(256) void btrans_k(const void* src, const int* flags, u16* dst, int K, int N){
  int f = flags[0];
  int total = K*N;
  for (int idx = blockIdx.x*256 + threadIdx.x; idx < total; idx += gridDim.x*256) {
    int k = idx / N, n = idx - k*N;
    u16 v = f ? f2bf(((const float*)src)[idx]) : ((const u16*)src)[idx];
    dst[(size_t)n*K + k] = v;
  }
}

// w[o][c][kk] -> W2[kk][o][c] bf16
__global__ __launch_bounds__(256) void wtrans2_k(const void* w, const int* flags, u16* dst){
  const int total = 512*512*9;
  int f = flags[0];
  for (int idx = blockIdx.x*256 + threadIdx.x; idx < total; idx += gridDim.x*256) {
    u16 v = f ? f2bf(((const float*)w)[idx]) : ((const u16*)w)[idx];
    int o = idx / 4608;
    int rem = idx - o*4608;
    int c = rem / 9;
    int kk = rem - c*9;
    dst[(size_t)kk*262144 + o*512 + c] = v;
  }
}

// rope[p][j]: j<32 -> sin, j>=32 -> cos
__global__ __launch_bounds__(64) void rope_k(float* rope){
  int p = blockIdx.x, j = threadIdx.x;
  int jj = (j < 32) ? j : j - 32;
  float invf = exp2f(-(float)jj * (13.287712379549449f/32.0f));  // 10000^(-jj/32)
  float prod = (float)p * invf;
  rope[p*64 + j] = (j < 32) ? sinf(prod) : cosf(prod);
}

// ---------------- MFMA bf16 GEMM: C[M,N] = A[M,K] @ Bt[N,K]^T ----------------
template<bool BIAS, bool GELU>
__global__ __launch_bounds__(256) void mgemm_k(const u16* A, const u16* Bt, const float* bias,
                                               float* C, int M, int N, int K){
  __shared__ u16 As[128][40];
  __shared__ u16 Bs[128][40];
  int tid = threadIdx.x;
  int lane = tid & 63;
  int wave = tid >> 6;
  int wm = (wave >> 1) * 64, wn = (wave & 1) * 64;
  int quad = lane >> 4, l16 = lane & 15;
  int m0 = blockIdx.y * 128, n0 = blockIdx.x * 128;
  fx4 acc[4][4] = {};
  int ar = tid >> 2;
  int ac = (tid & 3) * 8;
  for (int k0 = 0; k0 < K; k0 += 32) {
    *(u16x8*)&As[ar][ac]    = *(const u16x8*)&A[(size_t)(m0+ar)*K + k0 + ac];
    *(u16x8*)&As[ar+64][ac] = *(const u16x8*)&A[(size_t)(m0+ar+64)*K + k0 + ac];
    *(u16x8*)&Bs[ar][ac]    = *(const u16x8*)&Bt[(size_t)(n0+ar)*K + k0 + ac];
    *(u16x8*)&Bs[ar+64][ac] = *(const u16x8*)&Bt[(size_t)(n0+ar+64)*K + k0 + ac];
    __syncthreads();
    bf16x8 af[4], bfv[4];
    #pragma unroll
    for (int i = 0; i < 4; i++)
      af[i] = __builtin_bit_cast(bf16x8, *(const u16x8*)&As[wm + i*16 + l16][quad*8]);
    #pragma unroll
    for (int j = 0; j < 4; j++)
      bfv[j] = __builtin_bit_cast(bf16x8, *(const u16x8*)&Bs[wn + j*16 + l16][quad*8]);
    #pragma unroll
    for (int i = 0; i < 4; i++)
      #pragma unroll
      for (int j = 0; j < 4; j++)
        acc[i][j] = __builtin_amdgcn_mfma_f32_16x16x32_bf16(af[i], bfv[j], acc[i][j], 0, 0, 0);
    __syncthreads();
  }
  #pragma unroll
  for (int i = 0; i < 4; i++)
    #pragma unroll
    for (int j = 0; j < 4; j++) {
      int col = n0 + wn + j*16 + l16;
      float bv = BIAS ? bias[col] : 0.0f;
      #pragma unroll
      for (int r = 0; r < 4; r++) {
        int row = m0 + wm + i*16 + quad*4 + r;
        float v = acc[i][j][r] + bv;
        if (GELU) v = geluf(v);
        C[(size_t)row*N + col] = v;
      }
    }
}

// ---- batched attn GEMM: attn[b·2048+m][n] = qb[b] @ W2t[b]^T + b_out; fused masked cpad write ----
__global__ __launch_bounds__(256) void mgemm_attn_k(const u16* qb, const u16* W2t, const float* bias,
                                                    const int* mask, float* attn, u16* cpadb){
  __shared__ u16 As[128][40];
  __shared__ u16 Bs[128][40];
  int tid = threadIdx.x;
  int lane = tid & 63;
  int wave = tid >> 6;
  int wm = (wave >> 1) * 64, wn = (wave & 1) * 64;
  int quad = lane >> 4, l16 = lane & 15;
  int m0 = blockIdx.y * 128, n0 = blockIdx.x * 128, b = blockIdx.z;
  const u16* A  = qb  + (size_t)b*2048*512;
  const u16* Bt = W2t + (size_t)b*262144;
  fx4 acc[4][4] = {};
  int ar = tid >> 2;
  int ac = (tid & 3) * 8;
  for (int k0 = 0; k0 < 512; k0 += 32) {
    *(u16x8*)&As[ar][ac]    = *(const u16x8*)&A[(size_t)(m0+ar)*512 + k0 + ac];
    *(u16x8*)&As[ar+64][ac] = *(const u16x8*)&A[(size_t)(m0+ar+64)*512 + k0 + ac];
    *(u16x8*)&Bs[ar][ac]    = *(const u16x8*)&Bt[(size_t)(n0+ar)*512 + k0 + ac];
    *(u16x8*)&Bs[ar+64][ac] = *(const u16x8*)&Bt[(size_t)(n0+ar+64)*512 + k0 + ac];
    __syncthreads();
    bf16x8 af[4], bfv[4];
    #pragma unroll
    for (int i = 0; i < 4; i++)
      af[i] = __builtin_bit_cast(bf16x8, *(const u16x8*)&As[wm + i*16 + l16][quad*8]);
    #pragma unroll
    for (int j = 0; j < 4; j++)
      bfv[j] = __builtin_bit_cast(bf16x8, *(const u16x8*)&Bs[wn + j*16 + l16][quad*8]);
    #pragma unroll
    for (int i = 0; i < 4; i++)
      #pragma unroll
      for (int j = 0; j < 4; j++)
        acc[i][j] = __builtin_amdgcn_mfma_f32_16x16x32_bf16(af[i], bfv[j], acc[i][j], 0, 0, 0);
    __syncthreads();
  }
  #pragma unroll
  for (int i = 0; i < 4; i++)
    #pragma unroll
    for (int j = 0; j < 4; j++) {
      int col = n0 + wn + j*16 + l16;
      float bv = bias[col];
      #pragma unroll
      for (int r = 0; r < 4; r++) {
        int row_l = m0 + wm + i*16 + quad*4 + r;
        float v = acc[i][j][r] + bv;
        attn[((size_t)b*2048 + row_l)*512 + col] = v;
        int mk = mask[b*2048 + row_l];
        cpadb[((size_t)b*2088 + row_l + 20)*512 + col] = mk ? f2bf(v) : (u16)0;
      }
    }
}

// zero cpad edge rows t' in [0,20) and [2068,2088)
__global__ __launch_bounds__(256) void cpz_k(u16* cpadb){
  int idx = blockIdx.x*256 + threadIdx.x;
  if (idx < BB*40*512) {
    int c = idx & 511;
    int t = (idx >> 9) % 40;
    int b = idx / (40*512);
    int tt = (t < 20) ? t : 2048 + t;
    cpadb[((size_t)b*2088 + tt)*512 + c] = 0;
  }
}

// ---- merged conv: D = gelu(narrow)+gelu(wide), 128x128 tile, A staged once/chunk, W dbuf ----
__global__ __launch_bounds__(256, 2) void mconv2_k(const u16* cpad, const u16* Wn, const u16* Ww,
                                                   const float* bias_n, const float* bias_w,
                                                   float* D){
  __shared__ u16 As[168][72];
  __shared__ u16 Ws[2][128][72];
  int tid = threadIdx.x;
  int lane = tid & 63;
  int wave = tid >> 6;
  int wm = (wave >> 1) * 64, wn = (wave & 1) * 64;
  int quad = lane >> 4, l16 = lane & 15;
  int o0 = blockIdx.x * 128, m0 = blockIdx.y * 128, b = blockIdx.z;
  fx4 accN[4][4] = {}, accW[4][4] = {};
  const u16* cb = cpad + ((size_t)b*2088 + m0)*512;
  for (int c0 = 0; c0 < 512; c0 += 64) {
    // stage A: 168 rows x 64 u16 (covers wide span; narrow uses rows 16..151)
    for (int idx = tid; idx < 168*8; idx += 256) {
      int r = idx >> 3, off = (idx & 7)*8;
      *(u16x8*)&As[r][off] = *(const u16x8*)&cb[(size_t)r*512 + c0 + off];
    }
    // stage pair 0 (narrow tap 0) into buf 0
    {
      const u16* wp = Wn + (size_t)o0*512 + c0;
      #pragma unroll
      for (int u = 0; u < 4; u++) {
        int idx = tid + u*256;
        int r = idx >> 3, off = (idx & 7)*8;
        *(u16x8*)&Ws[0][r][off] = *(const u16x8*)&wp[(size_t)r*512 + off];
      }
    }
    __syncthreads();
    #pragma unroll
    for (int p = 0; p < 18; p++) {
      // prefetch next pair's weights to regs (overlaps with MFMA below)
      u16x8 pre[4];
      if (p < 17) {
        int np = p + 1;
        int kk = np >> 1;
        const u16* wsrc = (np & 1) ? Ww : Wn;
        const u16* wp = wsrc + (size_t)kk*262144 + (size_t)o0*512 + c0;
        #pragma unroll
        for (int u = 0; u < 4; u++) {
          int idx = tid + u*256;
          int r = idx >> 3, off = (idx & 7)*8;
          pre[u] = *(const u16x8*)&wp[(size_t)r*512 + off];
        }
      }
      int kk = p >> 1;
      int buf = p & 1;
      int shift = (p & 1) ? 5*kk : 16 + kk;
      #pragma unroll
      for (int ks = 0; ks < 2; ks++) {
        bf16x8 bfv[4];
        #pragma unroll
        for (int j = 0; j < 4; j++)
          bfv[j] = __builtin_bit_cast(bf16x8, *(const u16x8*)&Ws[buf][wn + j*16 + l16][ks*32 + quad*8]);
        if (p & 1) {
          #pragma unroll
          for (int i = 0; i < 4; i++) {
            bf16x8 afr = __builtin_bit_cast(bf16x8, *(const u16x8*)&As[shift + wm + i*16 + l16][ks*32 + quad*8]);
            #pragma unroll
            for (int j = 0; j < 4; j++)
              accW[i][j] = __builtin_amdgcn_mfma_f32_16x16x32_bf16(afr, bfv[j], accW[i][j], 0, 0, 0);
          }
        } else {
          #pragma unroll
          for (int i = 0; i < 4; i++) {
            bf16x8 afr = __builtin_bit_cast(bf16x8, *(const u16x8*)&As[shift + wm + i*16 + l16][ks*32 + quad*8]);
            #pragma unroll
            for (int j = 0; j < 4; j++)
              accN[i][j] = __builtin_amdgcn_mfma_f32_16x16x32_bf16(afr, bfv[j], accN[i][j], 0, 0, 0);
          }
        }
      }
      // write prefetched weights into the other buffer (its last readers finished pair p-1)
      if (p < 17) {
        #pragma unroll
        for (int u = 0; u < 4; u++) {
          int idx = tid + u*256;
          int r = idx >> 3, off = (idx & 7)*8;
          *(u16x8*)&Ws[buf ^ 1][r][off] = pre[u];
        }
      }
      __syncthreads();
    }
  }
  #pragma unroll
  for (int i = 0; i < 4; i++)
    #pragma unroll
    for (int j = 0; j < 4; j++) {
      int col = o0 + wn + j*16 + l16;
      float bn = bias_n[col], bw = bias_w[col];
      #pragma unroll
      for (int r = 0; r < 4; r++) {
        int row = b*2048 + m0 + wm + i*16 + quad*4 + r;
        float v = geluf(accN[i][j][r] + bn) + geluf(accW[i][j][r] + bw);
        D[(size_t)row*512 + col] = v;
      }
    }
}

// per-(b,n): qb = bf16(softmax(q+rope over d)*0.125); v *= mask in place
__global__ __launch_bounds__(512) void qv_k(const float* rope, const int* mask, float* qkv, u16* qb){
  int row = blockIdx.x;
  int n = row & (NN-1);
  int tid = threadIdx.x;
  int d = tid & 63;
  float* qp = qkv + (size_t)row*1536;
  float v = qp[tid] + rope[n*64 + d];
  float m = v;
  #pragma unroll
  for (int o = 32; o; o >>= 1) m = fmaxf(m, __shfl_xor(m, o, 64));
  float e = expf(v - m);
  float s = e;
  #pragma unroll
  for (int o = 32; o; o >>= 1) s += __shfl_xor(s, o, 64);
  qb[(size_t)row*512 + tid] = f2bf(e * (0.125f / s));
  float mk = mask[row] ? 1.0f : 0.0f;
  qp[1024 + tid] *= mk;
}

// segmented k-softmax stats: per (b,h), segment of 256 rows
__global__ __launch_bounds__(256) void kstat1_k(const float* qkv, const float* rope,
                                                const int* mask, float* kredM, float* kredS){
  int bh = blockIdx.x, seg = blockIdx.y;
  int b = bh >> 3, h = bh & 7;
  int tid = threadIdx.x;
  int d = tid & 63, g = tid >> 6;
  __shared__ float red[4][64];
  const float* kp = qkv + (size_t)b*NN*1536 + 512 + h*64 + d;
  const int* mp = mask + b*NN;
  int nbase = seg*256 + g*64;
  float m = -3.0e38f;
  for (int n = nbase; n < nbase+64; n++)
    if (mp[n]) m = fmaxf(m, kp[(size_t)n*1536] + rope[n*64 + d]);
  red[g][d] = m;
  __syncthreads();
  float M = fmaxf(fmaxf(red[0][d], red[1][d]), fmaxf(red[2][d], red[3][d]));
  __syncthreads();
  float s = 0.0f;
  if (M > -1e38f) {
    for (int n = nbase; n < nbase+64; n++)
      if (mp[n]) s += expf(kp[(size_t)n*1536] + rope[n*64 + d] - M);
  }
  red[g][d] = s;
  __syncthreads();
  if (g == 0) {
    int o = (bh*8 + seg)*64 + d;
    kredM[o] = M;
    kredS[o] = red[0][d] + red[1][d] + red[2][d] + red[3][d];
  }
}

__global__ __launch_bounds__(64) void kstat2_k(const float* kredM, const float* kredS,
                                               float* kM, float* kS){
  int bh = blockIdx.x, d = threadIdx.x;
  float M = -3.0e38f;
  for (int s = 0; s < 8; s++) M = fmaxf(M, kredM[(bh*8 + s)*64 + d]);
  float S = 0.0f;
  for (int s = 0; s < 8; s++) {
    float ms = kredM[(bh*8 + s)*64 + d];
    if (ms > -1e38f) S += kredS[(bh*8 + s)*64 + d] * expf(ms - M);
  }
  kM[bh*64 + d] = M;
  kS[bh*64 + d] = (S > 0.0f) ? S : 1.0f;
}

// k <- mask ? exp(k+rope-M)/S : 0  (in place)
__global__ __launch_bounds__(256) void kexp_k(const float* rope, const int* mask,
                                              const float* kM, const float* kS, float* qkv){
  const int total = NROWS*512;
  for (int idx = blockIdx.x*256 + threadIdx.x; idx < total; idx += gridDim.x*256) {
    int row = idx >> 9;
    int hd = idx & 511;
    int b = row >> 11, n = row & (NN-1);
    float* kp = qkv + (size_t)row*1536 + 512 + hd;
    if (mask[row]) {
      float v = *kp + rope[n*64 + (hd & 63)] - kM[b*512 + hd];
      *kp = expf(v) / kS[b*512 + hd];
    } else {
      *kp = 0.0f;
    }
  }
}

__global__ __launch_bounds__(256) void zero_k(float* p, int n){
  int idx = blockIdx.x*256 + threadIdx.x;
  if (idx < n) p[idx] = 0.0f;
}

#define FMA16(a, b, acc) \
  acc[0][0] = fmaf(a.x, b.x, acc[0][0]); acc[0][1] = fmaf(a.x, b.y, acc[0][1]); \
  acc[0][2] = fmaf(a.x, b.z, acc[0][2]); acc[0][3] = fmaf(a.x, b.w, acc[0][3]); \
  acc[1][0] = fmaf(a.y, b.x, acc[1][0]); acc[1][1] = fmaf(a.y, b.y, acc[1][1]); \
  acc[1][2] = fmaf(a.y, b.z, acc[1][2]); acc[1][3] = fmaf(a.y, b.w, acc[1][3]); \
  acc[2][0] = fmaf(a.z, b.x, acc[2][0]); acc[2][1] = fmaf(a.z, b.y, acc[2][1]); \
  acc[2][2] = fmaf(a.z, b.z, acc[2][2]); acc[2][3] = fmaf(a.z, b.w, acc[2][3]); \
  acc[3][0] = fmaf(a.w, b.x, acc[3][0]); acc[3][1] = fmaf(a.w, b.y, acc[3][1]); \
  acc[3][2] = fmaf(a.w, b.z, acc[3][2]); acc[3][3] = fmaf(a.w, b.w, acc[3][3]);

// ctx[bh][d][e] += sum_n ke[n,d]*v[n,e] over a 256-length n segment (fp32 VALU)
__global__ __launch_bounds__(256) void ctx_k(const float* qkv, float* ctx){
  int bh = blockIdx.x, seg = blockIdx.y;
  int b = bh >> 3, h = bh & 7;
  __shared__ float Ks[32][68], Vs[32][68];
  int tid = threadIdx.x, tx = tid & 15, ty = tid >> 4;
  float acc[4][4] = {{0.f,0.f,0.f,0.f},{0.f,0.f,0.f,0.f},{0.f,0.f,0.f,0.f},{0.f,0.f,0.f,0.f}};
  const float* basep = qkv + (size_t)(b*NN + seg*256)*1536 + h*64;
  int nl = tid >> 3, col = (tid & 7)*8;
  for (int nc = 0; nc < 256; nc += 32) {
    const float* kp = basep + (size_t)(nc + nl)*1536 + 512 + col;
    const float* vp = basep + (size_t)(nc + nl)*1536 + 1024 + col;
    float4 a0 = *(const float4*)kp, a1 = *(const float4*)(kp+4);
    float4 b0 = *(const float4*)vp, b1 = *(const float4*)(vp+4);
    *(float4*)&Ks[nl][col]   = a0; *(float4*)&Ks[nl][col+4] = a1;
    *(float4*)&Vs[nl][col]   = b0; *(float4*)&Vs[nl][col+4] = b1;
    __syncthreads();
    #pragma unroll
    for (int q = 0; q < 32; q++) {
      float4 a = *(const float4*)&Ks[q][ty*4];
      float4 b = *(const float4*)&Vs[q][tx*4];
      FMA16(a, b, acc)
    }
    __syncthreads();
  }
  float* cp = ctx + (size_t)bh*4096;
  #pragma unroll
  for (int i = 0; i < 4; i++)
    #pragma unroll
    for (int j = 0; j < 4; j++)
      atomicAdd(&cp[(ty*4 + i)*64 + tx*4 + j], acc[i][j]);
}

// W2t[b][o][h*64+d] = sum_e ctx[b,h][d][e] * woutt[o][h*64+e]   (bf16 out)
// grid (h, b); 4 waves; wave w handles o rows [w*128, w*128+128)
__global__ __launch_bounds__(256, 2) void ctxw_k(const float* ctx, const u16* woutt, u16* W2t){
  int h = blockIdx.x, b = blockIdx.y;
  int tid = threadIdx.x;
  int lane = tid & 63, wave = tid >> 6;
  int quad = lane >> 4, l16 = lane & 15;
  const float* cp = ctx + (size_t)(b*8 + h)*4096;
  fx4 acc[8][4] = {};
  #pragma unroll
  for (int ks = 0; ks < 2; ks++) {
    bf16x8 bfv[4];
    #pragma unroll
    for (int j = 0; j < 4; j++) {
      const float* src = cp + (j*16 + l16)*64 + ks*32 + quad*8;
      float4 v0 = *(const float4*)src, v1 = *(const float4*)(src + 4);
      bf16x8 t;
      t[0]=(__bf16)v0.x; t[1]=(__bf16)v0.y; t[2]=(__bf16)v0.z; t[3]=(__bf16)v0.w;
      t[4]=(__bf16)v1.x; t[5]=(__bf16)v1.y; t[6]=(__bf16)v1.z; t[7]=(__bf16)v1.w;
      bfv[j] = t;
    }
    #pragma unroll
    for (int i = 0; i < 8; i++) {
      int orow = wave*128 + i*16 + l16;
      bf16x8 afr = __builtin_bit_cast(bf16x8, *(const u16x8*)&woutt[(size_t)orow*512 + h*64 + ks*32 + quad*8]);
      #pragma unroll
      for (int j = 0; j < 4; j++)
        acc[i][j] = __builtin_amdgcn_mfma_f32_16x16x32_bf16(afr, bfv[j], acc[i][j], 0, 0, 0);
    }
  }
  u16* out = W2t + (size_t)b*262144;
  #pragma unroll
  for (int i = 0; i < 8; i++)
    #pragma unroll
    for (int j = 0; j < 4; j++)
      #pragma unroll
      for (int r = 0; r < 4; r++) {
        int orow = wave*128 + i*16 + quad*4 + r;
        out[(size_t)orow*512 + h*64 + j*16 + l16] = f2bf(acc[i][j][r]);
      }
}

__device__ __forceinline__ float block_sum512(float v, float* red){
  #pragma unroll
  for (int o = 32; o; o >>= 1) v += __shfl_xor(v, o, 64);
  int w = threadIdx.x >> 6;
  if ((threadIdx.x & 63) == 0) red[w] = v;
  __syncthreads();
  float t = red[0] + red[1] + red[2] + red[3];
  __syncthreads();
  return t;
}

// LN over 512; OM=1: bf16 out; OM=2: flags[0]? fp32 : bf16
template<bool ADD, int OM>
__global__ __launch_bounds__(256) void ln_k(const float* X, const float* Y,
                                            const float* g, const float* be,
                                            const int* flags, void* out){
  __shared__ float red[4];
  size_t row = blockIdx.x;
  int tid = threadIdx.x;
  const float* xp = X + row*512;
  float x0 = xp[tid], x1 = xp[tid + 256];
  if (ADD) { const float* yp = Y + row*512; x0 += yp[tid]; x1 += yp[tid + 256]; }
  float mean = block_sum512(x0 + x1, red) * (1.0f/512.0f);
  float d0 = x0 - mean, d1 = x1 - mean;
  float var = block_sum512(d0*d0 + d1*d1, red) * (1.0f/512.0f);
  float inv = rsqrtf(var + 1e-5f);
  float r0 = d0*inv*g[tid]       + be[tid];
  float r1 = d1*inv*g[tid + 256] + be[tid + 256];
  bool obf = (OM == 1) || (OM == 2 && !flags[0]);
  if (obf) {
    u16* op = (u16*)out;
    op[row*512 + tid]       = f2bf(r0);
    op[row*512 + tid + 256] = f2bf(r1);
  } else {
    float* op = (float*)out;
    op[row*512 + tid]       = r0;
    op[row*512 + tid + 256] = r1;
  }
}

extern "C" void kernel_launch(void* const* d_in, const int* in_sizes, int n_in,
                              void* d_out, int out_size, void* d_ws, size_t ws_size,
                              hipStream_t stream) {
  const void* tokens   = d_in[0];
  const void* mask     = d_in[1];
  const void* w_qkv    = d_in[2];
  const void* w_out    = d_in[3];
  const void* b_out    = d_in[4];
  const void* w_narrow = d_in[5];
  const void* b_narrow = d_in[6];
  const void* w_wide   = d_in[7];
  const void* b_wide   = d_in[8];
  const void* ln1_g    = d_in[9];
  const void* ln1_b    = d_in[10];
  const void* ff_w     = d_in[11];
  const void* ff_b     = d_in[12];
  const void* ln2_g    = d_in[13];
  const void* ln2_b    = d_in[14];

  float* ws = (float*)d_ws;
  int*   flags  = (int*)ws;                    // 16
  int*   m32    = (int*)(ws + 16);             // 8192 -> 8208
  float* params = ws + 8208;                   // 4096 -> 12304
  float* kredM  = ws + 12304;                  // 16384 -> 28688
  float* kredS  = ws + 28688;                  // 16384 -> 45072
  float* kM     = ws + 45072;                  // 2048 -> 47120
  float* kS     = ws + 47120;                  // 2048 -> 49168
  float* ctx    = ws + 49168;                  // 131072 -> 180240
  float* rope   = ws + 180240;                 // 131072 -> 311312
  u16*   tokbf  = (u16*)(ws + 311312);         // 4194304 u16 -> 2408464
  u16*   wqkvt  = (u16*)(ws + 2408464);        // 786432 u16 -> 2801680
  u16*   woutt  = (u16*)(ws + 2801680);        // 262144 u16 -> 2932752
  u16*   ffwt   = (u16*)(ws + 2932752);        // 262144 u16 -> 3063824
  u16*   wtN2   = (u16*)(ws + 3063824);        // 2359296 u16 -> 4243472
  u16*   wtW2   = (u16*)(ws + 4243472);        // 2359296 u16 -> 5423120
  u16*   qb     = (u16*)(ws + 5423120);        // 4194304 u16 -> 7520272
  u16*   W2t    = (u16*)(ws + 7520272);        // 1048576 u16 -> 8044560
  float* qkv    = ws + 8044560;                // 12582912 -> 20627472
  float* attn   = ws + 20627472;               // 4194304 -> 24821776 (~99.3 MB)
  // overlays inside qkv region (k/v dead after ctx_k)
  u16*   cpadb  = (u16*)qkv;                   // 4276224 u16 = 2138112 fl
  float* Dbuf   = qkv + 2138112;               // 4194304 fl -> 6332416
  float* Ebuf   = qkv + 6332416;               // 4194304 fl -> 10526720 (< 12582912)
  u16*   t1b    = tokbf;                       // tokens dead after qkv gemm

  float* p_bout = params;        float* p_bnar = params + 512;
  float* p_bwid = params + 1024; float* p_l1g  = params + 1536;
  float* p_l1b  = params + 2048; float* p_ffb  = params + 2560;
  float* p_l2g  = params + 3072; float* p_l2b  = params + 3584;

  sniff_k<<<dim3(1), dim3(256), 0, stream>>>((const u16*)tokens, (const unsigned int*)mask, flags);
  maskconv_k<<<dim3(32), dim3(256), 0, stream>>>(mask, flags, m32);
  params_k<<<dim3(8), dim3(256), 0, stream>>>(b_out, b_narrow, b_wide, ln1_g, ln1_b, ff_b, ln2_g, ln2_b,
                                              flags, params);
  bfcopy_k<<<dim3(2048), dim3(256), 0, stream>>>(tokens, flags, tokbf, NROWS*512);
  btrans_k<<<dim3(1024), dim3(256), 0, stream>>>(w_qkv, flags, wqkvt, 512, 1536);
  btrans_k<<<dim3(512), dim3(256), 0, stream>>>(w_out, flags, woutt, 512, 512);
  btrans_k<<<dim3(512), dim3(256), 0, stream>>>(ff_w, flags, ffwt, 512, 512);
  wtrans2_k<<<dim3(1152), dim3(256), 0, stream>>>(w_narrow, flags, wtN2);
  wtrans2_k<<<dim3(1152), dim3(256), 0, stream>>>(w_wide, flags, wtW2);
  rope_k<<<dim3(2048), dim3(64), 0, stream>>>(rope);

  // qkv = tokens @ w_qkv  (8192 x 1536, K=512)
  mgemm_k<false,false><<<dim3(12, 64), dim3(256), 0, stream>>>(
      tokbf, wqkvt, nullptr, qkv, NROWS, 1536, 512);

  qv_k<<<dim3(NROWS), dim3(512), 0, stream>>>(rope, m32, qkv, qb);
  kstat1_k<<<dim3(32, 8), dim3(256), 0, stream>>>(qkv, rope, m32, kredM, kredS);
  kstat2_k<<<dim3(32), dim3(64), 0, stream>>>(kredM, kredS, kM, kS);
  kexp_k<<<dim3(4096), dim3(256), 0, stream>>>(rope, m32, kM, kS, qkv);

  zero_k<<<dim3(512), dim3(256), 0, stream>>>(ctx, 131072);
  ctx_k<<<dim3(32, 8), dim3(256), 0, stream>>>(qkv, ctx);

  // W2t[b] = blockdiag(ctx_b) @ w_out  (absorbs the per-head inner product)
  ctxw_k<<<dim3(8, 4), dim3(256), 0, stream>>>(ctx, woutt, W2t);

  // qkv region dead from here; cpadb/Dbuf/Ebuf overlay it
  cpz_k<<<dim3(320), dim3(256), 0, stream>>>(cpadb);

  // attn = qb @ W2t[b]^T + b_out; fused masked bf16 cpad write
  mgemm_attn_k<<<dim3(4, 16, 4), dim3(256), 0, stream>>>(qb, W2t, p_bout, m32, attn, cpadb);

  // both convs in one pass
  mconv2_k<<<dim3(4, 16, 4), dim3(256), 0, stream>>>(cpadb, wtN2, wtW2, p_bnar, p_bwid, Dbuf);

  // t1 = LN(attn + Dbuf) -> bf16
  ln_k<true,1><<<dim3(NROWS), dim3(256), 0, stream>>>(attn, Dbuf, p_l1g, p_l1b, flags, (void*)t1b);

  // E = gelu(t1 @ ff_w + ff_b)
  mgemm_k<true,true><<<dim3(4, 64), dim3(256), 0, stream>>>(
      t1b, ffwt, p_ffb, Ebuf, NROWS, 512, 512);

  // out = LN(E) -> d_out, dtype per flags
  ln_k<false,2><<<dim3(NROWS), dim3(256), 0, stream>>>(Ebuf, nullptr, p_l2g, p_l2b, flags, d_out);
}

// Round 5
// 412.286 us; speedup vs baseline: 4.7795x; 1.2049x over previous
//
#include <hip/hip_runtime.h>
#include <hip/hip_bf16.h>

#define BB 4
#define NN 2048
#define NROWS (BB*NN)   // 8192

typedef unsigned short u16;
typedef __bf16 bf16x8 __attribute__((ext_vector_type(8)));
typedef u16    u16x8  __attribute__((ext_vector_type(8)));
typedef float  fx4    __attribute__((ext_vector_type(4)));

__device__ __forceinline__ float bf2f(u16 u){
  union { float f; unsigned int i; } x; x.i = ((unsigned int)u) << 16; return x.f;
}
__device__ __forceinline__ u16 f2bf(float f){
  union { float f; unsigned int i; } x; x.f = f;
  unsigned int i = x.i;
  i += 0x7fffu + ((i >> 16) & 1u);
  return (u16)(i >> 16);
}
__device__ __forceinline__ float geluf(float x){
  return 0.5f * x * (1.0f + erff(x * 0.70710678118654752f));
}

// flags[0]=1 if float inputs fp32 (else bf16); flags[1]=1 if mask byte-packed
__global__ __launch_bounds__(256) void sniff_k(const u16* tokens, const unsigned int* mask, int* flags){
  __shared__ int s_f32, s_byte;
  if (threadIdx.x == 0) { s_f32 = 0; s_byte = 0; }
  __syncthreads();
  for (int i = threadIdx.x; i < 4096; i += 256) {
    float v = bf2f(tokens[i]);
    if (!(fabsf(v) < 1e10f)) atomicOr(&s_f32, 1);
  }
  for (int i = threadIdx.x; i < 2048; i += 256) {
    if (mask[i] > 1u) atomicOr(&s_byte, 1);
  }
  __syncthreads();
  if (threadIdx.x == 0) { flags[0] = s_f32; flags[1] = s_byte; }
}

// rope + m32 + params + zero(ctx) in one launch (grid-stride over ranges)
__global__ __launch_bounds__(256) void misc_k(const void* mask,
                                              const void* p0, const void* p1, const void* p2,
                                              const void* p3, const void* p4, const void* p5,
                                              const void* p6, const void* p7,
                                              const int* flags, float* rope, int* m32,
                                              float* params, float* ctx){
  const void* srcs[8] = {p0,p1,p2,p3,p4,p5,p6,p7};
  int f32 = flags[0], mbyte = flags[1];
  const int T = 131072 + 8192 + 4096 + 131072;
  for (int i = blockIdx.x*256 + threadIdx.x; i < T; i += gridDim.x*256) {
    if (i < 131072) {
      int p = i >> 6, j = i & 63;
      int jj = (j < 32) ? j : j - 32;
      float invf = exp2f(-(float)jj * (13.287712379549449f/32.0f));  // 10000^(-jj/32)
      float prod = (float)p * invf;
      rope[i] = (j < 32) ? sinf(prod) : cosf(prod);
    } else if (i < 139264) {
      int k = i - 131072;
      int v = mbyte ? (int)((const unsigned char*)mask)[k] : ((const int*)mask)[k];
      m32[k] = v ? 1 : 0;
    } else if (i < 143360) {
      int k = i - 139264;
      int pid = k >> 9, j = k & 511;
      const void* s = srcs[pid];
      params[k] = f32 ? ((const float*)s)[j] : bf2f(((const u16*)s)[j]);
    } else {
      ctx[i - 143360] = 0.0f;
    }
  }
}

// all big weight transforms + token bf16 copy in one launch
__global__ __launch_bounds__(256) void prep_k(const void* tokens, const void* w_qkv,
                                              const void* w_out, const void* ff_w,
                                              const void* w_narrow, const void* w_wide,
                                              const int* flags,
                                              u16* tokbf, u16* wqkvt, u16* woutt, u16* ffwt,
                                              u16* wtN2, u16* wtW2){
  int f = flags[0];
  const int T = 10223616;
  for (int i = blockIdx.x*256 + threadIdx.x; i < T; i += gridDim.x*256) {
    if (i < 4194304) {
      tokbf[i] = f ? f2bf(((const float*)tokens)[i]) : ((const u16*)tokens)[i];
    } else if (i < 4980736) {
      int k2 = i - 4194304;
      u16 v = f ? f2bf(((const float*)w_qkv)[k2]) : ((const u16*)w_qkv)[k2];
      int k = k2 / 1536, n = k2 - k*1536;
      wqkvt[(size_t)n*512 + k] = v;
    } else if (i < 5242880) {
      int k2 = i - 4980736;
      u16 v = f ? f2bf(((const float*)w_out)[k2]) : ((const u16*)w_out)[k2];
      int k = k2 >> 9, n = k2 & 511;
      woutt[(size_t)n*512 + k] = v;
    } else if (i < 5505024) {
      int k2 = i - 5242880;
      u16 v = f ? f2bf(((const float*)ff_w)[k2]) : ((const u16*)ff_w)[k2];
      int k = k2 >> 9, n = k2 & 511;
      ffwt[(size_t)n*512 + k] = v;
    } else if (i < 7864320) {
      int k2 = i - 5505024;
      u16 v = f ? f2bf(((const float*)w_narrow)[k2]) : ((const u16*)w_narrow)[k2];
      int o = k2 / 4608;
      int rem = k2 - o*4608;
      int c = rem / 9;
      int kk = rem - c*9;
      wtN2[(size_t)kk*262144 + o*512 + c] = v;
    } else {
      int k2 = i - 7864320;
      u16 v = f ? f2bf(((const float*)w_wide)[k2]) : ((const u16*)w_wide)[k2];
      int o = k2 / 4608;
      int rem = k2 - o*4608;
      int c = rem / 9;
      int kk = rem - c*9;
      wtW2[(size_t)kk*262144 + o*512 + c] = v;
    }
  }
}

// ---------------- MFMA bf16 GEMM 128x128: C[M,N] = A[M,K] @ Bt[N,K]^T ----------------
template<bool BIAS, bool GELU>
__global__ __launch_bounds__(256) void mgemm_k(const u16* A, const u16* Bt, const float* bias,
                                               float* C, int M, int N, int K){
  __shared__ u16 As[128][40];
  __shared__ u16 Bs[128][40];
  int tid = threadIdx.x;
  int lane = tid & 63;
  int wave = tid >> 6;
  int wm = (wave >> 1) * 64, wn = (wave & 1) * 64;
  int quad = lane >> 4, l16 = lane & 15;
  int m0 = blockIdx.y * 128, n0 = blockIdx.x * 128;
  fx4 acc[4][4] = {};
  int ar = tid >> 2;
  int ac = (tid & 3) * 8;
  for (int k0 = 0; k0 < K; k0 += 32) {
    *(u16x8*)&As[ar][ac]    = *(const u16x8*)&A[(size_t)(m0+ar)*K + k0 + ac];
    *(u16x8*)&As[ar+64][ac] = *(const u16x8*)&A[(size_t)(m0+ar+64)*K + k0 + ac];
    *(u16x8*)&Bs[ar][ac]    = *(const u16x8*)&Bt[(size_t)(n0+ar)*K + k0 + ac];
    *(u16x8*)&Bs[ar+64][ac] = *(const u16x8*)&Bt[(size_t)(n0+ar+64)*K + k0 + ac];
    __syncthreads();
    bf16x8 af[4], bfv[4];
    #pragma unroll
    for (int i = 0; i < 4; i++)
      af[i] = __builtin_bit_cast(bf16x8, *(const u16x8*)&As[wm + i*16 + l16][quad*8]);
    #pragma unroll
    for (int j = 0; j < 4; j++)
      bfv[j] = __builtin_bit_cast(bf16x8, *(const u16x8*)&Bs[wn + j*16 + l16][quad*8]);
    #pragma unroll
    for (int i = 0; i < 4; i++)
      #pragma unroll
      for (int j = 0; j < 4; j++)
        acc[i][j] = __builtin_amdgcn_mfma_f32_16x16x32_bf16(af[i], bfv[j], acc[i][j], 0, 0, 0);
    __syncthreads();
  }
  #pragma unroll
  for (int i = 0; i < 4; i++)
    #pragma unroll
    for (int j = 0; j < 4; j++) {
      int col = n0 + wn + j*16 + l16;
      float bv = BIAS ? bias[col] : 0.0f;
      #pragma unroll
      for (int r = 0; r < 4; r++) {
        int row = m0 + wm + i*16 + quad*4 + r;
        float v = acc[i][j][r] + bv;
        if (GELU) v = geluf(v);
        C[(size_t)row*N + col] = v;
      }
    }
}

// ---------------- MFMA bf16 GEMM, M-tile 64 (grid-doubling variant) ----------------
template<bool BIAS, bool GELU>
__global__ __launch_bounds__(256) void mgemm64_k(const u16* A, const u16* Bt, const float* bias,
                                                 float* C, int M, int N, int K){
  __shared__ u16 As[64][40];
  __shared__ u16 Bs[128][40];
  int tid = threadIdx.x;
  int lane = tid & 63;
  int wave = tid >> 6;
  int wn = wave * 32;
  int quad = lane >> 4, l16 = lane & 15;
  int m0 = blockIdx.y * 64, n0 = blockIdx.x * 128;
  fx4 acc[4][2] = {};
  int ar = tid >> 2;
  int ac = (tid & 3) * 8;
  for (int k0 = 0; k0 < K; k0 += 32) {
    *(u16x8*)&As[ar][ac]    = *(const u16x8*)&A[(size_t)(m0+ar)*K + k0 + ac];
    *(u16x8*)&Bs[ar][ac]    = *(const u16x8*)&Bt[(size_t)(n0+ar)*K + k0 + ac];
    *(u16x8*)&Bs[ar+64][ac] = *(const u16x8*)&Bt[(size_t)(n0+ar+64)*K + k0 + ac];
    __syncthreads();
    bf16x8 af[4], bfv[2];
    #pragma unroll
    for (int i = 0; i < 4; i++)
      af[i] = __builtin_bit_cast(bf16x8, *(const u16x8*)&As[i*16 + l16][quad*8]);
    #pragma unroll
    for (int j = 0; j < 2; j++)
      bfv[j] = __builtin_bit_cast(bf16x8, *(const u16x8*)&Bs[wn + j*16 + l16][quad*8]);
    #pragma unroll
    for (int i = 0; i < 4; i++)
      #pragma unroll
      for (int j = 0; j < 2; j++)
        acc[i][j] = __builtin_amdgcn_mfma_f32_16x16x32_bf16(af[i], bfv[j], acc[i][j], 0, 0, 0);
    __syncthreads();
  }
  #pragma unroll
  for (int i = 0; i < 4; i++)
    #pragma unroll
    for (int j = 0; j < 2; j++) {
      int col = n0 + wn + j*16 + l16;
      float bv = BIAS ? bias[col] : 0.0f;
      #pragma unroll
      for (int r = 0; r < 4; r++) {
        int row = m0 + i*16 + quad*4 + r;
        float v = acc[i][j][r] + bv;
        if (GELU) v = geluf(v);
        C[(size_t)row*N + col] = v;
      }
    }
}

// ---- batched attn GEMM (M-tile 64): attn = qb[b] @ W2t[b]^T + b_out; fused masked cpad ----
__global__ __launch_bounds__(256) void mgemm_attn64_k(const u16* qb, const u16* W2t, const float* bias,
                                                      const int* mask, float* attn, u16* cpadb){
  __shared__ u16 As[64][40];
  __shared__ u16 Bs[128][40];
  int tid = threadIdx.x;
  int lane = tid & 63;
  int wave = tid >> 6;
  int wn = wave * 32;
  int quad = lane >> 4, l16 = lane & 15;
  int m0 = blockIdx.y * 64, n0 = blockIdx.x * 128, b = blockIdx.z;
  const u16* A  = qb  + (size_t)b*2048*512;
  const u16* Bt = W2t + (size_t)b*262144;
  fx4 acc[4][2] = {};
  int ar = tid >> 2;
  int ac = (tid & 3) * 8;
  for (int k0 = 0; k0 < 512; k0 += 32) {
    *(u16x8*)&As[ar][ac]    = *(const u16x8*)&A[(size_t)(m0+ar)*512 + k0 + ac];
    *(u16x8*)&Bs[ar][ac]    = *(const u16x8*)&Bt[(size_t)(n0+ar)*512 + k0 + ac];
    *(u16x8*)&Bs[ar+64][ac] = *(const u16x8*)&Bt[(size_t)(n0+ar+64)*512 + k0 + ac];
    __syncthreads();
    bf16x8 af[4], bfv[2];
    #pragma unroll
    for (int i = 0; i < 4; i++)
      af[i] = __builtin_bit_cast(bf16x8, *(const u16x8*)&As[i*16 + l16][quad*8]);
    #pragma unroll
    for (int j = 0; j < 2; j++)
      bfv[j] = __builtin_bit_cast(bf16x8, *(const u16x8*)&Bs[wn + j*16 + l16][quad*8]);
    #pragma unroll
    for (int i = 0; i < 4; i++)
      #pragma unroll
      for (int j = 0; j < 2; j++)
        acc[i][j] = __builtin_amdgcn_mfma_f32_16x16x32_bf16(af[i], bfv[j], acc[i][j], 0, 0, 0);
    __syncthreads();
  }
  #pragma unroll
  for (int i = 0; i < 4; i++)
    #pragma unroll
    for (int j = 0; j < 2; j++) {
      int col = n0 + wn + j*16 + l16;
      float bv = bias[col];
      #pragma unroll
      for (int r = 0; r < 4; r++) {
        int row_l = m0 + i*16 + quad*4 + r;
        float v = acc[i][j][r] + bv;
        attn[((size_t)b*2048 + row_l)*512 + col] = v;
        int mk = mask[b*2048 + row_l];
        cpadb[((size_t)b*2088 + row_l + 20)*512 + col] = mk ? f2bf(v) : (u16)0;
      }
    }
}

// zero cpad edge rows t' in [0,20) and [2068,2088)
__global__ __launch_bounds__(256) void cpz_k(u16* cpadb){
  int idx = blockIdx.x*256 + threadIdx.x;
  if (idx < BB*40*512) {
    int c = idx & 511;
    int t = (idx >> 9) % 40;
    int b = idx / (40*512);
    int tt = (t < 20) ? t : 2048 + t;
    cpadb[((size_t)b*2088 + tt)*512 + c] = 0;
  }
}

// ---- conv, ONE conv per block: grid (4 o, 16 t, 8 = b*2+cid). D = gelu(conv+bias) ----
__global__ __launch_bounds__(256, 2) void mconv3_k(const u16* cpad, const u16* Wn, const u16* Ww,
                                                   const float* bias_n, const float* bias_w,
                                                   float* Dn, float* Dw){
  __shared__ u16 As[168][72];
  __shared__ u16 Ws[2][128][72];
  int tid = threadIdx.x;
  int lane = tid & 63;
  int wave = tid >> 6;
  int wm = (wave >> 1) * 64, wn = (wave & 1) * 64;
  int quad = lane >> 4, l16 = lane & 15;
  int o0 = blockIdx.x * 128, m0 = blockIdx.y * 128;
  int b = blockIdx.z >> 1, cid = blockIdx.z & 1;
  const u16* W = cid ? Ww : Wn;
  const float* bias = cid ? bias_w : bias_n;
  float* D = cid ? Dw : Dn;
  fx4 acc[4][4] = {};
  const u16* cb = cpad + ((size_t)b*2088 + m0)*512;
  for (int c0 = 0; c0 < 512; c0 += 64) {
    for (int idx = tid; idx < 168*8; idx += 256) {
      int r = idx >> 3, off = (idx & 7)*8;
      *(u16x8*)&As[r][off] = *(const u16x8*)&cb[(size_t)r*512 + c0 + off];
    }
    {
      const u16* wp = W + (size_t)o0*512 + c0;
      #pragma unroll
      for (int u = 0; u < 4; u++) {
        int idx = tid + u*256;
        int r = idx >> 3, off = (idx & 7)*8;
        *(u16x8*)&Ws[0][r][off] = *(const u16x8*)&wp[(size_t)r*512 + off];
      }
    }
    __syncthreads();
    #pragma unroll
    for (int kk = 0; kk < 9; kk++) {
      u16x8 pre[4];
      if (kk < 8) {
        const u16* wp = W + (size_t)(kk+1)*262144 + (size_t)o0*512 + c0;
        #pragma unroll
        for (int u = 0; u < 4; u++) {
          int idx = tid + u*256;
          int r = idx >> 3, off = (idx & 7)*8;
          pre[u] = *(const u16x8*)&wp[(size_t)r*512 + off];
        }
      }
      int buf = kk & 1;
      int shift = cid ? 5*kk : 16 + kk;
      #pragma unroll
      for (int ks = 0; ks < 2; ks++) {
        bf16x8 bfv[4];
        #pragma unroll
        for (int j = 0; j < 4; j++)
          bfv[j] = __builtin_bit_cast(bf16x8, *(const u16x8*)&Ws[buf][wn + j*16 + l16][ks*32 + quad*8]);
        #pragma unroll
        for (int i = 0; i < 4; i++) {
          bf16x8 afr = __builtin_bit_cast(bf16x8, *(const u16x8*)&As[shift + wm + i*16 + l16][ks*32 + quad*8]);
          #pragma unroll
          for (int j = 0; j < 4; j++)
            acc[i][j] = __builtin_amdgcn_mfma_f32_16x16x32_bf16(afr, bfv[j], acc[i][j], 0, 0, 0);
        }
      }
      if (kk < 8) {
        #pragma unroll
        for (int u = 0; u < 4; u++) {
          int idx = tid + u*256;
          int r = idx >> 3, off = (idx & 7)*8;
          *(u16x8*)&Ws[buf ^ 1][r][off] = pre[u];
        }
      }
      __syncthreads();
    }
  }
  #pragma unroll
  for (int i = 0; i < 4; i++)
    #pragma unroll
    for (int j = 0; j < 4; j++) {
      int col = o0 + wn + j*16 + l16;
      float bv = bias[col];
      #pragma unroll
      for (int r = 0; r < 4; r++) {
        int row = b*2048 + m0 + wm + i*16 + quad*4 + r;
        D[(size_t)row*512 + col] = geluf(acc[i][j][r] + bv);
      }
    }
}

// per-(b,n): qb = bf16(softmax(q+rope over d)*0.125); v *= mask in place
__global__ __launch_bounds__(512) void qv_k(const float* rope, const int* mask, float* qkv, u16* qb){
  int row = blockIdx.x;
  int n = row & (NN-1);
  int tid = threadIdx.x;
  int d = tid & 63;
  float* qp = qkv + (size_t)row*1536;
  float v = qp[tid] + rope[n*64 + d];
  float m = v;
  #pragma unroll
  for (int o = 32; o; o >>= 1) m = fmaxf(m, __shfl_xor(m, o, 64));
  float e = expf(v - m);
  float s = e;
  #pragma unroll
  for (int o = 32; o; o >>= 1) s += __shfl_xor(s, o, 64);
  qb[(size_t)row*512 + tid] = f2bf(e * (0.125f / s));
  float mk = mask[row] ? 1.0f : 0.0f;
  qp[1024 + tid] *= mk;
}

// segmented k-softmax stats: per (b,h), segment of 256 rows
__global__ __launch_bounds__(256) void kstat1_k(const float* qkv, const float* rope,
                                                const int* mask, float* kredM, float* kredS){
  int bh = blockIdx.x, seg = blockIdx.y;
  int b = bh >> 3, h = bh & 7;
  int tid = threadIdx.x;
  int d = tid & 63, g = tid >> 6;
  __shared__ float red[4][64];
  const float* kp = qkv + (size_t)b*NN*1536 + 512 + h*64 + d;
  const int* mp = mask + b*NN;
  int nbase = seg*256 + g*64;
  float m = -3.0e38f;
  for (int n = nbase; n < nbase+64; n++)
    if (mp[n]) m = fmaxf(m, kp[(size_t)n*1536] + rope[n*64 + d]);
  red[g][d] = m;
  __syncthreads();
  float M = fmaxf(fmaxf(red[0][d], red[1][d]), fmaxf(red[2][d], red[3][d]));
  __syncthreads();
  float s = 0.0f;
  if (M > -1e38f) {
    for (int n = nbase; n < nbase+64; n++)
      if (mp[n]) s += expf(kp[(size_t)n*1536] + rope[n*64 + d] - M);
  }
  red[g][d] = s;
  __syncthreads();
  if (g == 0) {
    int o = (bh*8 + seg)*64 + d;
    kredM[o] = M;
    kredS[o] = red[0][d] + red[1][d] + red[2][d] + red[3][d];
  }
}

__global__ __launch_bounds__(64) void kstat2_k(const float* kredM, const float* kredS,
                                               float* kM, float* kS){
  int bh = blockIdx.x, d = threadIdx.x;
  float M = -3.0e38f;
  for (int s = 0; s < 8; s++) M = fmaxf(M, kredM[(bh*8 + s)*64 + d]);
  float S = 0.0f;
  for (int s = 0; s < 8; s++) {
    float ms = kredM[(bh*8 + s)*64 + d];
    if (ms > -1e38f) S += kredS[(bh*8 + s)*64 + d] * expf(ms - M);
  }
  kM[bh*64 + d] = M;
  kS[bh*64 + d] = (S > 0.0f) ? S : 1.0f;
}

#define FMA16(a, b, acc) \
  acc[0][0] = fmaf(a.x, b.x, acc[0][0]); acc[0][1] = fmaf(a.x, b.y, acc[0][1]); \
  acc[0][2] = fmaf(a.x, b.z, acc[0][2]); acc[0][3] = fmaf(a.x, b.w, acc[0][3]); \
  acc[1][0] = fmaf(a.y, b.x, acc[1][0]); acc[1][1] = fmaf(a.y, b.y, acc[1][1]); \
  acc[1][2] = fmaf(a.y, b.z, acc[1][2]); acc[1][3] = fmaf(a.y, b.w, acc[1][3]); \
  acc[2][0] = fmaf(a.z, b.x, acc[2][0]); acc[2][1] = fmaf(a.z, b.y, acc[2][1]); \
  acc[2][2] = fmaf(a.z, b.z, acc[2][2]); acc[2][3] = fmaf(a.z, b.w, acc[2][3]); \
  acc[3][0] = fmaf(a.w, b.x, acc[3][0]); acc[3][1] = fmaf(a.w, b.y, acc[3][1]); \
  acc[3][2] = fmaf(a.w, b.z, acc[3][2]); acc[3][3] = fmaf(a.w, b.w, acc[3][3]);

// ctx[bh][d][e] += sum_n ke[n,d]*v[n,e]; ke = mask? exp(k+rope-M)/S : 0 computed inline
__global__ __launch_bounds__(256) void ctx_k(const float* qkv, const float* rope, const int* mask,
                                             const float* kM, const float* kS, float* ctx){
  int bh = blockIdx.x, seg = blockIdx.y;
  int b = bh >> 3, h = bh & 7;
  __shared__ float Ks[32][68], Vs[32][68];
  int tid = threadIdx.x, tx = tid & 15, ty = tid >> 4;
  float acc[4][4] = {{0.f,0.f,0.f,0.f},{0.f,0.f,0.f,0.f},{0.f,0.f,0.f,0.f},{0.f,0.f,0.f,0.f}};
  const float* basep = qkv + (size_t)(b*NN + seg*256)*1536 + h*64;
  const int* mp = mask + b*NN;
  int nl = tid >> 3, dcol = (tid & 7)*8;
  float4 km0 = *(const float4*)&kM[bh*64 + dcol];
  float4 km1 = *(const float4*)&kM[bh*64 + dcol + 4];
  float4 ksv0 = *(const float4*)&kS[bh*64 + dcol];
  float4 ksv1 = *(const float4*)&kS[bh*64 + dcol + 4];
  float4 rs0 = {1.0f/ksv0.x, 1.0f/ksv0.y, 1.0f/ksv0.z, 1.0f/ksv0.w};
  float4 rs1 = {1.0f/ksv1.x, 1.0f/ksv1.y, 1.0f/ksv1.z, 1.0f/ksv1.w};
  for (int nc = 0; nc < 256; nc += 32) {
    int n = seg*256 + nc + nl;
    const float* kp = basep + (size_t)(nc + nl)*1536 + 512 + dcol;
    const float* vp = basep + (size_t)(nc + nl)*1536 + 1024 + dcol;
    float4 a0 = *(const float4*)kp, a1 = *(const float4*)(kp+4);
    float4 b0 = *(const float4*)vp, b1 = *(const float4*)(vp+4);
    if (mp[n]) {
      float4 r0 = *(const float4*)&rope[n*64 + dcol];
      float4 r1 = *(const float4*)&rope[n*64 + dcol + 4];
      a0.x = expf(a0.x + r0.x - km0.x) * rs0.x;
      a0.y = expf(a0.y + r0.y - km0.y) * rs0.y;
      a0.z = expf(a0.z + r0.z - km0.z) * rs0.z;
      a0.w = expf(a0.w + r0.w - km0.w) * rs0.w;
      a1.x = expf(a1.x + r1.x - km1.x) * rs1.x;
      a1.y = expf(a1.y + r1.y - km1.y) * rs1.y;
      a1.z = expf(a1.z + r1.z - km1.z) * rs1.z;
      a1.w = expf(a1.w + r1.w - km1.w) * rs1.w;
    } else {
      a0 = (float4){0,0,0,0}; a1 = (float4){0,0,0,0};
    }
    *(float4*)&Ks[nl][dcol]   = a0; *(float4*)&Ks[nl][dcol+4] = a1;
    *(float4*)&Vs[nl][dcol]   = b0; *(float4*)&Vs[nl][dcol+4] = b1;
    __syncthreads();
    #pragma unroll
    for (int q = 0; q < 32; q++) {
      float4 a = *(const float4*)&Ks[q][ty*4];
      float4 b = *(const float4*)&Vs[q][tx*4];
      FMA16(a, b, acc)
    }
    __syncthreads();
  }
  float* cp = ctx + (size_t)bh*4096;
  #pragma unroll
  for (int i = 0; i < 4; i++)
    #pragma unroll
    for (int j = 0; j < 4; j++)
      atomicAdd(&cp[(ty*4 + i)*64 + tx*4 + j], acc[i][j]);
}

// W2t[b][o][h*64+d] = sum_e ctx[b,h][d][e] * woutt[o][h*64+e]   (bf16 out)
__global__ __launch_bounds__(256, 2) void ctxw_k(const float* ctx, const u16* woutt, u16* W2t){
  int h = blockIdx.x, b = blockIdx.y;
  int tid = threadIdx.x;
  int lane = tid & 63, wave = tid >> 6;
  int quad = lane >> 4, l16 = lane & 15;
  const float* cp = ctx + (size_t)(b*8 + h)*4096;
  fx4 acc[8][4] = {};
  #pragma unroll
  for (int ks = 0; ks < 2; ks++) {
    bf16x8 bfv[4];
    #pragma unroll
    for (int j = 0; j < 4; j++) {
      const float* src = cp + (j*16 + l16)*64 + ks*32 + quad*8;
      float4 v0 = *(const float4*)src, v1 = *(const float4*)(src + 4);
      bf16x8 t;
      t[0]=(__bf16)v0.x; t[1]=(__bf16)v0.y; t[2]=(__bf16)v0.z; t[3]=(__bf16)v0.w;
      t[4]=(__bf16)v1.x; t[5]=(__bf16)v1.y; t[6]=(__bf16)v1.z; t[7]=(__bf16)v1.w;
      bfv[j] = t;
    }
    #pragma unroll
    for (int i = 0; i < 8; i++) {
      int orow = wave*128 + i*16 + l16;
      bf16x8 afr = __builtin_bit_cast(bf16x8, *(const u16x8*)&woutt[(size_t)orow*512 + h*64 + ks*32 + quad*8]);
      #pragma unroll
      for (int j = 0; j < 4; j++)
        acc[i][j] = __builtin_amdgcn_mfma_f32_16x16x32_bf16(afr, bfv[j], acc[i][j], 0, 0, 0);
    }
  }
  u16* out = W2t + (size_t)b*262144;
  #pragma unroll
  for (int i = 0; i < 8; i++)
    #pragma unroll
    for (int j = 0; j < 4; j++)
      #pragma unroll
      for (int r = 0; r < 4; r++) {
        int orow = wave*128 + i*16 + quad*4 + r;
        out[(size_t)orow*512 + h*64 + j*16 + l16] = f2bf(acc[i][j][r]);
      }
}

__device__ __forceinline__ float block_sum512(float v, float* red){
  #pragma unroll
  for (int o = 32; o; o >>= 1) v += __shfl_xor(v, o, 64);
  int w = threadIdx.x >> 6;
  if ((threadIdx.x & 63) == 0) red[w] = v;
  __syncthreads();
  float t = red[0] + red[1] + red[2] + red[3];
  __syncthreads();
  return t;
}

// LN over 512; NADD extra inputs summed in; OM=1: bf16 out; OM=2: flags[0]? fp32 : bf16
template<int NADD, int OM>
__global__ __launch_bounds__(256) void ln_k(const float* X, const float* Y, const float* Z,
                                            const float* g, const float* be,
                                            const int* flags, void* out){
  __shared__ float red[4];
  size_t row = blockIdx.x;
  int tid = threadIdx.x;
  const float* xp = X + row*512;
  float x0 = xp[tid], x1 = xp[tid + 256];
  if (NADD >= 1) { const float* yp = Y + row*512; x0 += yp[tid]; x1 += yp[tid + 256]; }
  if (NADD >= 2) { const float* zp = Z + row*512; x0 += zp[tid]; x1 += zp[tid + 256]; }
  float mean = block_sum512(x0 + x1, red) * (1.0f/512.0f);
  float d0 = x0 - mean, d1 = x1 - mean;
  float var = block_sum512(d0*d0 + d1*d1, red) * (1.0f/512.0f);
  float inv = rsqrtf(var + 1e-5f);
  float r0 = d0*inv*g[tid]       + be[tid];
  float r1 = d1*inv*g[tid + 256] + be[tid + 256];
  bool obf = (OM == 1) || (OM == 2 && !flags[0]);
  if (obf) {
    u16* op = (u16*)out;
    op[row*512 + tid]       = f2bf(r0);
    op[row*512 + tid + 256] = f2bf(r1);
  } else {
    float* op = (float*)out;
    op[row*512 + tid]       = r0;
    op[row*512 + tid + 256] = r1;
  }
}

extern "C" void kernel_launch(void* const* d_in, const int* in_sizes, int n_in,
                              void* d_out, int out_size, void* d_ws, size_t ws_size,
                              hipStream_t stream) {
  const void* tokens   = d_in[0];
  const void* mask     = d_in[1];
  const void* w_qkv    = d_in[2];
  const void* w_out    = d_in[3];
  const void* b_out    = d_in[4];
  const void* w_narrow = d_in[5];
  const void* b_narrow = d_in[6];
  const void* w_wide   = d_in[7];
  const void* b_wide   = d_in[8];
  const void* ln1_g    = d_in[9];
  const void* ln1_b    = d_in[10];
  const void* ff_w     = d_in[11];
  const void* ff_b     = d_in[12];
  const void* ln2_g    = d_in[13];
  const void* ln2_b    = d_in[14];

  float* ws = (float*)d_ws;
  int*   flags  = (int*)ws;                    // 16
  int*   m32    = (int*)(ws + 16);             // 8192 -> 8208
  float* params = ws + 8208;                   // 4096 -> 12304
  float* kredM  = ws + 12304;                  // 16384 -> 28688
  float* kredS  = ws + 28688;                  // 16384 -> 45072
  float* kM     = ws + 45072;                  // 2048 -> 47120
  float* kS     = ws + 47120;                  // 2048 -> 49168
  float* ctx    = ws + 49168;                  // 131072 -> 180240
  float* rope   = ws + 180240;                 // 131072 -> 311312
  u16*   tokbf  = (u16*)(ws + 311312);         // 4194304 u16 -> 2408464
  u16*   wqkvt  = (u16*)(ws + 2408464);        // 786432 u16 -> 2801680
  u16*   woutt  = (u16*)(ws + 2801680);        // 262144 u16 -> 2932752
  u16*   ffwt   = (u16*)(ws + 2932752);        // 262144 u16 -> 3063824
  u16*   wtN2   = (u16*)(ws + 3063824);        // 2359296 u16 -> 4243472
  u16*   wtW2   = (u16*)(ws + 4243472);        // 2359296 u16 -> 5423120
  u16*   qb     = (u16*)(ws + 5423120);        // 4194304 u16 -> 7520272
  u16*   W2t    = (u16*)(ws + 7520272);        // 1048576 u16 -> 8044560
  float* qkv    = ws + 8044560;                // 12582912 -> 20627472
  float* attn   = ws + 20627472;               // 4194304 -> 24821776 (~99.3 MB)
  // overlays inside qkv region (k/v dead after ctx_k)
  u16*   cpadb  = (u16*)qkv;                   // 4276224 u16 = 2138112 fl
  float* Dn     = qkv + 2138112;               // 4194304 fl -> 6332416
  float* Dw     = qkv + 6332416;               // 4194304 fl -> 10526720 (< 12582912)
  float* Ebuf   = attn;                        // attn dead after ln1
  u16*   t1b    = tokbf;                       // tokens dead after qkv gemm

  float* p_bout = params;        float* p_bnar = params + 512;
  float* p_bwid = params + 1024; float* p_l1g  = params + 1536;
  float* p_l1b  = params + 2048; float* p_ffb  = params + 2560;
  float* p_l2g  = params + 3072; float* p_l2b  = params + 3584;

  sniff_k<<<dim3(1), dim3(256), 0, stream>>>((const u16*)tokens, (const unsigned int*)mask, flags);
  misc_k<<<dim3(1072), dim3(256), 0, stream>>>(mask, b_out, b_narrow, b_wide, ln1_g, ln1_b, ff_b,
                                               ln2_g, ln2_b, flags, rope, m32, params, ctx);
  prep_k<<<dim3(4096), dim3(256), 0, stream>>>(tokens, w_qkv, w_out, ff_w, w_narrow, w_wide,
                                               flags, tokbf, wqkvt, woutt, ffwt, wtN2, wtW2);

  // qkv = tokens @ w_qkv  (8192 x 1536, K=512)
  mgemm_k<false,false><<<dim3(12, 64), dim3(256), 0, stream>>>(
      tokbf, wqkvt, nullptr, qkv, NROWS, 1536, 512);

  qv_k<<<dim3(NROWS), dim3(512), 0, stream>>>(rope, m32, qkv, qb);
  kstat1_k<<<dim3(32, 8), dim3(256), 0, stream>>>(qkv, rope, m32, kredM, kredS);
  kstat2_k<<<dim3(32), dim3(64), 0, stream>>>(kredM, kredS, kM, kS);

  // ctx with fused k-exp (kexp pass eliminated)
  ctx_k<<<dim3(32, 8), dim3(256), 0, stream>>>(qkv, rope, m32, kM, kS, ctx);

  // W2t[b] = blockdiag(ctx_b) @ w_out
  ctxw_k<<<dim3(8, 4), dim3(256), 0, stream>>>(ctx, woutt, W2t);

  // qkv region dead from here; cpadb/Dn/Dw overlay it
  cpz_k<<<dim3(320), dim3(256), 0, stream>>>(cpadb);

  // attn = qb @ W2t[b]^T + b_out; fused masked bf16 cpad write  (grid 512)
  mgemm_attn64_k<<<dim3(4, 32, 4), dim3(256), 0, stream>>>(qb, W2t, p_bout, m32, attn, cpadb);

  // convs: one conv per block (grid 512, 2 blocks/CU)
  mconv3_k<<<dim3(4, 16, 8), dim3(256), 0, stream>>>(cpadb, wtN2, wtW2, p_bnar, p_bwid, Dn, Dw);

  // t1 = LN(attn + Dn + Dw) -> bf16
  ln_k<2,1><<<dim3(NROWS), dim3(256), 0, stream>>>(attn, Dn, Dw, p_l1g, p_l1b, flags, (void*)t1b);

  // E = gelu(t1 @ ff_w + ff_b)  (grid 512)
  mgemm64_k<true,true><<<dim3(4, 128), dim3(256), 0, stream>>>(
      t1b, ffwt, p_ffb, Ebuf, NROWS, 512, 512);

  // out = LN(E) -> d_out, dtype per flags
  ln_k<0,2><<<dim3(NROWS), dim3(256), 0, stream>>>(Ebuf, nullptr, nullptr, p_l2g, p_l2b, flags, d_out);
}

// Round 6
// 411.573 us; speedup vs baseline: 4.7878x; 1.0017x over previous
//
#include <hip/hip_runtime.h>
#include <hip/hip_bf16.h>

#define BB 4
#define NN 2048
#define NROWS (BB*NN)   // 8192

typedef unsigned short u16;
typedef __bf16 bf16x8 __attribute__((ext_vector_type(8)));
typedef u16    u16x8  __attribute__((ext_vector_type(8)));
typedef float  fx4    __attribute__((ext_vector_type(4)));

__device__ __forceinline__ float bf2f(u16 u){
  union { float f; unsigned int i; } x; x.i = ((unsigned int)u) << 16; return x.f;
}
__device__ __forceinline__ u16 f2bf(float f){
  union { float f; unsigned int i; } x; x.f = f;
  unsigned int i = x.i;
  i += 0x7fffu + ((i >> 16) & 1u);
  return (u16)(i >> 16);
}
__device__ __forceinline__ float geluf(float x){
  return 0.5f * x * (1.0f + erff(x * 0.70710678118654752f));
}

// flags[0]=1 if float inputs fp32 (else bf16); flags[1]=1 if mask byte-packed
__global__ __launch_bounds__(256) void sniff_k(const u16* tokens, const unsigned int* mask, int* flags){
  __shared__ int s_f32, s_byte;
  if (threadIdx.x == 0) { s_f32 = 0; s_byte = 0; }
  __syncthreads();
  for (int i = threadIdx.x; i < 4096; i += 256) {
    float v = bf2f(tokens[i]);
    if (!(fabsf(v) < 1e10f)) atomicOr(&s_f32, 1);
  }
  for (int i = threadIdx.x; i < 2048; i += 256) {
    if (mask[i] > 1u) atomicOr(&s_byte, 1);
  }
  __syncthreads();
  if (threadIdx.x == 0) { flags[0] = s_f32; flags[1] = s_byte; }
}

// rope + m32 + params + zero(ctx,kS) + tokbf in one grid-stride launch
__global__ __launch_bounds__(256) void misc_k(const void* mask, const void* tokens,
                                              const void* p0, const void* p1, const void* p2,
                                              const void* p3, const void* p4, const void* p5,
                                              const void* p6, const void* p7,
                                              const int* flags, float* rope, int* m32,
                                              float* params, float* ctx, float* kS, u16* tokbf){
  const void* srcs[8] = {p0,p1,p2,p3,p4,p5,p6,p7};
  int f32 = flags[0], mbyte = flags[1];
  const int T = 131072 + 8192 + 4096 + 131072 + 2048 + 4194304;
  for (int i = blockIdx.x*256 + threadIdx.x; i < T; i += gridDim.x*256) {
    if (i < 131072) {
      int p = i >> 6, j = i & 63;
      int jj = (j < 32) ? j : j - 32;
      float invf = exp2f(-(float)jj * (13.287712379549449f/32.0f));  // 10000^(-jj/32)
      float prod = (float)p * invf;
      rope[i] = (j < 32) ? sinf(prod) : cosf(prod);
    } else if (i < 139264) {
      int k = i - 131072;
      int v = mbyte ? (int)((const unsigned char*)mask)[k] : ((const int*)mask)[k];
      m32[k] = v ? 1 : 0;
    } else if (i < 143360) {
      int k = i - 139264;
      int pid = k >> 9, j = k & 511;
      const void* s = srcs[pid];
      params[k] = f32 ? ((const float*)s)[j] : bf2f(((const u16*)s)[j]);
    } else if (i < 274432) {
      ctx[i - 143360] = 0.0f;
    } else if (i < 276480) {
      kS[i - 274432] = 0.0f;
    } else {
      int k = i - 276480;
      tokbf[k] = f32 ? f2bf(((const float*)tokens)[k]) : ((const u16*)tokens)[k];
    }
  }
}

// LDS tile transpose [K][N]->[N][K] u16 for the three dense weights.
// grid (24, 8, 3); z=0: w_qkv (512x1536), z=1: w_out, z=2: ff_w (512x512)
__global__ __launch_bounds__(256) void t64_k(const void* w_qkv, const void* w_out, const void* ff_w,
                                             const int* flags, u16* wqkvt, u16* woutt, u16* ffwt){
  int z = blockIdx.z;
  int Nn = (z == 0) ? 1536 : 512;
  if (blockIdx.x * 64 >= Nn) return;
  const void* src = (z == 0) ? w_qkv : (z == 1) ? w_out : ff_w;
  u16* dst = (z == 0) ? wqkvt : (z == 1) ? woutt : ffwt;
  int f = flags[0];
  __shared__ u16 Ts[64][72];
  int n0 = blockIdx.x * 64, k0 = blockIdx.y * 64;
  int tid = threadIdx.x;
  int r = tid >> 2, cq = (tid & 3) * 16;
  #pragma unroll
  for (int u = 0; u < 2; u++) {
    int c = cq + u*8;
    int sidx = (k0 + r)*Nn + n0 + c;
    u16x8 v;
    if (f) {
      #pragma unroll
      for (int j = 0; j < 8; j++) v[j] = f2bf(((const float*)src)[sidx + j]);
    } else {
      v = *(const u16x8*)&((const u16*)src)[sidx];
    }
    *(u16x8*)&Ts[r][c] = v;
  }
  __syncthreads();
  #pragma unroll
  for (int u = 0; u < 2; u++) {
    int c = cq + u*8;
    u16x8 v;
    #pragma unroll
    for (int j = 0; j < 8; j++) v[j] = Ts[c + j][r];
    *(u16x8*)&dst[(size_t)(n0 + r)*512 + k0 + c] = v;
  }
}

// conv weights w[o][c][kk] -> W2[kk][o][c] bf16 via LDS; 1024 blocks (tensor*512 + o)
__global__ __launch_bounds__(256) void convw_k(const void* w_narrow, const void* w_wide,
                                               const int* flags, u16* wtN2, u16* wtW2){
  int bid = blockIdx.x;
  int tensor = bid >> 9, o = bid & 511;
  const void* src = tensor ? w_wide : w_narrow;
  u16* dst = tensor ? wtW2 : wtN2;
  int f = flags[0];
  __shared__ u16 Ls[4608];
  int tid = threadIdx.x;
  for (int i = tid; i < 4608; i += 256) {
    Ls[i] = f ? f2bf(((const float*)src)[(size_t)o*4608 + i]) : ((const u16*)src)[(size_t)o*4608 + i];
  }
  __syncthreads();
  #pragma unroll
  for (int kk = 0; kk < 9; kk++) {
    #pragma unroll
    for (int u = 0; u < 2; u++) {
      int c = tid + u*256;
      dst[(size_t)kk*262144 + o*512 + c] = Ls[c*9 + kk];
    }
  }
}

// ---------------- MFMA bf16 GEMM 128x128: C[M,N] = A[M,K] @ Bt[N,K]^T (fp32 out) ------------
template<bool BIAS, bool GELU>
__global__ __launch_bounds__(256) void mgemm_k(const u16* A, const u16* Bt, const float* bias,
                                               float* C, int M, int N, int K){
  __shared__ u16 As[128][40];
  __shared__ u16 Bs[128][40];
  int tid = threadIdx.x;
  int lane = tid & 63;
  int wave = tid >> 6;
  int wm = (wave >> 1) * 64, wn = (wave & 1) * 64;
  int quad = lane >> 4, l16 = lane & 15;
  int m0 = blockIdx.y * 128, n0 = blockIdx.x * 128;
  fx4 acc[4][4] = {};
  int ar = tid >> 2;
  int ac = (tid & 3) * 8;
  for (int k0 = 0; k0 < K; k0 += 32) {
    *(u16x8*)&As[ar][ac]    = *(const u16x8*)&A[(size_t)(m0+ar)*K + k0 + ac];
    *(u16x8*)&As[ar+64][ac] = *(const u16x8*)&A[(size_t)(m0+ar+64)*K + k0 + ac];
    *(u16x8*)&Bs[ar][ac]    = *(const u16x8*)&Bt[(size_t)(n0+ar)*K + k0 + ac];
    *(u16x8*)&Bs[ar+64][ac] = *(const u16x8*)&Bt[(size_t)(n0+ar+64)*K + k0 + ac];
    __syncthreads();
    bf16x8 af[4], bfv[4];
    #pragma unroll
    for (int i = 0; i < 4; i++)
      af[i] = __builtin_bit_cast(bf16x8, *(const u16x8*)&As[wm + i*16 + l16][quad*8]);
    #pragma unroll
    for (int j = 0; j < 4; j++)
      bfv[j] = __builtin_bit_cast(bf16x8, *(const u16x8*)&Bs[wn + j*16 + l16][quad*8]);
    #pragma unroll
    for (int i = 0; i < 4; i++)
      #pragma unroll
      for (int j = 0; j < 4; j++)
        acc[i][j] = __builtin_amdgcn_mfma_f32_16x16x32_bf16(af[i], bfv[j], acc[i][j], 0, 0, 0);
    __syncthreads();
  }
  #pragma unroll
  for (int i = 0; i < 4; i++)
    #pragma unroll
    for (int j = 0; j < 4; j++) {
      int col = n0 + wn + j*16 + l16;
      float bv = BIAS ? bias[col] : 0.0f;
      #pragma unroll
      for (int r = 0; r < 4; r++) {
        int row = m0 + wm + i*16 + quad*4 + r;
        float v = acc[i][j][r] + bv;
        if (GELU) v = geluf(v);
        C[(size_t)row*N + col] = v;
      }
    }
}

// ---------------- MFMA bf16 GEMM, M-tile 64, bf16 out ----------------
template<bool BIAS, bool GELU>
__global__ __launch_bounds__(256) void mgemm64b_k(const u16* A, const u16* Bt, const float* bias,
                                                  u16* C, int M, int N, int K){
  __shared__ u16 As[64][40];
  __shared__ u16 Bs[128][40];
  int tid = threadIdx.x;
  int lane = tid & 63;
  int wave = tid >> 6;
  int wn = wave * 32;
  int quad = lane >> 4, l16 = lane & 15;
  int m0 = blockIdx.y * 64, n0 = blockIdx.x * 128;
  fx4 acc[4][2] = {};
  int ar = tid >> 2;
  int ac = (tid & 3) * 8;
  for (int k0 = 0; k0 < K; k0 += 32) {
    *(u16x8*)&As[ar][ac]    = *(const u16x8*)&A[(size_t)(m0+ar)*K + k0 + ac];
    *(u16x8*)&Bs[ar][ac]    = *(const u16x8*)&Bt[(size_t)(n0+ar)*K + k0 + ac];
    *(u16x8*)&Bs[ar+64][ac] = *(const u16x8*)&Bt[(size_t)(n0+ar+64)*K + k0 + ac];
    __syncthreads();
    bf16x8 af[4], bfv[2];
    #pragma unroll
    for (int i = 0; i < 4; i++)
      af[i] = __builtin_bit_cast(bf16x8, *(const u16x8*)&As[i*16 + l16][quad*8]);
    #pragma unroll
    for (int j = 0; j < 2; j++)
      bfv[j] = __builtin_bit_cast(bf16x8, *(const u16x8*)&Bs[wn + j*16 + l16][quad*8]);
    #pragma unroll
    for (int i = 0; i < 4; i++)
      #pragma unroll
      for (int j = 0; j < 2; j++)
        acc[i][j] = __builtin_amdgcn_mfma_f32_16x16x32_bf16(af[i], bfv[j], acc[i][j], 0, 0, 0);
    __syncthreads();
  }
  #pragma unroll
  for (int i = 0; i < 4; i++)
    #pragma unroll
    for (int j = 0; j < 2; j++) {
      int col = n0 + wn + j*16 + l16;
      float bv = BIAS ? bias[col] : 0.0f;
      #pragma unroll
      for (int r = 0; r < 4; r++) {
        int row = m0 + i*16 + quad*4 + r;
        float v = acc[i][j][r] + bv;
        if (GELU) v = geluf(v);
        C[(size_t)row*N + col] = f2bf(v);
      }
    }
}

// ---- batched attn GEMM (M-tile 64): attnb = bf16(qb[b] @ W2t[b]^T + b_out); fused masked cpad ----
__global__ __launch_bounds__(256) void mgemm_attn64_k(const u16* qb, const u16* W2t, const float* bias,
                                                      const int* mask, u16* attnb, u16* cpadb){
  __shared__ u16 As[64][40];
  __shared__ u16 Bs[128][40];
  int tid = threadIdx.x;
  int lane = tid & 63;
  int wave = tid >> 6;
  int wn = wave * 32;
  int quad = lane >> 4, l16 = lane & 15;
  int m0 = blockIdx.y * 64, n0 = blockIdx.x * 128, b = blockIdx.z;
  const u16* A  = qb  + (size_t)b*2048*512;
  const u16* Bt = W2t + (size_t)b*262144;
  fx4 acc[4][2] = {};
  int ar = tid >> 2;
  int ac = (tid & 3) * 8;
  for (int k0 = 0; k0 < 512; k0 += 32) {
    *(u16x8*)&As[ar][ac]    = *(const u16x8*)&A[(size_t)(m0+ar)*512 + k0 + ac];
    *(u16x8*)&Bs[ar][ac]    = *(const u16x8*)&Bt[(size_t)(n0+ar)*512 + k0 + ac];
    *(u16x8*)&Bs[ar+64][ac] = *(const u16x8*)&Bt[(size_t)(n0+ar+64)*512 + k0 + ac];
    __syncthreads();
    bf16x8 af[4], bfv[2];
    #pragma unroll
    for (int i = 0; i < 4; i++)
      af[i] = __builtin_bit_cast(bf16x8, *(const u16x8*)&As[i*16 + l16][quad*8]);
    #pragma unroll
    for (int j = 0; j < 2; j++)
      bfv[j] = __builtin_bit_cast(bf16x8, *(const u16x8*)&Bs[wn + j*16 + l16][quad*8]);
    #pragma unroll
    for (int i = 0; i < 4; i++)
      #pragma unroll
      for (int j = 0; j < 2; j++)
        acc[i][j] = __builtin_amdgcn_mfma_f32_16x16x32_bf16(af[i], bfv[j], acc[i][j], 0, 0, 0);
    __syncthreads();
  }
  #pragma unroll
  for (int i = 0; i < 4; i++)
    #pragma unroll
    for (int j = 0; j < 2; j++) {
      int col = n0 + wn + j*16 + l16;
      float bv = bias[col];
      #pragma unroll
      for (int r = 0; r < 4; r++) {
        int row_l = m0 + i*16 + quad*4 + r;
        float v = acc[i][j][r] + bv;
        u16 vb = f2bf(v);
        attnb[((size_t)b*2048 + row_l)*512 + col] = vb;
        int mk = mask[b*2048 + row_l];
        cpadb[((size_t)b*2088 + row_l + 20)*512 + col] = mk ? vb : (u16)0;
      }
    }
}

// ---- conv, 256x128 block tile, wave tile 128x64, 1 conv per block; bf16 out ----
// grid (4 o, 8 t, 8 = b*2+cid)
__global__ __launch_bounds__(256, 1) void mconv4_k(const u16* cpad, const u16* Wn, const u16* Ww,
                                                   const float* bias_n, const float* bias_w,
                                                   u16* Dn, u16* Dw){
  __shared__ u16 As[296][72];
  __shared__ u16 Ws[2][128][72];
  int tid = threadIdx.x;
  int lane = tid & 63;
  int wave = tid >> 6;
  int wm = (wave >> 1) * 128;   // t offset within 256
  int wn2 = (wave & 1) * 64;    // o offset within 128
  int quad = lane >> 4, l16 = lane & 15;
  int o0 = blockIdx.x * 128, m0 = blockIdx.y * 256;
  int b = blockIdx.z >> 1, cid = blockIdx.z & 1;
  const u16* W = cid ? Ww : Wn;
  const float* bias = cid ? bias_w : bias_n;
  u16* D = cid ? Dw : Dn;
  fx4 acc[8][4] = {};
  const u16* cb = cpad + ((size_t)b*2088 + m0)*512;
  for (int c0 = 0; c0 < 512; c0 += 64) {
    // stage A: 296 rows x 64 u16
    for (int idx = tid; idx < 296*8; idx += 256) {
      int r = idx >> 3, off = (idx & 7)*8;
      *(u16x8*)&As[r][off] = *(const u16x8*)&cb[(size_t)r*512 + c0 + off];
    }
    // stage tap-0 weights into buf 0
    {
      const u16* wp = W + (size_t)o0*512 + c0;
      #pragma unroll
      for (int u = 0; u < 4; u++) {
        int idx = tid + u*256;
        int r = idx >> 3, off = (idx & 7)*8;
        *(u16x8*)&Ws[0][r][off] = *(const u16x8*)&wp[(size_t)r*512 + off];
      }
    }
    __syncthreads();
    #pragma unroll
    for (int kk = 0; kk < 9; kk++) {
      u16x8 pre[4];
      if (kk < 8) {
        const u16* wp = W + (size_t)(kk+1)*262144 + (size_t)o0*512 + c0;
        #pragma unroll
        for (int u = 0; u < 4; u++) {
          int idx = tid + u*256;
          int r = idx >> 3, off = (idx & 7)*8;
          pre[u] = *(const u16x8*)&wp[(size_t)r*512 + off];
        }
      }
      int buf = kk & 1;
      int shift = cid ? 5*kk : 16 + kk;
      #pragma unroll
      for (int ks = 0; ks < 2; ks++) {
        bf16x8 bfv[4];
        #pragma unroll
        for (int j = 0; j < 4; j++)
          bfv[j] = __builtin_bit_cast(bf16x8, *(const u16x8*)&Ws[buf][wn2 + j*16 + l16][ks*32 + quad*8]);
        #pragma unroll
        for (int i = 0; i < 8; i++) {
          bf16x8 afr = __builtin_bit_cast(bf16x8, *(const u16x8*)&As[shift + wm + i*16 + l16][ks*32 + quad*8]);
          #pragma unroll
          for (int j = 0; j < 4; j++)
            acc[i][j] = __builtin_amdgcn_mfma_f32_16x16x32_bf16(afr, bfv[j], acc[i][j], 0, 0, 0);
        }
      }
      if (kk < 8) {
        #pragma unroll
        for (int u = 0; u < 4; u++) {
          int idx = tid + u*256;
          int r = idx >> 3, off = (idx & 7)*8;
          *(u16x8*)&Ws[buf ^ 1][r][off] = pre[u];
        }
      }
      __syncthreads();
    }
  }
  #pragma unroll
  for (int i = 0; i < 8; i++)
    #pragma unroll
    for (int j = 0; j < 4; j++) {
      int col = o0 + wn2 + j*16 + l16;
      float bv = bias[col];
      #pragma unroll
      for (int r = 0; r < 4; r++) {
        int row = b*2048 + m0 + wm + i*16 + quad*4 + r;
        D[(size_t)row*512 + col] = f2bf(geluf(acc[i][j][r] + bv));
      }
    }
}

// merged: qv (blocks 0..8191) + kstat-M (blocks 8192..8447); 512 threads
__global__ __launch_bounds__(512) void qvks_k(const float* rope, const int* mask, float* qkv,
                                              u16* qb, float* kredM){
  int bx = blockIdx.x;
  int tid = threadIdx.x;
  if (bx < NROWS) {
    int row = bx;
    int n = row & (NN-1);
    int d = tid & 63;
    float* qp = qkv + (size_t)row*1536;
    float v = qp[tid] + rope[n*64 + d];
    float m = v;
    #pragma unroll
    for (int o = 32; o; o >>= 1) m = fmaxf(m, __shfl_xor(m, o, 64));
    float e = expf(v - m);
    float s = e;
    #pragma unroll
    for (int o = 32; o; o >>= 1) s += __shfl_xor(s, o, 64);
    qb[(size_t)row*512 + tid] = f2bf(e * (0.125f / s));
    float mk = mask[row] ? 1.0f : 0.0f;
    qp[1024 + tid] *= mk;
  } else {
    int seg = bx - NROWS;           // 0..255
    int bh = seg >> 3, s = seg & 7;
    int b = bh >> 3, h = bh & 7;
    int d = tid & 63, g = tid >> 6; // 8 groups of 32 rows
    __shared__ float red[8][64];
    const float* kp = qkv + (size_t)b*NN*1536 + 512 + h*64 + d;
    const int* mp = mask + b*NN;
    int nbase = s*256 + g*32;
    float m = -3.0e38f;
    for (int n = nbase; n < nbase+32; n++)
      if (mp[n]) m = fmaxf(m, kp[(size_t)n*1536] + rope[n*64 + d]);
    red[g][d] = m;
    __syncthreads();
    if (g == 0) {
      float M = m;
      #pragma unroll
      for (int gg = 1; gg < 8; gg++) M = fmaxf(M, red[gg][d]);
      kredM[(bh*8 + s)*64 + d] = M;
    }
  }
}

__global__ __launch_bounds__(64) void kstat2_k(const float* kredM, float* kM){
  int bh = blockIdx.x, d = threadIdx.x;
  float M = -3.0e38f;
  for (int s = 0; s < 8; s++) M = fmaxf(M, kredM[(bh*8 + s)*64 + d]);
  kM[bh*64 + d] = M;
}

#define FMA16(a, b, acc) \
  acc[0][0] = fmaf(a.x, b.x, acc[0][0]); acc[0][1] = fmaf(a.x, b.y, acc[0][1]); \
  acc[0][2] = fmaf(a.x, b.z, acc[0][2]); acc[0][3] = fmaf(a.x, b.w, acc[0][3]); \
  acc[1][0] = fmaf(a.y, b.x, acc[1][0]); acc[1][1] = fmaf(a.y, b.y, acc[1][1]); \
  acc[1][2] = fmaf(a.y, b.z, acc[1][2]); acc[1][3] = fmaf(a.y, b.w, acc[1][3]); \
  acc[2][0] = fmaf(a.z, b.x, acc[2][0]); acc[2][1] = fmaf(a.z, b.y, acc[2][1]); \
  acc[2][2] = fmaf(a.z, b.z, acc[2][2]); acc[2][3] = fmaf(a.z, b.w, acc[2][3]); \
  acc[3][0] = fmaf(a.w, b.x, acc[3][0]); acc[3][1] = fmaf(a.w, b.y, acc[3][1]); \
  acc[3][2] = fmaf(a.w, b.z, acc[3][2]); acc[3][3] = fmaf(a.w, b.w, acc[3][3]);

// ctx[bh][d][e] += sum_n e(n,d)*v[n,e] with e=mask?exp(k+rope-M):0; also S[bh][d] += sum_n e
__global__ __launch_bounds__(256) void ctx_k(const float* qkv, const float* rope, const int* mask,
                                             const float* kM, float* ctx, float* Sg){
  int bh = blockIdx.x, seg = blockIdx.y;
  int b = bh >> 3, h = bh & 7;
  __shared__ float Ks[32][68], Vs[32][68];
  __shared__ float sS[64];
  int tid = threadIdx.x, tx = tid & 15, ty = tid >> 4;
  if (tid < 64) sS[tid] = 0.0f;
  float acc[4][4] = {{0.f,0.f,0.f,0.f},{0.f,0.f,0.f,0.f},{0.f,0.f,0.f,0.f},{0.f,0.f,0.f,0.f}};
  float sp[8] = {0,0,0,0,0,0,0,0};
  const float* basep = qkv + (size_t)(b*NN + seg*256)*1536 + h*64;
  const int* mp = mask + b*NN;
  int nl = tid >> 3, dcol = (tid & 7)*8;
  float4 km0 = *(const float4*)&kM[bh*64 + dcol];
  float4 km1 = *(const float4*)&kM[bh*64 + dcol + 4];
  for (int nc = 0; nc < 256; nc += 32) {
    int n = seg*256 + nc + nl;
    const float* kp = basep + (size_t)(nc + nl)*1536 + 512 + dcol;
    const float* vp = basep + (size_t)(nc + nl)*1536 + 1024 + dcol;
    float4 a0 = *(const float4*)kp, a1 = *(const float4*)(kp+4);
    float4 b0 = *(const float4*)vp, b1 = *(const float4*)(vp+4);
    if (mp[n]) {
      float4 r0 = *(const float4*)&rope[n*64 + dcol];
      float4 r1 = *(const float4*)&rope[n*64 + dcol + 4];
      a0.x = expf(a0.x + r0.x - km0.x);
      a0.y = expf(a0.y + r0.y - km0.y);
      a0.z = expf(a0.z + r0.z - km0.z);
      a0.w = expf(a0.w + r0.w - km0.w);
      a1.x = expf(a1.x + r1.x - km1.x);
      a1.y = expf(a1.y + r1.y - km1.y);
      a1.z = expf(a1.z + r1.z - km1.z);
      a1.w = expf(a1.w + r1.w - km1.w);
    } else {
      a0 = (float4){0,0,0,0}; a1 = (float4){0,0,0,0};
    }
    sp[0] += a0.x; sp[1] += a0.y; sp[2] += a0.z; sp[3] += a0.w;
    sp[4] += a1.x; sp[5] += a1.y; sp[6] += a1.z; sp[7] += a1.w;
    *(float4*)&Ks[nl][dcol]   = a0; *(float4*)&Ks[nl][dcol+4] = a1;
    *(float4*)&Vs[nl][dcol]   = b0; *(float4*)&Vs[nl][dcol+4] = b1;
    __syncthreads();
    #pragma unroll
    for (int q = 0; q < 32; q++) {
      float4 a = *(const float4*)&Ks[q][ty*4];
      float4 b = *(const float4*)&Vs[q][tx*4];
      FMA16(a, b, acc)
    }
    __syncthreads();
  }
  #pragma unroll
  for (int j = 0; j < 8; j++) atomicAdd(&sS[dcol + j], sp[j]);
  float* cp = ctx + (size_t)bh*4096;
  #pragma unroll
  for (int i = 0; i < 4; i++)
    #pragma unroll
    for (int j = 0; j < 4; j++)
      atomicAdd(&cp[(ty*4 + i)*64 + tx*4 + j], acc[i][j]);
  __syncthreads();
  if (tid < 64) atomicAdd(&Sg[bh*64 + tid], sS[tid]);
}

// merged: ctxw (blocks 0..31) + cpad-edge-zero (blocks 32..351)
// W2t[b][o][h*64+d] = sum_e (ctx[b,h][d][e]/S[d]) * woutt[o][h*64+e]
__global__ __launch_bounds__(256) void ctxw_k(const float* ctx, const float* Sg, const u16* woutt,
                                              u16* W2t, u16* cpadb){
  int bx = blockIdx.x;
  int tid = threadIdx.x;
  if (bx >= 32) {
    int idx = (bx - 32)*256 + tid;
    if (idx < BB*40*512) {
      int c = idx & 511;
      int t = (idx >> 9) % 40;
      int b = idx / (40*512);
      int tt = (t < 20) ? t : 2048 + t;
      cpadb[((size_t)b*2088 + tt)*512 + c] = 0;
    }
    return;
  }
  int h = bx & 7, b = bx >> 3;
  int lane = tid & 63, wave = tid >> 6;
  int quad = lane >> 4, l16 = lane & 15;
  const float* cp = ctx + (size_t)(b*8 + h)*4096;
  fx4 acc[8][4] = {};
  #pragma unroll
  for (int ks = 0; ks < 2; ks++) {
    bf16x8 bfv[4];
    #pragma unroll
    for (int j = 0; j < 4; j++) {
      int d = j*16 + l16;
      float S = Sg[(b*8 + h)*64 + d];
      float rs = (S > 0.0f) ? 1.0f/S : 0.0f;
      const float* src = cp + d*64 + ks*32 + quad*8;
      float4 v0 = *(const float4*)src, v1 = *(const float4*)(src + 4);
      bf16x8 t;
      t[0]=(__bf16)(v0.x*rs); t[1]=(__bf16)(v0.y*rs); t[2]=(__bf16)(v0.z*rs); t[3]=(__bf16)(v0.w*rs);
      t[4]=(__bf16)(v1.x*rs); t[5]=(__bf16)(v1.y*rs); t[6]=(__bf16)(v1.z*rs); t[7]=(__bf16)(v1.w*rs);
      bfv[j] = t;
    }
    #pragma unroll
    for (int i = 0; i < 8; i++) {
      int orow = wave*128 + i*16 + l16;
      bf16x8 afr = __builtin_bit_cast(bf16x8, *(const u16x8*)&woutt[(size_t)orow*512 + h*64 + ks*32 + quad*8]);
      #pragma unroll
      for (int j = 0; j < 4; j++)
        acc[i][j] = __builtin_amdgcn_mfma_f32_16x16x32_bf16(afr, bfv[j], acc[i][j], 0, 0, 0);
    }
  }
  u16* out = W2t + (size_t)b*262144;
  #pragma unroll
  for (int i = 0; i < 8; i++)
    #pragma unroll
    for (int j = 0; j < 4; j++)
      #pragma unroll
      for (int r = 0; r < 4; r++) {
        int orow = wave*128 + i*16 + quad*4 + r;
        out[(size_t)orow*512 + h*64 + j*16 + l16] = f2bf(acc[i][j][r]);
      }
}

__device__ __forceinline__ float block_sum512(float v, float* red){
  #pragma unroll
  for (int o = 32; o; o >>= 1) v += __shfl_xor(v, o, 64);
  int w = threadIdx.x >> 6;
  if ((threadIdx.x & 63) == 0) red[w] = v;
  __syncthreads();
  float t = red[0] + red[1] + red[2] + red[3];
  __syncthreads();
  return t;
}

// LN over 512 with bf16 inputs; NADD extra inputs; OM=1: bf16 out; OM=2: flags[0]? fp32 : bf16
template<int NADD, int OM>
__global__ __launch_bounds__(256) void ln_k(const u16* X, const u16* Y, const u16* Z,
                                            const float* g, const float* be,
                                            const int* flags, void* out){
  __shared__ float red[4];
  size_t row = blockIdx.x;
  int tid = threadIdx.x;
  const u16* xp = X + row*512;
  float x0 = bf2f(xp[tid]), x1 = bf2f(xp[tid + 256]);
  if (NADD >= 1) { const u16* yp = Y + row*512; x0 += bf2f(yp[tid]); x1 += bf2f(yp[tid + 256]); }
  if (NADD >= 2) { const u16* zp = Z + row*512; x0 += bf2f(zp[tid]); x1 += bf2f(zp[tid + 256]); }
  float mean = block_sum512(x0 + x1, red) * (1.0f/512.0f);
  float d0 = x0 - mean, d1 = x1 - mean;
  float var = block_sum512(d0*d0 + d1*d1, red) * (1.0f/512.0f);
  float inv = rsqrtf(var + 1e-5f);
  float r0 = d0*inv*g[tid]       + be[tid];
  float r1 = d1*inv*g[tid + 256] + be[tid + 256];
  bool obf = (OM == 1) || (OM == 2 && !flags[0]);
  if (obf) {
    u16* op = (u16*)out;
    op[row*512 + tid]       = f2bf(r0);
    op[row*512 + tid + 256] = f2bf(r1);
  } else {
    float* op = (float*)out;
    op[row*512 + tid]       = r0;
    op[row*512 + tid + 256] = r1;
  }
}

extern "C" void kernel_launch(void* const* d_in, const int* in_sizes, int n_in,
                              void* d_out, int out_size, void* d_ws, size_t ws_size,
                              hipStream_t stream) {
  const void* tokens   = d_in[0];
  const void* mask     = d_in[1];
  const void* w_qkv    = d_in[2];
  const void* w_out    = d_in[3];
  const void* b_out    = d_in[4];
  const void* w_narrow = d_in[5];
  const void* b_narrow = d_in[6];
  const void* w_wide   = d_in[7];
  const void* b_wide   = d_in[8];
  const void* ln1_g    = d_in[9];
  const void* ln1_b    = d_in[10];
  const void* ff_w     = d_in[11];
  const void* ff_b     = d_in[12];
  const void* ln2_g    = d_in[13];
  const void* ln2_b    = d_in[14];

  float* ws = (float*)d_ws;
  int*   flags  = (int*)ws;                    // 16
  int*   m32    = (int*)(ws + 16);             // 8192 -> 8208
  float* params = ws + 8208;                   // 4096 -> 12304
  float* kredM  = ws + 12304;                  // 16384 -> 28688
  float* kM     = ws + 28688;                  // 2048 -> 30736
  float* kS     = ws + 30736;                  // 2048 -> 32784
  float* ctx    = ws + 32784;                  // 131072 -> 163856
  float* rope   = ws + 163856;                 // 131072 -> 294928
  u16*   tokbf  = (u16*)(ws + 294928);         // 4194304 u16 -> 2392080
  u16*   wqkvt  = (u16*)(ws + 2392080);        // 786432 u16 -> 2785296
  u16*   woutt  = (u16*)(ws + 2785296);        // 262144 u16 -> 2916368
  u16*   ffwt   = (u16*)(ws + 2916368);        // 262144 u16 -> 3047440
  u16*   wtN2   = (u16*)(ws + 3047440);        // 2359296 u16 -> 4227088
  u16*   wtW2   = (u16*)(ws + 4227088);        // 2359296 u16 -> 5406736
  u16*   qb     = (u16*)(ws + 5406736);        // 4194304 u16 -> 7503888
  u16*   W2t    = (u16*)(ws + 7503888);        // 1048576 u16 -> 8028176
  u16*   attnb  = (u16*)(ws + 8028176);        // 4194304 u16 -> 10125328
  float* qkv    = ws + 10125328;               // 12582912 -> 22708240 (~91 MB)
  // overlays inside qkv region (k/v dead after ctx_k)
  u16*   cpadb  = (u16*)qkv;                   // 4276224 u16 = 2138112 fl
  u16*   Dnb    = (u16*)(qkv + 2138112);       // 4194304 u16 = 2097152 fl
  u16*   Dwb    = (u16*)(qkv + 4235264);       // 4194304 u16 -> 6332416 fl  (< 12582912)
  u16*   Eb     = attnb;                       // attnb dead after ln1
  u16*   t1b    = tokbf;                       // tokens dead after qkv gemm

  float* p_bout = params;        float* p_bnar = params + 512;
  float* p_bwid = params + 1024; float* p_l1g  = params + 1536;
  float* p_l1b  = params + 2048; float* p_ffb  = params + 2560;
  float* p_l2g  = params + 3072; float* p_l2b  = params + 3584;

  sniff_k<<<dim3(1), dim3(256), 0, stream>>>((const u16*)tokens, (const unsigned int*)mask, flags);
  misc_k<<<dim3(8192), dim3(256), 0, stream>>>(mask, tokens, b_out, b_narrow, b_wide, ln1_g, ln1_b,
                                               ff_b, ln2_g, ln2_b, flags, rope, m32, params, ctx,
                                               kS, tokbf);
  t64_k<<<dim3(24, 8, 3), dim3(256), 0, stream>>>(w_qkv, w_out, ff_w, flags, wqkvt, woutt, ffwt);
  convw_k<<<dim3(1024), dim3(256), 0, stream>>>(w_narrow, w_wide, flags, wtN2, wtW2);

  // qkv = tokens @ w_qkv  (8192 x 1536, K=512)
  mgemm_k<false,false><<<dim3(12, 64), dim3(256), 0, stream>>>(
      tokbf, wqkvt, nullptr, qkv, NROWS, 1536, 512);

  // q-softmax + v-mask + k-colmax(seg) in one launch
  qvks_k<<<dim3(NROWS + 256), dim3(512), 0, stream>>>(rope, m32, qkv, qb, kredM);
  kstat2_k<<<dim3(32), dim3(64), 0, stream>>>(kredM, kM);

  // ctx with fused k-exp and S accumulation
  ctx_k<<<dim3(32, 8), dim3(256), 0, stream>>>(qkv, rope, m32, kM, ctx, kS);

  // W2t[b] = (blockdiag(ctx_b)/S) @ w_out; + cpad edge zero
  ctxw_k<<<dim3(352), dim3(256), 0, stream>>>(ctx, kS, woutt, W2t, cpadb);

  // attn = qb @ W2t[b]^T + b_out (bf16); fused masked cpad write
  mgemm_attn64_k<<<dim3(4, 32, 4), dim3(256), 0, stream>>>(qb, W2t, p_bout, m32, attnb, cpadb);

  // convs: 256x128 tiles, wave 128x64, one conv per block
  mconv4_k<<<dim3(4, 8, 8), dim3(256), 0, stream>>>(cpadb, wtN2, wtW2, p_bnar, p_bwid, Dnb, Dwb);

  // t1 = LN(attn + Dn + Dw) -> bf16
  ln_k<2,1><<<dim3(NROWS), dim3(256), 0, stream>>>(attnb, Dnb, Dwb, p_l1g, p_l1b, flags, (void*)t1b);

  // E = gelu(t1 @ ff_w + ff_b) -> bf16
  mgemm64b_k<true,true><<<dim3(4, 128), dim3(256), 0, stream>>>(
      t1b, ffwt, p_ffb, Eb, NROWS, 512, 512);

  // out = LN(E) -> d_out, dtype per flags
  ln_k<0,2><<<dim3(NROWS), dim3(256), 0, stream>>>(Eb, nullptr, nullptr, p_l2g, p_l2b, flags, d_out);
}

// Round 7
// 366.276 us; speedup vs baseline: 5.3799x; 1.1237x over previous
//
#include <hip/hip_runtime.h>
#include <hip/hip_bf16.h>

#define BB 4
#define NN 2048
#define NROWS (BB*NN)   // 8192

typedef unsigned short u16;
typedef __bf16 bf16x8 __attribute__((ext_vector_type(8)));
typedef u16    u16x8  __attribute__((ext_vector_type(8)));
typedef float  fx4    __attribute__((ext_vector_type(4)));

__device__ __forceinline__ float bf2f(u16 u){
  union { float f; unsigned int i; } x; x.i = ((unsigned int)u) << 16; return x.f;
}
__device__ __forceinline__ u16 f2bf(float f){
  union { float f; unsigned int i; } x; x.f = f;
  unsigned int i = x.i;
  i += 0x7fffu + ((i >> 16) & 1u);
  return (u16)(i >> 16);
}
__device__ __forceinline__ float geluf(float x){
  return 0.5f * x * (1.0f + erff(x * 0.70710678118654752f));
}

// flags[0]=1 if float inputs fp32 (else bf16); flags[1]=1 if mask byte-packed
__global__ __launch_bounds__(256) void sniff_k(const u16* tokens, const unsigned int* mask, int* flags){
  __shared__ int s_f32, s_byte;
  if (threadIdx.x == 0) { s_f32 = 0; s_byte = 0; }
  __syncthreads();
  for (int i = threadIdx.x; i < 4096; i += 256) {
    float v = bf2f(tokens[i]);
    if (!(fabsf(v) < 1e10f)) atomicOr(&s_f32, 1);
  }
  for (int i = threadIdx.x; i < 2048; i += 256) {
    if (mask[i] > 1u) atomicOr(&s_byte, 1);
  }
  __syncthreads();
  if (threadIdx.x == 0) { flags[0] = s_f32; flags[1] = s_byte; }
}

// rope + m32 + params + zero(ctx,kS) + tokbf in one grid-stride launch
__global__ __launch_bounds__(256) void misc_k(const void* mask, const void* tokens,
                                              const void* p0, const void* p1, const void* p2,
                                              const void* p3, const void* p4, const void* p5,
                                              const void* p6, const void* p7,
                                              const int* flags, float* rope, int* m32,
                                              float* params, float* ctx, float* kS, u16* tokbf){
  const void* srcs[8] = {p0,p1,p2,p3,p4,p5,p6,p7};
  int f32 = flags[0], mbyte = flags[1];
  const int T = 131072 + 8192 + 4096 + 131072 + 2048 + 4194304;
  for (int i = blockIdx.x*256 + threadIdx.x; i < T; i += gridDim.x*256) {
    if (i < 131072) {
      int p = i >> 6, j = i & 63;
      int jj = (j < 32) ? j : j - 32;
      float invf = exp2f(-(float)jj * (13.287712379549449f/32.0f));  // 10000^(-jj/32)
      float prod = (float)p * invf;
      rope[i] = (j < 32) ? sinf(prod) : cosf(prod);
    } else if (i < 139264) {
      int k = i - 131072;
      int v = mbyte ? (int)((const unsigned char*)mask)[k] : ((const int*)mask)[k];
      m32[k] = v ? 1 : 0;
    } else if (i < 143360) {
      int k = i - 139264;
      int pid = k >> 9, j = k & 511;
      const void* s = srcs[pid];
      params[k] = f32 ? ((const float*)s)[j] : bf2f(((const u16*)s)[j]);
    } else if (i < 274432) {
      ctx[i - 143360] = 0.0f;
    } else if (i < 276480) {
      kS[i - 274432] = 0.0f;
    } else {
      int k = i - 276480;
      tokbf[k] = f32 ? f2bf(((const float*)tokens)[k]) : ((const u16*)tokens)[k];
    }
  }
}

// merged weight prep: blocks [0,1024): conv weights w[o][c][kk] -> W2[kk][o][c];
// blocks [1024,1600): LDS tile transpose [K][N]->[N][K] for the three dense weights
__global__ __launch_bounds__(256) void prep2_k(const void* w_qkv, const void* w_out, const void* ff_w,
                                               const void* w_narrow, const void* w_wide,
                                               const int* flags,
                                               u16* wqkvt, u16* woutt, u16* ffwt,
                                               u16* wtN2, u16* wtW2){
  int bid = blockIdx.x;
  int f = flags[0];
  int tid = threadIdx.x;
  if (bid < 1024) {
    int tensor = bid >> 9, o = bid & 511;
    const void* src = tensor ? w_wide : w_narrow;
    u16* dst = tensor ? wtW2 : wtN2;
    __shared__ u16 Ls[4608];
    for (int i = tid; i < 4608; i += 256) {
      Ls[i] = f ? f2bf(((const float*)src)[(size_t)o*4608 + i]) : ((const u16*)src)[(size_t)o*4608 + i];
    }
    __syncthreads();
    #pragma unroll
    for (int kk = 0; kk < 9; kk++) {
      #pragma unroll
      for (int u = 0; u < 2; u++) {
        int c = tid + u*256;
        dst[(size_t)kk*262144 + o*512 + c] = Ls[c*9 + kk];
      }
    }
  } else {
    int id = bid - 1024;
    int z = id / 192;
    int rem = id - z*192;
    int x = rem % 24, y = rem / 24;
    int Nn = (z == 0) ? 1536 : 512;
    if (x * 64 >= Nn) return;
    const void* src = (z == 0) ? w_qkv : (z == 1) ? w_out : ff_w;
    u16* dst = (z == 0) ? wqkvt : (z == 1) ? woutt : ffwt;
    __shared__ u16 Ts[64][72];
    int n0 = x * 64, k0 = y * 64;
    int r = tid >> 2, cq = (tid & 3) * 16;
    #pragma unroll
    for (int u = 0; u < 2; u++) {
      int c = cq + u*8;
      int sidx = (k0 + r)*Nn + n0 + c;
      u16x8 v;
      if (f) {
        #pragma unroll
        for (int j = 0; j < 8; j++) v[j] = f2bf(((const float*)src)[sidx + j]);
      } else {
        v = *(const u16x8*)&((const u16*)src)[sidx];
      }
      *(u16x8*)&Ts[r][c] = v;
    }
    __syncthreads();
    #pragma unroll
    for (int u = 0; u < 2; u++) {
      int c = cq + u*8;
      u16x8 v;
      #pragma unroll
      for (int j = 0; j < 8; j++) v[j] = Ts[c + j][r];
      *(u16x8*)&dst[(size_t)(n0 + r)*512 + k0 + c] = v;
    }
  }
}

// ---------------- MFMA bf16 GEMM 128x128: C[M,N] = A[M,K] @ Bt[N,K]^T (fp32 out) ------------
template<bool BIAS, bool GELU>
__global__ __launch_bounds__(256) void mgemm_k(const u16* A, const u16* Bt, const float* bias,
                                               float* C, int M, int N, int K){
  __shared__ u16 As[128][40];
  __shared__ u16 Bs[128][40];
  int tid = threadIdx.x;
  int lane = tid & 63;
  int wave = tid >> 6;
  int wm = (wave >> 1) * 64, wn = (wave & 1) * 64;
  int quad = lane >> 4, l16 = lane & 15;
  int m0 = blockIdx.y * 128, n0 = blockIdx.x * 128;
  fx4 acc[4][4] = {};
  int ar = tid >> 2;
  int ac = (tid & 3) * 8;
  for (int k0 = 0; k0 < K; k0 += 32) {
    *(u16x8*)&As[ar][ac]    = *(const u16x8*)&A[(size_t)(m0+ar)*K + k0 + ac];
    *(u16x8*)&As[ar+64][ac] = *(const u16x8*)&A[(size_t)(m0+ar+64)*K + k0 + ac];
    *(u16x8*)&Bs[ar][ac]    = *(const u16x8*)&Bt[(size_t)(n0+ar)*K + k0 + ac];
    *(u16x8*)&Bs[ar+64][ac] = *(const u16x8*)&Bt[(size_t)(n0+ar+64)*K + k0 + ac];
    __syncthreads();
    bf16x8 af[4], bfv[4];
    #pragma unroll
    for (int i = 0; i < 4; i++)
      af[i] = __builtin_bit_cast(bf16x8, *(const u16x8*)&As[wm + i*16 + l16][quad*8]);
    #pragma unroll
    for (int j = 0; j < 4; j++)
      bfv[j] = __builtin_bit_cast(bf16x8, *(const u16x8*)&Bs[wn + j*16 + l16][quad*8]);
    #pragma unroll
    for (int i = 0; i < 4; i++)
      #pragma unroll
      for (int j = 0; j < 4; j++)
        acc[i][j] = __builtin_amdgcn_mfma_f32_16x16x32_bf16(af[i], bfv[j], acc[i][j], 0, 0, 0);
    __syncthreads();
  }
  #pragma unroll
  for (int i = 0; i < 4; i++)
    #pragma unroll
    for (int j = 0; j < 4; j++) {
      int col = n0 + wn + j*16 + l16;
      float bv = BIAS ? bias[col] : 0.0f;
      #pragma unroll
      for (int r = 0; r < 4; r++) {
        int row = m0 + wm + i*16 + quad*4 + r;
        float v = acc[i][j][r] + bv;
        if (GELU) v = geluf(v);
        C[(size_t)row*N + col] = v;
      }
    }
}

// ---------------- MFMA bf16 GEMM, M-tile 64, bf16 out ----------------
template<bool BIAS, bool GELU>
__global__ __launch_bounds__(256) void mgemm64b_k(const u16* A, const u16* Bt, const float* bias,
                                                  u16* C, int M, int N, int K){
  __shared__ u16 As[64][40];
  __shared__ u16 Bs[128][40];
  int tid = threadIdx.x;
  int lane = tid & 63;
  int wave = tid >> 6;
  int wn = wave * 32;
  int quad = lane >> 4, l16 = lane & 15;
  int m0 = blockIdx.y * 64, n0 = blockIdx.x * 128;
  fx4 acc[4][2] = {};
  int ar = tid >> 2;
  int ac = (tid & 3) * 8;
  for (int k0 = 0; k0 < K; k0 += 32) {
    *(u16x8*)&As[ar][ac]    = *(const u16x8*)&A[(size_t)(m0+ar)*K + k0 + ac];
    *(u16x8*)&Bs[ar][ac]    = *(const u16x8*)&Bt[(size_t)(n0+ar)*K + k0 + ac];
    *(u16x8*)&Bs[ar+64][ac] = *(const u16x8*)&Bt[(size_t)(n0+ar+64)*K + k0 + ac];
    __syncthreads();
    bf16x8 af[4], bfv[2];
    #pragma unroll
    for (int i = 0; i < 4; i++)
      af[i] = __builtin_bit_cast(bf16x8, *(const u16x8*)&As[i*16 + l16][quad*8]);
    #pragma unroll
    for (int j = 0; j < 2; j++)
      bfv[j] = __builtin_bit_cast(bf16x8, *(const u16x8*)&Bs[wn + j*16 + l16][quad*8]);
    #pragma unroll
    for (int i = 0; i < 4; i++)
      #pragma unroll
      for (int j = 0; j < 2; j++)
        acc[i][j] = __builtin_amdgcn_mfma_f32_16x16x32_bf16(af[i], bfv[j], acc[i][j], 0, 0, 0);
    __syncthreads();
  }
  #pragma unroll
  for (int i = 0; i < 4; i++)
    #pragma unroll
    for (int j = 0; j < 2; j++) {
      int col = n0 + wn + j*16 + l16;
      float bv = BIAS ? bias[col] : 0.0f;
      #pragma unroll
      for (int r = 0; r < 4; r++) {
        int row = m0 + i*16 + quad*4 + r;
        float v = acc[i][j][r] + bv;
        if (GELU) v = geluf(v);
        C[(size_t)row*N + col] = f2bf(v);
      }
    }
}

// ---- batched attn GEMM (M-tile 64): attnb = bf16(qb[b] @ W2t[b]^T + b_out); fused masked cpad ----
__global__ __launch_bounds__(256) void mgemm_attn64_k(const u16* qb, const u16* W2t, const float* bias,
                                                      const int* mask, u16* attnb, u16* cpadb){
  __shared__ u16 As[64][40];
  __shared__ u16 Bs[128][40];
  int tid = threadIdx.x;
  int lane = tid & 63;
  int wave = tid >> 6;
  int wn = wave * 32;
  int quad = lane >> 4, l16 = lane & 15;
  int m0 = blockIdx.y * 64, n0 = blockIdx.x * 128, b = blockIdx.z;
  const u16* A  = qb  + (size_t)b*2048*512;
  const u16* Bt = W2t + (size_t)b*262144;
  fx4 acc[4][2] = {};
  int ar = tid >> 2;
  int ac = (tid & 3) * 8;
  for (int k0 = 0; k0 < 512; k0 += 32) {
    *(u16x8*)&As[ar][ac]    = *(const u16x8*)&A[(size_t)(m0+ar)*512 + k0 + ac];
    *(u16x8*)&Bs[ar][ac]    = *(const u16x8*)&Bt[(size_t)(n0+ar)*512 + k0 + ac];
    *(u16x8*)&Bs[ar+64][ac] = *(const u16x8*)&Bt[(size_t)(n0+ar+64)*512 + k0 + ac];
    __syncthreads();
    bf16x8 af[4], bfv[2];
    #pragma unroll
    for (int i = 0; i < 4; i++)
      af[i] = __builtin_bit_cast(bf16x8, *(const u16x8*)&As[i*16 + l16][quad*8]);
    #pragma unroll
    for (int j = 0; j < 2; j++)
      bfv[j] = __builtin_bit_cast(bf16x8, *(const u16x8*)&Bs[wn + j*16 + l16][quad*8]);
    #pragma unroll
    for (int i = 0; i < 4; i++)
      #pragma unroll
      for (int j = 0; j < 2; j++)
        acc[i][j] = __builtin_amdgcn_mfma_f32_16x16x32_bf16(af[i], bfv[j], acc[i][j], 0, 0, 0);
    __syncthreads();
  }
  #pragma unroll
  for (int i = 0; i < 4; i++)
    #pragma unroll
    for (int j = 0; j < 2; j++) {
      int col = n0 + wn + j*16 + l16;
      float bv = bias[col];
      #pragma unroll
      for (int r = 0; r < 4; r++) {
        int row_l = m0 + i*16 + quad*4 + r;
        float v = acc[i][j][r] + bv;
        u16 vb = f2bf(v);
        attnb[((size_t)b*2048 + row_l)*512 + col] = vb;
        int mk = mask[b*2048 + row_l];
        cpadb[((size_t)b*2088 + row_l + 20)*512 + col] = mk ? vb : (u16)0;
      }
    }
}

// ---- conv: 128t x 64o block tile, wave tile 64x32, single-buffer W + reg prefetch ----
// LDS 33.4KB -> 4 blocks/CU. grid (8 o, 16 t, 8 = b*2+cid). bf16 out.
__global__ __launch_bounds__(256, 4) void mconv5_k(const u16* cpad, const u16* Wn, const u16* Ww,
                                                   const float* bias_n, const float* bias_w,
                                                   u16* Dn, u16* Dw){
  __shared__ u16 As[168][72];
  __shared__ u16 Ws[64][72];
  int tid = threadIdx.x;
  int lane = tid & 63;
  int wave = tid >> 6;
  int wm = (wave >> 1) * 64;    // t-offset within 128
  int wo = (wave & 1) * 32;     // o-offset within 64
  int quad = lane >> 4, l16 = lane & 15;
  int o0 = blockIdx.x * 64, m0 = blockIdx.y * 128;
  int b = blockIdx.z >> 1, cid = blockIdx.z & 1;
  const u16* W = cid ? Ww : Wn;
  const float* bias = cid ? bias_w : bias_n;
  u16* D = cid ? Dw : Dn;
  fx4 acc[4][2] = {};
  const u16* cb = cpad + ((size_t)b*2088 + m0)*512;
  for (int c0 = 0; c0 < 512; c0 += 64) {
    __syncthreads();   // previous chunk's readers of As/Ws done
    // stage A: 168 rows x 64 u16
    for (int idx = tid; idx < 168*8; idx += 256) {
      int r = idx >> 3, off = (idx & 7)*8;
      *(u16x8*)&As[r][off] = *(const u16x8*)&cb[(size_t)r*512 + c0 + off];
    }
    // prefetch tap-0 weights into regs
    u16x8 pre[2];
    {
      const u16* wp = W + (size_t)o0*512 + c0;
      #pragma unroll
      for (int u = 0; u < 2; u++) {
        int idx = tid + u*256;
        int r = idx >> 3, off = (idx & 7)*8;
        pre[u] = *(const u16x8*)&wp[(size_t)r*512 + off];
      }
    }
    #pragma unroll
    for (int kk = 0; kk < 9; kk++) {
      if (kk > 0) __syncthreads();   // readers of tap kk-1 done before Ws overwrite
      #pragma unroll
      for (int u = 0; u < 2; u++) {
        int idx = tid + u*256;
        int r = idx >> 3, off = (idx & 7)*8;
        *(u16x8*)&Ws[r][off] = pre[u];
      }
      if (kk < 8) {
        const u16* wp = W + (size_t)(kk+1)*262144 + (size_t)o0*512 + c0;
        #pragma unroll
        for (int u = 0; u < 2; u++) {
          int idx = tid + u*256;
          int r = idx >> 3, off = (idx & 7)*8;
          pre[u] = *(const u16x8*)&wp[(size_t)r*512 + off];
        }
      }
      __syncthreads();               // Ws (and As for kk==0) visible
      int shift = cid ? 5*kk : 16 + kk;
      #pragma unroll
      for (int ks = 0; ks < 2; ks++) {
        bf16x8 bfv[2];
        #pragma unroll
        for (int j = 0; j < 2; j++)
          bfv[j] = __builtin_bit_cast(bf16x8, *(const u16x8*)&Ws[wo + j*16 + l16][ks*32 + quad*8]);
        #pragma unroll
        for (int i = 0; i < 4; i++) {
          bf16x8 afr = __builtin_bit_cast(bf16x8, *(const u16x8*)&As[shift + wm + i*16 + l16][ks*32 + quad*8]);
          #pragma unroll
          for (int j = 0; j < 2; j++)
            acc[i][j] = __builtin_amdgcn_mfma_f32_16x16x32_bf16(afr, bfv[j], acc[i][j], 0, 0, 0);
        }
      }
    }
  }
  #pragma unroll
  for (int i = 0; i < 4; i++)
    #pragma unroll
    for (int j = 0; j < 2; j++) {
      int col = o0 + wo + j*16 + l16;
      float bv = bias[col];
      #pragma unroll
      for (int r = 0; r < 4; r++) {
        int row = b*2048 + m0 + wm + i*16 + quad*4 + r;
        D[(size_t)row*512 + col] = f2bf(geluf(acc[i][j][r] + bv));
      }
    }
}

// merged: qv (blocks 0..8191) + kstat-M (blocks 8192..8447); 512 threads
__global__ __launch_bounds__(512) void qvks_k(const float* rope, const int* mask, float* qkv,
                                              u16* qb, float* kredM){
  int bx = blockIdx.x;
  int tid = threadIdx.x;
  if (bx < NROWS) {
    int row = bx;
    int n = row & (NN-1);
    int d = tid & 63;
    float* qp = qkv + (size_t)row*1536;
    float v = qp[tid] + rope[n*64 + d];
    float m = v;
    #pragma unroll
    for (int o = 32; o; o >>= 1) m = fmaxf(m, __shfl_xor(m, o, 64));
    float e = expf(v - m);
    float s = e;
    #pragma unroll
    for (int o = 32; o; o >>= 1) s += __shfl_xor(s, o, 64);
    qb[(size_t)row*512 + tid] = f2bf(e * (0.125f / s));
    float mk = mask[row] ? 1.0f : 0.0f;
    qp[1024 + tid] *= mk;
  } else {
    int seg = bx - NROWS;           // 0..255
    int bh = seg >> 3, s = seg & 7;
    int b = bh >> 3, h = bh & 7;
    int d = tid & 63, g = tid >> 6; // 8 groups of 32 rows
    __shared__ float red[8][64];
    const float* kp = qkv + (size_t)b*NN*1536 + 512 + h*64 + d;
    const int* mp = mask + b*NN;
    int nbase = s*256 + g*32;
    float m = -3.0e38f;
    for (int n = nbase; n < nbase+32; n++)
      if (mp[n]) m = fmaxf(m, kp[(size_t)n*1536] + rope[n*64 + d]);
    red[g][d] = m;
    __syncthreads();
    if (g == 0) {
      float M = m;
      #pragma unroll
      for (int gg = 1; gg < 8; gg++) M = fmaxf(M, red[gg][d]);
      kredM[(bh*8 + s)*64 + d] = M;
    }
  }
}

#define FMA16(a, b, acc) \
  acc[0][0] = fmaf(a.x, b.x, acc[0][0]); acc[0][1] = fmaf(a.x, b.y, acc[0][1]); \
  acc[0][2] = fmaf(a.x, b.z, acc[0][2]); acc[0][3] = fmaf(a.x, b.w, acc[0][3]); \
  acc[1][0] = fmaf(a.y, b.x, acc[1][0]); acc[1][1] = fmaf(a.y, b.y, acc[1][1]); \
  acc[1][2] = fmaf(a.y, b.z, acc[1][2]); acc[1][3] = fmaf(a.y, b.w, acc[1][3]); \
  acc[2][0] = fmaf(a.z, b.x, acc[2][0]); acc[2][1] = fmaf(a.z, b.y, acc[2][1]); \
  acc[2][2] = fmaf(a.z, b.z, acc[2][2]); acc[2][3] = fmaf(a.z, b.w, acc[2][3]); \
  acc[3][0] = fmaf(a.w, b.x, acc[3][0]); acc[3][1] = fmaf(a.w, b.y, acc[3][1]); \
  acc[3][2] = fmaf(a.w, b.z, acc[3][2]); acc[3][3] = fmaf(a.w, b.w, acc[3][3]);

// ctx[bh][d][e] += sum_n e(n,d)*v[n,e], e=mask?exp(k+rope-M):0; S[bh][d] += sum_n e.
// kM computed inline from kredM (kstat2 eliminated).
__global__ __launch_bounds__(256) void ctx_k(const float* qkv, const float* rope, const int* mask,
                                             const float* kredM, float* ctx, float* Sg){
  int bh = blockIdx.x, seg = blockIdx.y;
  int b = bh >> 3, h = bh & 7;
  __shared__ float Ks[32][68], Vs[32][68];
  __shared__ float sS[64];
  __shared__ float sM[64];
  int tid = threadIdx.x, tx = tid & 15, ty = tid >> 4;
  if (tid < 64) {
    sS[tid] = 0.0f;
    float M = -3.0e38f;
    #pragma unroll
    for (int s = 0; s < 8; s++) M = fmaxf(M, kredM[(bh*8 + s)*64 + tid]);
    sM[tid] = M;
  }
  __syncthreads();
  float acc[4][4] = {{0.f,0.f,0.f,0.f},{0.f,0.f,0.f,0.f},{0.f,0.f,0.f,0.f},{0.f,0.f,0.f,0.f}};
  float sp[8] = {0,0,0,0,0,0,0,0};
  const float* basep = qkv + (size_t)(b*NN + seg*256)*1536 + h*64;
  const int* mp = mask + b*NN;
  int nl = tid >> 3, dcol = (tid & 7)*8;
  float4 km0 = *(const float4*)&sM[dcol];
  float4 km1 = *(const float4*)&sM[dcol + 4];
  for (int nc = 0; nc < 256; nc += 32) {
    int n = seg*256 + nc + nl;
    const float* kp = basep + (size_t)(nc + nl)*1536 + 512 + dcol;
    const float* vp = basep + (size_t)(nc + nl)*1536 + 1024 + dcol;
    float4 a0 = *(const float4*)kp, a1 = *(const float4*)(kp+4);
    float4 b0 = *(const float4*)vp, b1 = *(const float4*)(vp+4);
    if (mp[n]) {
      float4 r0 = *(const float4*)&rope[n*64 + dcol];
      float4 r1 = *(const float4*)&rope[n*64 + dcol + 4];
      a0.x = expf(a0.x + r0.x - km0.x);
      a0.y = expf(a0.y + r0.y - km0.y);
      a0.z = expf(a0.z + r0.z - km0.z);
      a0.w = expf(a0.w + r0.w - km0.w);
      a1.x = expf(a1.x + r1.x - km1.x);
      a1.y = expf(a1.y + r1.y - km1.y);
      a1.z = expf(a1.z + r1.z - km1.z);
      a1.w = expf(a1.w + r1.w - km1.w);
    } else {
      a0 = (float4){0,0,0,0}; a1 = (float4){0,0,0,0};
    }
    sp[0] += a0.x; sp[1] += a0.y; sp[2] += a0.z; sp[3] += a0.w;
    sp[4] += a1.x; sp[5] += a1.y; sp[6] += a1.z; sp[7] += a1.w;
    *(float4*)&Ks[nl][dcol]   = a0; *(float4*)&Ks[nl][dcol+4] = a1;
    *(float4*)&Vs[nl][dcol]   = b0; *(float4*)&Vs[nl][dcol+4] = b1;
    __syncthreads();
    #pragma unroll
    for (int q = 0; q < 32; q++) {
      float4 a = *(const float4*)&Ks[q][ty*4];
      float4 b = *(const float4*)&Vs[q][tx*4];
      FMA16(a, b, acc)
    }
    __syncthreads();
  }
  #pragma unroll
  for (int j = 0; j < 8; j++) atomicAdd(&sS[dcol + j], sp[j]);
  float* cp = ctx + (size_t)bh*4096;
  #pragma unroll
  for (int i = 0; i < 4; i++)
    #pragma unroll
    for (int j = 0; j < 4; j++)
      atomicAdd(&cp[(ty*4 + i)*64 + tx*4 + j], acc[i][j]);
  __syncthreads();
  if (tid < 64) atomicAdd(&Sg[bh*64 + tid], sS[tid]);
}

// merged: ctxw (blocks 0..31) + cpad-edge-zero (blocks 32..351)
// W2t[b][o][h*64+d] = sum_e (ctx[b,h][d][e]/S[d]) * woutt[o][h*64+e]
__global__ __launch_bounds__(256) void ctxw_k(const float* ctx, const float* Sg, const u16* woutt,
                                              u16* W2t, u16* cpadb){
  int bx = blockIdx.x;
  int tid = threadIdx.x;
  if (bx >= 32) {
    int idx = (bx - 32)*256 + tid;
    if (idx < BB*40*512) {
      int c = idx & 511;
      int t = (idx >> 9) % 40;
      int b = idx / (40*512);
      int tt = (t < 20) ? t : 2048 + t;
      cpadb[((size_t)b*2088 + tt)*512 + c] = 0;
    }
    return;
  }
  int h = bx & 7, b = bx >> 3;
  int lane = tid & 63, wave = tid >> 6;
  int quad = lane >> 4, l16 = lane & 15;
  const float* cp = ctx + (size_t)(b*8 + h)*4096;
  fx4 acc[8][4] = {};
  #pragma unroll
  for (int ks = 0; ks < 2; ks++) {
    bf16x8 bfv[4];
    #pragma unroll
    for (int j = 0; j < 4; j++) {
      int d = j*16 + l16;
      float S = Sg[(b*8 + h)*64 + d];
      float rs = (S > 0.0f) ? 1.0f/S : 0.0f;
      const float* src = cp + d*64 + ks*32 + quad*8;
      float4 v0 = *(const float4*)src, v1 = *(const float4*)(src + 4);
      bf16x8 t;
      t[0]=(__bf16)(v0.x*rs); t[1]=(__bf16)(v0.y*rs); t[2]=(__bf16)(v0.z*rs); t[3]=(__bf16)(v0.w*rs);
      t[4]=(__bf16)(v1.x*rs); t[5]=(__bf16)(v1.y*rs); t[6]=(__bf16)(v1.z*rs); t[7]=(__bf16)(v1.w*rs);
      bfv[j] = t;
    }
    #pragma unroll
    for (int i = 0; i < 8; i++) {
      int orow = wave*128 + i*16 + l16;
      bf16x8 afr = __builtin_bit_cast(bf16x8, *(const u16x8*)&woutt[(size_t)orow*512 + h*64 + ks*32 + quad*8]);
      #pragma unroll
      for (int j = 0; j < 4; j++)
        acc[i][j] = __builtin_amdgcn_mfma_f32_16x16x32_bf16(afr, bfv[j], acc[i][j], 0, 0, 0);
    }
  }
  u16* out = W2t + (size_t)b*262144;
  #pragma unroll
  for (int i = 0; i < 8; i++)
    #pragma unroll
    for (int j = 0; j < 4; j++)
      #pragma unroll
      for (int r = 0; r < 4; r++) {
        int orow = wave*128 + i*16 + quad*4 + r;
        out[(size_t)orow*512 + h*64 + j*16 + l16] = f2bf(acc[i][j][r]);
      }
}

__device__ __forceinline__ float block_sum512(float v, float* red){
  #pragma unroll
  for (int o = 32; o; o >>= 1) v += __shfl_xor(v, o, 64);
  int w = threadIdx.x >> 6;
  if ((threadIdx.x & 63) == 0) red[w] = v;
  __syncthreads();
  float t = red[0] + red[1] + red[2] + red[3];
  __syncthreads();
  return t;
}

// LN over 512 with bf16 inputs; NADD extra inputs; OM=1: bf16 out; OM=2: flags[0]? fp32 : bf16
template<int NADD, int OM>
__global__ __launch_bounds__(256) void ln_k(const u16* X, const u16* Y, const u16* Z,
                                            const float* g, const float* be,
                                            const int* flags, void* out){
  __shared__ float red[4];
  size_t row = blockIdx.x;
  int tid = threadIdx.x;
  const u16* xp = X + row*512;
  float x0 = bf2f(xp[tid]), x1 = bf2f(xp[tid + 256]);
  if (NADD >= 1) { const u16* yp = Y + row*512; x0 += bf2f(yp[tid]); x1 += bf2f(yp[tid + 256]); }
  if (NADD >= 2) { const u16* zp = Z + row*512; x0 += bf2f(zp[tid]); x1 += bf2f(zp[tid + 256]); }
  float mean = block_sum512(x0 + x1, red) * (1.0f/512.0f);
  float d0 = x0 - mean, d1 = x1 - mean;
  float var = block_sum512(d0*d0 + d1*d1, red) * (1.0f/512.0f);
  float inv = rsqrtf(var + 1e-5f);
  float r0 = d0*inv*g[tid]       + be[tid];
  float r1 = d1*inv*g[tid + 256] + be[tid + 256];
  bool obf = (OM == 1) || (OM == 2 && !flags[0]);
  if (obf) {
    u16* op = (u16*)out;
    op[row*512 + tid]       = f2bf(r0);
    op[row*512 + tid + 256] = f2bf(r1);
  } else {
    float* op = (float*)out;
    op[row*512 + tid]       = r0;
    op[row*512 + tid + 256] = r1;
  }
}

extern "C" void kernel_launch(void* const* d_in, const int* in_sizes, int n_in,
                              void* d_out, int out_size, void* d_ws, size_t ws_size,
                              hipStream_t stream) {
  const void* tokens   = d_in[0];
  const void* mask     = d_in[1];
  const void* w_qkv    = d_in[2];
  const void* w_out    = d_in[3];
  const void* b_out    = d_in[4];
  const void* w_narrow = d_in[5];
  const void* b_narrow = d_in[6];
  const void* w_wide   = d_in[7];
  const void* b_wide   = d_in[8];
  const void* ln1_g    = d_in[9];
  const void* ln1_b    = d_in[10];
  const void* ff_w     = d_in[11];
  const void* ff_b     = d_in[12];
  const void* ln2_g    = d_in[13];
  const void* ln2_b    = d_in[14];

  float* ws = (float*)d_ws;
  int*   flags  = (int*)ws;                    // 16
  int*   m32    = (int*)(ws + 16);             // 8192 -> 8208
  float* params = ws + 8208;                   // 4096 -> 12304
  float* kredM  = ws + 12304;                  // 16384 -> 28688
  float* kS     = ws + 28688;                  // 2048 -> 30736
  float* ctx    = ws + 30736;                  // 131072 -> 161808
  float* rope   = ws + 161808;                 // 131072 -> 292880
  u16*   tokbf  = (u16*)(ws + 292880);         // 4194304 u16 -> 2390032
  u16*   wqkvt  = (u16*)(ws + 2390032);        // 786432 u16 -> 2783248
  u16*   woutt  = (u16*)(ws + 2783248);        // 262144 u16 -> 2914320
  u16*   ffwt   = (u16*)(ws + 2914320);        // 262144 u16 -> 3045392
  u16*   wtN2   = (u16*)(ws + 3045392);        // 2359296 u16 -> 4225040
  u16*   wtW2   = (u16*)(ws + 4225040);        // 2359296 u16 -> 5404688
  u16*   qb     = (u16*)(ws + 5404688);        // 4194304 u16 -> 7501840
  u16*   W2t    = (u16*)(ws + 7501840);        // 1048576 u16 -> 8026128
  u16*   attnb  = (u16*)(ws + 8026128);        // 4194304 u16 -> 10123280
  float* qkv    = ws + 10123280;               // 12582912 -> 22706192 (~91 MB)
  // overlays inside qkv region (k/v dead after ctx_k)
  u16*   cpadb  = (u16*)qkv;                   // 4276224 u16 = 2138112 fl
  u16*   Dnb    = (u16*)(qkv + 2138112);       // 4194304 u16 = 2097152 fl
  u16*   Dwb    = (u16*)(qkv + 4235264);       // 4194304 u16 -> 6332416 fl  (< 12582912)
  u16*   Eb     = attnb;                       // attnb dead after ln1
  u16*   t1b    = tokbf;                       // tokens dead after qkv gemm

  float* p_bout = params;        float* p_bnar = params + 512;
  float* p_bwid = params + 1024; float* p_l1g  = params + 1536;
  float* p_l1b  = params + 2048; float* p_ffb  = params + 2560;
  float* p_l2g  = params + 3072; float* p_l2b  = params + 3584;

  sniff_k<<<dim3(1), dim3(256), 0, stream>>>((const u16*)tokens, (const unsigned int*)mask, flags);
  misc_k<<<dim3(8192), dim3(256), 0, stream>>>(mask, tokens, b_out, b_narrow, b_wide, ln1_g, ln1_b,
                                               ff_b, ln2_g, ln2_b, flags, rope, m32, params, ctx,
                                               kS, tokbf);
  prep2_k<<<dim3(1600), dim3(256), 0, stream>>>(w_qkv, w_out, ff_w, w_narrow, w_wide, flags,
                                                wqkvt, woutt, ffwt, wtN2, wtW2);

  // qkv = tokens @ w_qkv  (8192 x 1536, K=512)
  mgemm_k<false,false><<<dim3(12, 64), dim3(256), 0, stream>>>(
      tokbf, wqkvt, nullptr, qkv, NROWS, 1536, 512);

  // q-softmax + v-mask + k-colmax(seg) in one launch
  qvks_k<<<dim3(NROWS + 256), dim3(512), 0, stream>>>(rope, m32, qkv, qb, kredM);

  // ctx with fused k-exp, inline kM reduction, and S accumulation
  ctx_k<<<dim3(32, 8), dim3(256), 0, stream>>>(qkv, rope, m32, kredM, ctx, kS);

  // W2t[b] = (blockdiag(ctx_b)/S) @ w_out; + cpad edge zero
  ctxw_k<<<dim3(352), dim3(256), 0, stream>>>(ctx, kS, woutt, W2t, cpadb);

  // attn = qb @ W2t[b]^T + b_out (bf16); fused masked cpad write
  mgemm_attn64_k<<<dim3(4, 32, 4), dim3(256), 0, stream>>>(qb, W2t, p_bout, m32, attnb, cpadb);

  // convs: 128x64 tiles, 4 blocks/CU, single-buffer W + reg prefetch
  mconv5_k<<<dim3(8, 16, 8), dim3(256), 0, stream>>>(cpadb, wtN2, wtW2, p_bnar, p_bwid, Dnb, Dwb);

  // t1 = LN(attn + Dn + Dw) -> bf16
  ln_k<2,1><<<dim3(NROWS), dim3(256), 0, stream>>>(attnb, Dnb, Dwb, p_l1g, p_l1b, flags, (void*)t1b);

  // E = gelu(t1 @ ff_w + ff_b) -> bf16
  mgemm64b_k<true,true><<<dim3(4, 128), dim3(256), 0, stream>>>(
      t1b, ffwt, p_ffb, Eb, NROWS, 512, 512);

  // out = LN(E) -> d_out, dtype per flags
  ln_k<0,2><<<dim3(NROWS), dim3(256), 0, stream>>>(Eb, nullptr, nullptr, p_l2g, p_l2b, flags, d_out);
}

// Round 8
// 353.306 us; speedup vs baseline: 5.5774x; 1.0367x over previous
//
#include <hip/hip_runtime.h>
#include <hip/hip_bf16.h>

#define BB 4
#define NN 2048
#define NROWS (BB*NN)   // 8192

typedef unsigned short u16;
typedef __bf16 bf16x8 __attribute__((ext_vector_type(8)));
typedef u16    u16x8  __attribute__((ext_vector_type(8)));
typedef float  fx4    __attribute__((ext_vector_type(4)));

__device__ __forceinline__ float bf2f(u16 u){
  union { float f; unsigned int i; } x; x.i = ((unsigned int)u) << 16; return x.f;
}
__device__ __forceinline__ u16 f2bf(float f){
  union { float f; unsigned int i; } x; x.f = f;
  unsigned int i = x.i;
  i += 0x7fffu + ((i >> 16) & 1u);
  return (u16)(i >> 16);
}
__device__ __forceinline__ float geluf(float x){
  return 0.5f * x * (1.0f + erff(x * 0.70710678118654752f));
}

// flags[0]=1 if float inputs fp32 (else bf16); flags[1]=1 if mask byte-packed
__global__ __launch_bounds__(256) void sniff_k(const u16* tokens, const unsigned int* mask, int* flags){
  __shared__ int s_f32, s_byte;
  if (threadIdx.x == 0) { s_f32 = 0; s_byte = 0; }
  __syncthreads();
  for (int i = threadIdx.x; i < 4096; i += 256) {
    float v = bf2f(tokens[i]);
    if (!(fabsf(v) < 1e10f)) atomicOr(&s_f32, 1);
  }
  for (int i = threadIdx.x; i < 2048; i += 256) {
    if (mask[i] > 1u) atomicOr(&s_byte, 1);
  }
  __syncthreads();
  if (threadIdx.x == 0) { flags[0] = s_f32; flags[1] = s_byte; }
}

// rope + m32 + params + zero(ctx,kS) + tokbf in one grid-stride launch
__global__ __launch_bounds__(256) void misc_k(const void* mask, const void* tokens,
                                              const void* p0, const void* p1, const void* p2,
                                              const void* p3, const void* p4, const void* p5,
                                              const void* p6, const void* p7,
                                              const int* flags, float* rope, int* m32,
                                              float* params, float* ctx, float* kS, u16* tokbf){
  const void* srcs[8] = {p0,p1,p2,p3,p4,p5,p6,p7};
  int f32 = flags[0], mbyte = flags[1];
  const int T = 131072 + 8192 + 4096 + 131072 + 2048 + 4194304;
  for (int i = blockIdx.x*256 + threadIdx.x; i < T; i += gridDim.x*256) {
    if (i < 131072) {
      int p = i >> 6, j = i & 63;
      int jj = (j < 32) ? j : j - 32;
      float invf = exp2f(-(float)jj * (13.287712379549449f/32.0f));  // 10000^(-jj/32)
      float prod = (float)p * invf;
      rope[i] = (j < 32) ? sinf(prod) : cosf(prod);
    } else if (i < 139264) {
      int k = i - 131072;
      int v = mbyte ? (int)((const unsigned char*)mask)[k] : ((const int*)mask)[k];
      m32[k] = v ? 1 : 0;
    } else if (i < 143360) {
      int k = i - 139264;
      int pid = k >> 9, j = k & 511;
      const void* s = srcs[pid];
      params[k] = f32 ? ((const float*)s)[j] : bf2f(((const u16*)s)[j]);
    } else if (i < 274432) {
      ctx[i - 143360] = 0.0f;
    } else if (i < 276480) {
      kS[i - 274432] = 0.0f;
    } else {
      int k = i - 276480;
      tokbf[k] = f32 ? f2bf(((const float*)tokens)[k]) : ((const u16*)tokens)[k];
    }
  }
}

// merged weight prep: blocks [0,1024): conv weights w[o][c][kk] -> W2[kk][o][c];
// blocks [1024,1600): LDS tile transpose [K][N]->[N][K] for the three dense weights
__global__ __launch_bounds__(256) void prep2_k(const void* w_qkv, const void* w_out, const void* ff_w,
                                               const void* w_narrow, const void* w_wide,
                                               const int* flags,
                                               u16* wqkvt, u16* woutt, u16* ffwt,
                                               u16* wtN2, u16* wtW2){
  int bid = blockIdx.x;
  int f = flags[0];
  int tid = threadIdx.x;
  if (bid < 1024) {
    int tensor = bid >> 9, o = bid & 511;
    const void* src = tensor ? w_wide : w_narrow;
    u16* dst = tensor ? wtW2 : wtN2;
    __shared__ u16 Ls[4608];
    for (int i = tid; i < 4608; i += 256) {
      Ls[i] = f ? f2bf(((const float*)src)[(size_t)o*4608 + i]) : ((const u16*)src)[(size_t)o*4608 + i];
    }
    __syncthreads();
    #pragma unroll
    for (int kk = 0; kk < 9; kk++) {
      #pragma unroll
      for (int u = 0; u < 2; u++) {
        int c = tid + u*256;
        dst[(size_t)kk*262144 + o*512 + c] = Ls[c*9 + kk];
      }
    }
  } else {
    int id = bid - 1024;
    int z = id / 192;
    int rem = id - z*192;
    int x = rem % 24, y = rem / 24;
    int Nn = (z == 0) ? 1536 : 512;
    if (x * 64 >= Nn) return;
    const void* src = (z == 0) ? w_qkv : (z == 1) ? w_out : ff_w;
    u16* dst = (z == 0) ? wqkvt : (z == 1) ? woutt : ffwt;
    __shared__ u16 Ts[64][72];
    int n0 = x * 64, k0 = y * 64;
    int r = tid >> 2, cq = (tid & 3) * 16;
    #pragma unroll
    for (int u = 0; u < 2; u++) {
      int c = cq + u*8;
      int sidx = (k0 + r)*Nn + n0 + c;
      u16x8 v;
      if (f) {
        #pragma unroll
        for (int j = 0; j < 8; j++) v[j] = f2bf(((const float*)src)[sidx + j]);
      } else {
        v = *(const u16x8*)&((const u16*)src)[sidx];
      }
      *(u16x8*)&Ts[r][c] = v;
    }
    __syncthreads();
    #pragma unroll
    for (int u = 0; u < 2; u++) {
      int c = cq + u*8;
      u16x8 v;
      #pragma unroll
      for (int j = 0; j < 8; j++) v[j] = Ts[c + j][r];
      *(u16x8*)&dst[(size_t)(n0 + r)*512 + k0 + c] = v;
    }
  }
}

// ---- qkv GEMM (128x128 tile) with fused q-softmax / k-exp / v-mask epilogue ----
// blockIdx.x: 0..3 -> q cols, 4..7 -> k cols, 8..11 -> v cols. M=0 softmax trick (exact).
__global__ __launch_bounds__(256) void mgemm_qkv_k(const u16* A, const u16* Bt, const float* rope,
                                                   const int* mask, u16* qb, u16* keb, u16* vb){
  __shared__ u16 As[128][40];
  __shared__ u16 Bs[128][40];
  __shared__ int smask[128];
  int tid = threadIdx.x;
  int lane = tid & 63;
  int wave = tid >> 6;
  int wm = (wave >> 1) * 64, wn = (wave & 1) * 64;
  int quad = lane >> 4, l16 = lane & 15;
  int m0 = blockIdx.y * 128, n0 = blockIdx.x * 128;
  fx4 acc[4][4] = {};
  int ar = tid >> 2;
  int ac = (tid & 3) * 8;
  for (int k0 = 0; k0 < 512; k0 += 32) {
    *(u16x8*)&As[ar][ac]    = *(const u16x8*)&A[(size_t)(m0+ar)*512 + k0 + ac];
    *(u16x8*)&As[ar+64][ac] = *(const u16x8*)&A[(size_t)(m0+ar+64)*512 + k0 + ac];
    *(u16x8*)&Bs[ar][ac]    = *(const u16x8*)&Bt[(size_t)(n0+ar)*512 + k0 + ac];
    *(u16x8*)&Bs[ar+64][ac] = *(const u16x8*)&Bt[(size_t)(n0+ar+64)*512 + k0 + ac];
    __syncthreads();
    bf16x8 af[4], bfv[4];
    #pragma unroll
    for (int i = 0; i < 4; i++)
      af[i] = __builtin_bit_cast(bf16x8, *(const u16x8*)&As[wm + i*16 + l16][quad*8]);
    #pragma unroll
    for (int j = 0; j < 4; j++)
      bfv[j] = __builtin_bit_cast(bf16x8, *(const u16x8*)&Bs[wn + j*16 + l16][quad*8]);
    #pragma unroll
    for (int i = 0; i < 4; i++)
      #pragma unroll
      for (int j = 0; j < 4; j++)
        acc[i][j] = __builtin_amdgcn_mfma_f32_16x16x32_bf16(af[i], bfv[j], acc[i][j], 0, 0, 0);
    __syncthreads();
  }
  int x = blockIdx.x;
  if (x >= 4) {
    if (tid < 128) smask[tid] = mask[m0 + tid];
    __syncthreads();
  }
  if (x < 4) {
    // q: softmax over d (64 cols = 4 regs x 16 lanes), scale 1/8, bf16 out
    #pragma unroll
    for (int i = 0; i < 4; i++)
      #pragma unroll
      for (int r = 0; r < 4; r++) {
        int rl = wm + i*16 + quad*4 + r;
        int row = m0 + rl;
        int nseq = row & (NN-1);
        const float* rp = rope + nseq*64 + l16;
        float e0 = __expf(acc[i][0][r] + rp[0]);
        float e1 = __expf(acc[i][1][r] + rp[16]);
        float e2 = __expf(acc[i][2][r] + rp[32]);
        float e3 = __expf(acc[i][3][r] + rp[48]);
        float s = e0 + e1 + e2 + e3;
        s += __shfl_xor(s, 1); s += __shfl_xor(s, 2);
        s += __shfl_xor(s, 4); s += __shfl_xor(s, 8);
        float sc = 0.125f / s;
        size_t base = (size_t)row*512 + n0 + wn + l16;
        qb[base]      = f2bf(e0*sc);
        qb[base + 16] = f2bf(e1*sc);
        qb[base + 32] = f2bf(e2*sc);
        qb[base + 48] = f2bf(e3*sc);
      }
  } else if (x < 8) {
    // k: ke = mask ? exp(k + rope) : 0 (bf16)
    #pragma unroll
    for (int i = 0; i < 4; i++)
      #pragma unroll
      for (int r = 0; r < 4; r++) {
        int rl = wm + i*16 + quad*4 + r;
        int row = m0 + rl;
        int nseq = row & (NN-1);
        int mk = smask[rl];
        const float* rp = rope + nseq*64 + l16;
        size_t base = (size_t)row*512 + (n0 - 512) + wn + l16;
        #pragma unroll
        for (int j = 0; j < 4; j++) {
          float ke = mk ? __expf(acc[i][j][r] + rp[j*16]) : 0.0f;
          keb[base + j*16] = f2bf(ke);
        }
      }
  } else {
    // v: masked bf16
    #pragma unroll
    for (int i = 0; i < 4; i++)
      #pragma unroll
      for (int r = 0; r < 4; r++) {
        int rl = wm + i*16 + quad*4 + r;
        int row = m0 + rl;
        int mk = smask[rl];
        size_t base = (size_t)row*512 + (n0 - 1024) + wn + l16;
        #pragma unroll
        for (int j = 0; j < 4; j++)
          vb[base + j*16] = mk ? f2bf(acc[i][j][r]) : (u16)0;
      }
  }
}

#define FMA16(a, b, acc) \
  acc[0][0] = fmaf(a.x, b.x, acc[0][0]); acc[0][1] = fmaf(a.x, b.y, acc[0][1]); \
  acc[0][2] = fmaf(a.x, b.z, acc[0][2]); acc[0][3] = fmaf(a.x, b.w, acc[0][3]); \
  acc[1][0] = fmaf(a.y, b.x, acc[1][0]); acc[1][1] = fmaf(a.y, b.y, acc[1][1]); \
  acc[1][2] = fmaf(a.y, b.z, acc[1][2]); acc[1][3] = fmaf(a.y, b.w, acc[1][3]); \
  acc[2][0] = fmaf(a.z, b.x, acc[2][0]); acc[2][1] = fmaf(a.z, b.y, acc[2][1]); \
  acc[2][2] = fmaf(a.z, b.z, acc[2][2]); acc[2][3] = fmaf(a.z, b.w, acc[2][3]); \
  acc[3][0] = fmaf(a.w, b.x, acc[3][0]); acc[3][1] = fmaf(a.w, b.y, acc[3][1]); \
  acc[3][2] = fmaf(a.w, b.z, acc[3][2]); acc[3][3] = fmaf(a.w, b.w, acc[3][3]);

// ctx[bh][d][e] += sum_n ke[n,d]*v[n,e] (bf16 inputs, exp/mask pre-applied); S[bh][d] += sum ke
__global__ __launch_bounds__(256) void ctx_k(const u16* keb, const u16* vb, float* ctx, float* Sg){
  int bh = blockIdx.x, seg = blockIdx.y;
  int b = bh >> 3, h = bh & 7;
  __shared__ float Ks[32][68], Vs[32][68];
  __shared__ float sS[64];
  int tid = threadIdx.x, tx = tid & 15, ty = tid >> 4;
  if (tid < 64) sS[tid] = 0.0f;
  float acc[4][4] = {{0.f,0.f,0.f,0.f},{0.f,0.f,0.f,0.f},{0.f,0.f,0.f,0.f},{0.f,0.f,0.f,0.f}};
  float sp[8] = {0,0,0,0,0,0,0,0};
  int nl = tid >> 3, dcol = (tid & 7)*8;
  const u16* kp0 = keb + (size_t)(b*NN + seg*256)*512 + h*64 + dcol;
  const u16* vp0 = vb  + (size_t)(b*NN + seg*256)*512 + h*64 + dcol;
  for (int nc = 0; nc < 256; nc += 32) {
    u16x8 ku = *(const u16x8*)(kp0 + (size_t)(nc + nl)*512);
    u16x8 vu = *(const u16x8*)(vp0 + (size_t)(nc + nl)*512);
    float a[8], bb[8];
    #pragma unroll
    for (int t = 0; t < 8; t++) { a[t] = bf2f(ku[t]); bb[t] = bf2f(vu[t]); sp[t] += a[t]; }
    *(float4*)&Ks[nl][dcol]   = (float4){a[0],a[1],a[2],a[3]};
    *(float4*)&Ks[nl][dcol+4] = (float4){a[4],a[5],a[6],a[7]};
    *(float4*)&Vs[nl][dcol]   = (float4){bb[0],bb[1],bb[2],bb[3]};
    *(float4*)&Vs[nl][dcol+4] = (float4){bb[4],bb[5],bb[6],bb[7]};
    __syncthreads();
    #pragma unroll
    for (int q = 0; q < 32; q++) {
      float4 a4 = *(const float4*)&Ks[q][ty*4];
      float4 b4 = *(const float4*)&Vs[q][tx*4];
      FMA16(a4, b4, acc)
    }
    __syncthreads();
  }
  #pragma unroll
  for (int j = 0; j < 8; j++) atomicAdd(&sS[dcol + j], sp[j]);
  float* cp = ctx + (size_t)bh*4096;
  #pragma unroll
  for (int i = 0; i < 4; i++)
    #pragma unroll
    for (int j = 0; j < 4; j++)
      atomicAdd(&cp[(ty*4 + i)*64 + tx*4 + j], acc[i][j]);
  __syncthreads();
  if (tid < 64) atomicAdd(&Sg[bh*64 + tid], sS[tid]);
}

// merged: ctxw (blocks 0..31) + cpad-edge-zero (blocks 32..351)
// W2t[b][o][h*64+d] = sum_e (ctx[b,h][d][e]/S[d]) * woutt[o][h*64+e]
__global__ __launch_bounds__(256) void ctxw_k(const float* ctx, const float* Sg, const u16* woutt,
                                              u16* W2t, u16* cpadb){
  int bx = blockIdx.x;
  int tid = threadIdx.x;
  if (bx >= 32) {
    int idx = (bx - 32)*256 + tid;
    if (idx < BB*40*512) {
      int c = idx & 511;
      int t = (idx >> 9) % 40;
      int b = idx / (40*512);
      int tt = (t < 20) ? t : 2048 + t;
      cpadb[((size_t)b*2088 + tt)*512 + c] = 0;
    }
    return;
  }
  int h = bx & 7, b = bx >> 3;
  int lane = tid & 63, wave = tid >> 6;
  int quad = lane >> 4, l16 = lane & 15;
  const float* cp = ctx + (size_t)(b*8 + h)*4096;
  fx4 acc[8][4] = {};
  #pragma unroll
  for (int ks = 0; ks < 2; ks++) {
    bf16x8 bfv[4];
    #pragma unroll
    for (int j = 0; j < 4; j++) {
      int d = j*16 + l16;
      float S = Sg[(b*8 + h)*64 + d];
      float rs = (S > 0.0f) ? 1.0f/S : 0.0f;
      const float* src = cp + d*64 + ks*32 + quad*8;
      float4 v0 = *(const float4*)src, v1 = *(const float4*)(src + 4);
      bf16x8 t;
      t[0]=(__bf16)(v0.x*rs); t[1]=(__bf16)(v0.y*rs); t[2]=(__bf16)(v0.z*rs); t[3]=(__bf16)(v0.w*rs);
      t[4]=(__bf16)(v1.x*rs); t[5]=(__bf16)(v1.y*rs); t[6]=(__bf16)(v1.z*rs); t[7]=(__bf16)(v1.w*rs);
      bfv[j] = t;
    }
    #pragma unroll
    for (int i = 0; i < 8; i++) {
      int orow = wave*128 + i*16 + l16;
      bf16x8 afr = __builtin_bit_cast(bf16x8, *(const u16x8*)&woutt[(size_t)orow*512 + h*64 + ks*32 + quad*8]);
      #pragma unroll
      for (int j = 0; j < 4; j++)
        acc[i][j] = __builtin_amdgcn_mfma_f32_16x16x32_bf16(afr, bfv[j], acc[i][j], 0, 0, 0);
    }
  }
  u16* out = W2t + (size_t)b*262144;
  #pragma unroll
  for (int i = 0; i < 8; i++)
    #pragma unroll
    for (int j = 0; j < 4; j++)
      #pragma unroll
      for (int r = 0; r < 4; r++) {
        int orow = wave*128 + i*16 + quad*4 + r;
        out[(size_t)orow*512 + h*64 + j*16 + l16] = f2bf(acc[i][j][r]);
      }
}

// ---- batched attn GEMM (M-tile 64): attnb = bf16(qb[b] @ W2t[b]^T + b_out); fused masked cpad ----
__global__ __launch_bounds__(256) void mgemm_attn64_k(const u16* qb, const u16* W2t, const float* bias,
                                                      const int* mask, u16* attnb, u16* cpadb){
  __shared__ u16 As[64][40];
  __shared__ u16 Bs[128][40];
  int tid = threadIdx.x;
  int lane = tid & 63;
  int wave = tid >> 6;
  int wn = wave * 32;
  int quad = lane >> 4, l16 = lane & 15;
  int m0 = blockIdx.y * 64, n0 = blockIdx.x * 128, b = blockIdx.z;
  const u16* A  = qb  + (size_t)b*2048*512;
  const u16* Bt = W2t + (size_t)b*262144;
  fx4 acc[4][2] = {};
  int ar = tid >> 2;
  int ac = (tid & 3) * 8;
  for (int k0 = 0; k0 < 512; k0 += 32) {
    *(u16x8*)&As[ar][ac]    = *(const u16x8*)&A[(size_t)(m0+ar)*512 + k0 + ac];
    *(u16x8*)&Bs[ar][ac]    = *(const u16x8*)&Bt[(size_t)(n0+ar)*512 + k0 + ac];
    *(u16x8*)&Bs[ar+64][ac] = *(const u16x8*)&Bt[(size_t)(n0+ar+64)*512 + k0 + ac];
    __syncthreads();
    bf16x8 af[4], bfv[2];
    #pragma unroll
    for (int i = 0; i < 4; i++)
      af[i] = __builtin_bit_cast(bf16x8, *(const u16x8*)&As[i*16 + l16][quad*8]);
    #pragma unroll
    for (int j = 0; j < 2; j++)
      bfv[j] = __builtin_bit_cast(bf16x8, *(const u16x8*)&Bs[wn + j*16 + l16][quad*8]);
    #pragma unroll
    for (int i = 0; i < 4; i++)
      #pragma unroll
      for (int j = 0; j < 2; j++)
        acc[i][j] = __builtin_amdgcn_mfma_f32_16x16x32_bf16(af[i], bfv[j], acc[i][j], 0, 0, 0);
    __syncthreads();
  }
  #pragma unroll
  for (int i = 0; i < 4; i++)
    #pragma unroll
    for (int j = 0; j < 2; j++) {
      int col = n0 + wn + j*16 + l16;
      float bv = bias[col];
      #pragma unroll
      for (int r = 0; r < 4; r++) {
        int row_l = m0 + i*16 + quad*4 + r;
        float v = acc[i][j][r] + bv;
        u16 vbb = f2bf(v);
        attnb[((size_t)b*2048 + row_l)*512 + col] = vbb;
        int mk = mask[b*2048 + row_l];
        cpadb[((size_t)b*2088 + row_l + 20)*512 + col] = mk ? vbb : (u16)0;
      }
    }
}

// ---- conv: 128t x 128o block tile, 2x2 waves of 64x64, single-buffer W + reg prefetch ----
// LDS 42.6KB -> 2 blocks/CU resident (grid 512). bf16 out. grid (4 o, 16 t, 8 = b*2+cid)
__global__ __launch_bounds__(256, 2) void mconv6_k(const u16* cpad, const u16* Wn, const u16* Ww,
                                                   const float* bias_n, const float* bias_w,
                                                   u16* Dn, u16* Dw){
  __shared__ u16 As[168][72];
  __shared__ u16 Ws[128][72];
  int tid = threadIdx.x;
  int lane = tid & 63;
  int wave = tid >> 6;
  int wm = (wave >> 1) * 64;    // t-offset within 128
  int wo = (wave & 1) * 64;     // o-offset within 128
  int quad = lane >> 4, l16 = lane & 15;
  int o0 = blockIdx.x * 128, m0 = blockIdx.y * 128;
  int b = blockIdx.z >> 1, cid = blockIdx.z & 1;
  const u16* W = cid ? Ww : Wn;
  const float* bias = cid ? bias_w : bias_n;
  u16* D = cid ? Dw : Dn;
  fx4 acc[4][4] = {};
  const u16* cb = cpad + ((size_t)b*2088 + m0)*512;
  for (int c0 = 0; c0 < 512; c0 += 64) {
    __syncthreads();   // previous chunk's readers of As/Ws done
    // stage A: 168 rows x 64 u16
    for (int idx = tid; idx < 168*8; idx += 256) {
      int r = idx >> 3, off = (idx & 7)*8;
      *(u16x8*)&As[r][off] = *(const u16x8*)&cb[(size_t)r*512 + c0 + off];
    }
    // prefetch tap-0 weights (128 o x 64 c) into regs
    u16x8 pre[4];
    {
      const u16* wp = W + (size_t)o0*512 + c0;
      #pragma unroll
      for (int u = 0; u < 4; u++) {
        int idx = tid + u*256;
        int r = idx >> 3, off = (idx & 7)*8;
        pre[u] = *(const u16x8*)&wp[(size_t)r*512 + off];
      }
    }
    #pragma unroll
    for (int kk = 0; kk < 9; kk++) {
      if (kk > 0) __syncthreads();   // readers of tap kk-1 done before Ws overwrite
      #pragma unroll
      for (int u = 0; u < 4; u++) {
        int idx = tid + u*256;
        int r = idx >> 3, off = (idx & 7)*8;
        *(u16x8*)&Ws[r][off] = pre[u];
      }
      if (kk < 8) {
        const u16* wp = W + (size_t)(kk+1)*262144 + (size_t)o0*512 + c0;
        #pragma unroll
        for (int u = 0; u < 4; u++) {
          int idx = tid + u*256;
          int r = idx >> 3, off = (idx & 7)*8;
          pre[u] = *(const u16x8*)&wp[(size_t)r*512 + off];
        }
      }
      __syncthreads();               // Ws (and As for kk==0) visible
      int shift = cid ? 5*kk : 16 + kk;
      #pragma unroll
      for (int ks = 0; ks < 2; ks++) {
        bf16x8 bfv[4];
        #pragma unroll
        for (int j = 0; j < 4; j++)
          bfv[j] = __builtin_bit_cast(bf16x8, *(const u16x8*)&Ws[wo + j*16 + l16][ks*32 + quad*8]);
        #pragma unroll
        for (int i = 0; i < 4; i++) {
          bf16x8 afr = __builtin_bit_cast(bf16x8, *(const u16x8*)&As[shift + wm + i*16 + l16][ks*32 + quad*8]);
          #pragma unroll
          for (int j = 0; j < 4; j++)
            acc[i][j] = __builtin_amdgcn_mfma_f32_16x16x32_bf16(afr, bfv[j], acc[i][j], 0, 0, 0);
        }
      }
    }
  }
  #pragma unroll
  for (int i = 0; i < 4; i++)
    #pragma unroll
    for (int j = 0; j < 4; j++) {
      int col = o0 + wo + j*16 + l16;
      float bv = bias[col];
      #pragma unroll
      for (int r = 0; r < 4; r++) {
        int row = b*2048 + m0 + wm + i*16 + quad*4 + r;
        D[(size_t)row*512 + col] = f2bf(geluf(acc[i][j][r] + bv));
      }
    }
}

// ---------------- MFMA bf16 GEMM, M-tile 64, bf16 out ----------------
template<bool BIAS, bool GELU>
__global__ __launch_bounds__(256) void mgemm64b_k(const u16* A, const u16* Bt, const float* bias,
                                                  u16* C, int M, int N, int K){
  __shared__ u16 As[64][40];
  __shared__ u16 Bs[128][40];
  int tid = threadIdx.x;
  int lane = tid & 63;
  int wave = tid >> 6;
  int wn = wave * 32;
  int quad = lane >> 4, l16 = lane & 15;
  int m0 = blockIdx.y * 64, n0 = blockIdx.x * 128;
  fx4 acc[4][2] = {};
  int ar = tid >> 2;
  int ac = (tid & 3) * 8;
  for (int k0 = 0; k0 < K; k0 += 32) {
    *(u16x8*)&As[ar][ac]    = *(const u16x8*)&A[(size_t)(m0+ar)*K + k0 + ac];
    *(u16x8*)&Bs[ar][ac]    = *(const u16x8*)&Bt[(size_t)(n0+ar)*K + k0 + ac];
    *(u16x8*)&Bs[ar+64][ac] = *(const u16x8*)&Bt[(size_t)(n0+ar+64)*K + k0 + ac];
    __syncthreads();
    bf16x8 af[4], bfv[2];
    #pragma unroll
    for (int i = 0; i < 4; i++)
      af[i] = __builtin_bit_cast(bf16x8, *(const u16x8*)&As[i*16 + l16][quad*8]);
    #pragma unroll
    for (int j = 0; j < 2; j++)
      bfv[j] = __builtin_bit_cast(bf16x8, *(const u16x8*)&Bs[wn + j*16 + l16][quad*8]);
    #pragma unroll
    for (int i = 0; i < 4; i++)
      #pragma unroll
      for (int j = 0; j < 2; j++)
        acc[i][j] = __builtin_amdgcn_mfma_f32_16x16x32_bf16(af[i], bfv[j], acc[i][j], 0, 0, 0);
    __syncthreads();
  }
  #pragma unroll
  for (int i = 0; i < 4; i++)
    #pragma unroll
    for (int j = 0; j < 2; j++) {
      int col = n0 + wn + j*16 + l16;
      float bv = BIAS ? bias[col] : 0.0f;
      #pragma unroll
      for (int r = 0; r < 4; r++) {
        int row = m0 + i*16 + quad*4 + r;
        float v = acc[i][j][r] + bv;
        if (GELU) v = geluf(v);
        C[(size_t)row*N + col] = f2bf(v);
      }
    }
}

__device__ __forceinline__ float block_sum512(float v, float* red){
  #pragma unroll
  for (int o = 32; o; o >>= 1) v += __shfl_xor(v, o, 64);
  int w = threadIdx.x >> 6;
  if ((threadIdx.x & 63) == 0) red[w] = v;
  __syncthreads();
  float t = red[0] + red[1] + red[2] + red[3];
  __syncthreads();
  return t;
}

// LN over 512 with bf16 inputs; NADD extra inputs; OM=1: bf16 out; OM=2: flags[0]? fp32 : bf16
template<int NADD, int OM>
__global__ __launch_bounds__(256) void ln_k(const u16* X, const u16* Y, const u16* Z,
                                            const float* g, const float* be,
                                            const int* flags, void* out){
  __shared__ float red[4];
  size_t row = blockIdx.x;
  int tid = threadIdx.x;
  const u16* xp = X + row*512;
  float x0 = bf2f(xp[tid]), x1 = bf2f(xp[tid + 256]);
  if (NADD >= 1) { const u16* yp = Y + row*512; x0 += bf2f(yp[tid]); x1 += bf2f(yp[tid + 256]); }
  if (NADD >= 2) { const u16* zp = Z + row*512; x0 += bf2f(zp[tid]); x1 += bf2f(zp[tid + 256]); }
  float mean = block_sum512(x0 + x1, red) * (1.0f/512.0f);
  float d0 = x0 - mean, d1 = x1 - mean;
  float var = block_sum512(d0*d0 + d1*d1, red) * (1.0f/512.0f);
  float inv = rsqrtf(var + 1e-5f);
  float r0 = d0*inv*g[tid]       + be[tid];
  float r1 = d1*inv*g[tid + 256] + be[tid + 256];
  bool obf = (OM == 1) || (OM == 2 && !flags[0]);
  if (obf) {
    u16* op = (u16*)out;
    op[row*512 + tid]       = f2bf(r0);
    op[row*512 + tid + 256] = f2bf(r1);
  } else {
    float* op = (float*)out;
    op[row*512 + tid]       = r0;
    op[row*512 + tid + 256] = r1;
  }
}

extern "C" void kernel_launch(void* const* d_in, const int* in_sizes, int n_in,
                              void* d_out, int out_size, void* d_ws, size_t ws_size,
                              hipStream_t stream) {
  const void* tokens   = d_in[0];
  const void* mask     = d_in[1];
  const void* w_qkv    = d_in[2];
  const void* w_out    = d_in[3];
  const void* b_out    = d_in[4];
  const void* w_narrow = d_in[5];
  const void* b_narrow = d_in[6];
  const void* w_wide   = d_in[7];
  const void* b_wide   = d_in[8];
  const void* ln1_g    = d_in[9];
  const void* ln1_b    = d_in[10];
  const void* ff_w     = d_in[11];
  const void* ff_b     = d_in[12];
  const void* ln2_g    = d_in[13];
  const void* ln2_b    = d_in[14];

  float* ws = (float*)d_ws;
  int*   flags  = (int*)ws;                    // 16
  int*   m32    = (int*)(ws + 16);             // 8192 -> 8208
  float* params = ws + 8208;                   // 4096 -> 12304
  float* kS     = ws + 12304;                  // 2048 -> 14352
  float* ctx    = ws + 14352;                  // 131072 -> 145424
  float* rope   = ws + 145424;                 // 131072 -> 276496
  u16*   tokbf  = (u16*)(ws + 276496);         // 4194304 u16 -> 2373648
  u16*   wqkvt  = (u16*)(ws + 2373648);        // 786432 u16 -> 2766864
  u16*   woutt  = (u16*)(ws + 2766864);        // 262144 u16 -> 2897936
  u16*   ffwt   = (u16*)(ws + 2897936);        // 262144 u16 -> 3029008
  u16*   wtN2   = (u16*)(ws + 3029008);        // 2359296 u16 -> 4208656
  u16*   wtW2   = (u16*)(ws + 4208656);        // 2359296 u16 -> 5388304
  u16*   qb     = (u16*)(ws + 5388304);        // 4194304 u16 -> 7485456
  u16*   keb    = (u16*)(ws + 7485456);        // 4194304 u16 -> 9582608
  u16*   vb     = (u16*)(ws + 9582608);        // 4194304 u16 -> 11679760
  u16*   W2t    = (u16*)(ws + 11679760);       // 1048576 u16 -> 12204048
  u16*   attnb  = (u16*)(ws + 12204048);       // 4194304 u16 -> 14301200
  u16*   cpadb  = (u16*)(ws + 14301200);       // 4276224 u16 -> 16439312
  u16*   Dnb    = (u16*)(ws + 16439312);       // 4194304 u16 -> 18536464
  u16*   Dwb    = (u16*)(ws + 18536464);       // 4194304 u16 -> 20633616 (~82.5 MB)
  u16*   Eb     = attnb;                       // attnb dead after ln1
  u16*   t1b    = tokbf;                       // tokens dead after qkv gemm

  float* p_bout = params;        float* p_bnar = params + 512;
  float* p_bwid = params + 1024; float* p_l1g  = params + 1536;
  float* p_l1b  = params + 2048; float* p_ffb  = params + 2560;
  float* p_l2g  = params + 3072; float* p_l2b  = params + 3584;

  sniff_k<<<dim3(1), dim3(256), 0, stream>>>((const u16*)tokens, (const unsigned int*)mask, flags);
  misc_k<<<dim3(8192), dim3(256), 0, stream>>>(mask, tokens, b_out, b_narrow, b_wide, ln1_g, ln1_b,
                                               ff_b, ln2_g, ln2_b, flags, rope, m32, params, ctx,
                                               kS, tokbf);
  prep2_k<<<dim3(1600), dim3(256), 0, stream>>>(w_qkv, w_out, ff_w, w_narrow, w_wide, flags,
                                                wqkvt, woutt, ffwt, wtN2, wtW2);

  // qkv GEMM with fused q-softmax / k-exp / v-mask epilogue (M=0 softmax trick)
  mgemm_qkv_k<<<dim3(12, 64), dim3(256), 0, stream>>>(
      tokbf, wqkvt, rope, m32, qb, keb, vb);

  // ctx = ke^T @ v (+ S accumulation), bf16 inputs
  ctx_k<<<dim3(32, 8), dim3(256), 0, stream>>>(keb, vb, ctx, kS);

  // W2t[b] = (blockdiag(ctx_b)/S) @ w_out; + cpad edge zero
  ctxw_k<<<dim3(352), dim3(256), 0, stream>>>(ctx, kS, woutt, W2t, cpadb);

  // attn = qb @ W2t[b]^T + b_out (bf16); fused masked cpad write
  mgemm_attn64_k<<<dim3(4, 32, 4), dim3(256), 0, stream>>>(qb, W2t, p_bout, m32, attnb, cpadb);

  // convs: 128x128 tiles (2x2 waves of 64x64), single-buffer W + reg prefetch
  mconv6_k<<<dim3(4, 16, 8), dim3(256), 0, stream>>>(cpadb, wtN2, wtW2, p_bnar, p_bwid, Dnb, Dwb);

  // t1 = LN(attn + Dn + Dw) -> bf16
  ln_k<2,1><<<dim3(NROWS), dim3(256), 0, stream>>>(attnb, Dnb, Dwb, p_l1g, p_l1b, flags, (void*)t1b);

  // E = gelu(t1 @ ff_w + ff_b) -> bf16
  mgemm64b_k<true,true><<<dim3(4, 128), dim3(256), 0, stream>>>(
      t1b, ffwt, p_ffb, Eb, NROWS, 512, 512);

  // out = LN(E) -> d_out, dtype per flags
  ln_k<0,2><<<dim3(NROWS), dim3(256), 0, stream>>>(Eb, nullptr, nullptr, p_l2g, p_l2b, flags, d_out);
}